// Round 6
// baseline (2076.298 us; speedup 1.0000x reference)
//
#include <hip/hip_runtime.h>
#include <math.h>

// ---------------------------------------------------------------------------
// Transpose all 32 weight matrices: wt[mat][c][k] = W[mat>>1][k][c]  (f32)
// mat = (l*8+t)*2 + which (0=Wl, 1=Wr)
// ---------------------------------------------------------------------------
__global__ __launch_bounds__(256) void transpose_w(
    const float* __restrict__ Wl, const float* __restrict__ Wr,
    float* __restrict__ wt)
{
  int elem = blockIdx.x * 256 + threadIdx.x;   // 0 .. 32*16384-1
  int mat = elem >> 14;
  int c = (elem >> 7) & 127;
  int k = elem & 127;
  const float* srcb = (mat & 1) ? Wr : Wl;
  int m2 = mat >> 1;
  wt[elem] = srcb[((long)m2 << 14) + (k << 7) + c];
}

// ---------------------------------------------------------------------------
// proj_v2: out[N,128] = x[N,128] @ W[128,128], W transposed wt[c][k].
// 64 rows x 128 cols per block (256 thr); per thread 8 rows x 4 cols.
// ---------------------------------------------------------------------------
template<bool ACC>
__global__ __launch_bounds__(256) void proj_v2(
    const float* __restrict__ xg, const float* __restrict__ wtg,
    float* __restrict__ out, int N)
{
  __shared__ __align__(16) float xs[64][128];
  const int tid = threadIdx.x;
  const long r0 = (long)blockIdx.x * 64;
  for (int i = tid; i < 2048; i += 256) {   // 64 rows x 32 float4
    int r = i >> 5, c4 = (i & 31) << 2;
    float4 v = {0.f, 0.f, 0.f, 0.f};
    if (r0 + r < N) v = *(const float4*)(xg + (r0 + r) * 128 + c4);
    *(float4*)&xs[r][c4] = v;
  }
  __syncthreads();
  const int rb = (tid >> 5) * 8, cb = (tid & 31) * 4;
  float acc[8][4] = {};
  for (int kc = 0; kc < 32; ++kc) {
    int k = kc << 2;
    float4 w0 = *(const float4*)(wtg + (cb + 0) * 128 + k);
    float4 w1 = *(const float4*)(wtg + (cb + 1) * 128 + k);
    float4 w2 = *(const float4*)(wtg + (cb + 2) * 128 + k);
    float4 w3 = *(const float4*)(wtg + (cb + 3) * 128 + k);
#pragma unroll
    for (int r = 0; r < 8; ++r) {
      float4 xv = *(const float4*)&xs[rb + r][k];
      acc[r][0] = fmaf(xv.x, w0.x, fmaf(xv.y, w0.y, fmaf(xv.z, w0.z, fmaf(xv.w, w0.w, acc[r][0]))));
      acc[r][1] = fmaf(xv.x, w1.x, fmaf(xv.y, w1.y, fmaf(xv.z, w1.z, fmaf(xv.w, w1.w, acc[r][1]))));
      acc[r][2] = fmaf(xv.x, w2.x, fmaf(xv.y, w2.y, fmaf(xv.z, w2.z, fmaf(xv.w, w2.w, acc[r][2]))));
      acc[r][3] = fmaf(xv.x, w3.x, fmaf(xv.y, w3.y, fmaf(xv.z, w3.z, fmaf(xv.w, w3.w, acc[r][3]))));
    }
  }
#pragma unroll
  for (int r = 0; r < 8; ++r) {
    long row = r0 + rb + r;
    if (row < N) {
      float* op = out + row * 128 + cb;
      if (ACC) {
        float4 cur = *(const float4*)op;
        cur.x += acc[r][0]; cur.y += acc[r][1];
        cur.z += acc[r][2]; cur.w += acc[r][3];
        *(float4*)op = cur;
      } else {
        float4 v = {acc[r][0], acc[r][1], acc[r][2], acc[r][3]};
        *(float4*)op = v;
      }
    }
  }
}

// ---------------------------------------------------------------------------
// Batched CSR build over all 5 edge types (3 launches total).
// ---------------------------------------------------------------------------
struct EdgeArgs {
  const int* src[5]; const int* dst[5];
  int* cur[5];         // degree, then cursor (aliased)
  int* rs[5];          // row_start[nd+1]
  int* csrc[5];
  int E[5]; int Nd[5];
  int blkOff[6];       // block-range per type for hist/fill grids
};

__global__ __launch_bounds__(256) void hist_all(EdgeArgs a)
{
  int blk = blockIdx.x, t = 0;
  while (blk >= a.blkOff[t + 1]) ++t;
  int e = (blk - a.blkOff[t]) * 256 + threadIdx.x;
  if (e < a.E[t]) atomicAdd(&a.cur[t][a.dst[t][e]], 1);
}

__global__ __launch_bounds__(1024) void scan_all(EdgeArgs a)
{
  int t = blockIdx.x;
  int n = a.Nd[t];
  int* deg = a.cur[t];
  int* rs = a.rs[t];
  __shared__ int tile[1024];
  __shared__ int sbase;
  int tid = threadIdx.x;
  if (tid == 0) sbase = 0;
  __syncthreads();
  for (int chunk = 0; chunk < n; chunk += 16384) {
    int idx0 = chunk + tid * 16;
    int v[16], sum = 0;
#pragma unroll
    for (int j = 0; j < 16; ++j) {
      v[j] = (idx0 + j < n) ? deg[idx0 + j] : 0;
      sum += v[j];
    }
    tile[tid] = sum;
    __syncthreads();
    for (int off = 1; off < 1024; off <<= 1) {   // Hillis-Steele inclusive
      int tv = (tid >= off) ? tile[tid - off] : 0;
      __syncthreads();
      tile[tid] += tv;
      __syncthreads();
    }
    int excl = sbase + ((tid > 0) ? tile[tid - 1] : 0);
#pragma unroll
    for (int j = 0; j < 16; ++j) {
      if (idx0 + j < n) { rs[idx0 + j] = excl; deg[idx0 + j] = excl; }
      excl += v[j];
    }
    __syncthreads();
    if (tid == 0) sbase += tile[1023];
    __syncthreads();
  }
  if (tid == 0) rs[n] = sbase;
}

__global__ __launch_bounds__(256) void fill_all(EdgeArgs a)
{
  int blk = blockIdx.x, t = 0;
  while (blk >= a.blkOff[t + 1]) ++t;
  int e = (blk - a.blkOff[t]) * 256 + threadIdx.x;
  if (e < a.E[t]) {
    int pos = atomicAdd(&a.cur[t][a.dst[t][e]], 1);
    a.csrc[t][pos] = a.src[t][e];
  }
}

// ---------------------------------------------------------------------------
// Fused GATv2 aggregate, one wave per dst row, 2-way edge unroll for MLP.
// Lane l owns channels 2l,2l+1; head h = lanes [8h,8h+8).
// agg[d] (=|+=) (sum_e a_e*hs[src_e])/(sum_e a_e+eps).
// ---------------------------------------------------------------------------
template<bool INIT>
__global__ __launch_bounds__(256) void gat_gather(
    const int* __restrict__ row_start, const int* __restrict__ csr_src,
    const float* __restrict__ hs, const float* __restrict__ hd,
    const float* __restrict__ att, float* __restrict__ agg, int Nd)
{
  int d = blockIdx.x * 4 + (threadIdx.x >> 6);
  if (d >= Nd) return;
  int lane = threadIdx.x & 63;
  float2 att2 = *(const float2*)(att + 2 * lane);
  float2 hd2 = *(const float2*)(hd + (long)d * 128 + 2 * lane);
  int beg = row_start[d], end = row_start[d + 1];
  float n0 = 0.f, n1 = 0.f, D = 0.f;
  int i = beg;
  for (; i + 1 < end; i += 2) {
    int s0 = csr_src[i], s1 = csr_src[i + 1];
    float2 ha = *(const float2*)(hs + (long)s0 * 128 + 2 * lane);
    float2 hb = *(const float2*)(hs + (long)s1 * 128 + 2 * lane);
    float va0 = ha.x + hd2.x, va1 = ha.y + hd2.y;
    float vb0 = hb.x + hd2.x, vb1 = hb.y + hd2.y;
    va0 = fmaxf(va0, 0.2f * va0); va1 = fmaxf(va1, 0.2f * va1);
    vb0 = fmaxf(vb0, 0.2f * vb0); vb1 = fmaxf(vb1, 0.2f * vb1);
    float pa = fmaf(va0, att2.x, va1 * att2.y);
    float pb = fmaf(vb0, att2.x, vb1 * att2.y);
    pa += __shfl_xor(pa, 1); pb += __shfl_xor(pb, 1);
    pa += __shfl_xor(pa, 2); pb += __shfl_xor(pb, 2);
    pa += __shfl_xor(pa, 4); pb += __shfl_xor(pb, 4);
    float aa = expf(fminf(pa, 60.f));
    float ab = expf(fminf(pb, 60.f));
    n0 = fmaf(aa, ha.x, n0); n1 = fmaf(aa, ha.y, n1); D += aa;
    n0 = fmaf(ab, hb.x, n0); n1 = fmaf(ab, hb.y, n1); D += ab;
  }
  if (i < end) {
    int s = csr_src[i];
    float2 h = *(const float2*)(hs + (long)s * 128 + 2 * lane);
    float v0 = h.x + hd2.x, v1 = h.y + hd2.y;
    v0 = fmaxf(v0, 0.2f * v0);
    v1 = fmaxf(v1, 0.2f * v1);
    float pp = fmaf(v0, att2.x, v1 * att2.y);
    pp += __shfl_xor(pp, 1);
    pp += __shfl_xor(pp, 2);
    pp += __shfl_xor(pp, 4);
    float a = expf(fminf(pp, 60.f));
    n0 = fmaf(a, h.x, n0);
    n1 = fmaf(a, h.y, n1);
    D += a;
  }
  float inv = 1.f / (D + 1e-16f);
  float* ap = agg + (long)d * 128 + 2 * lane;
  if (INIT) {
    float2 v = {n0 * inv, n1 * inv};
    *(float2*)ap = v;
  } else {
    float2 cur = *(const float2*)ap;
    cur.x += n0 * inv;
    cur.y += n1 * inv;
    *(float2*)ap = cur;
  }
}

// ---------------------------------------------------------------------------
// xf = LayerNorm(xin + elu(agg + sum_masked(bias)));  1 wave per row.
// ---------------------------------------------------------------------------
__global__ __launch_bounds__(256) void update_ln(
    const float* __restrict__ xin, float* __restrict__ xf,
    const float* __restrict__ agg, const float* __restrict__ biasl, int tmask,
    const float* __restrict__ gam, const float* __restrict__ bet, int N)
{
  int row = blockIdx.x * 4 + (threadIdx.x >> 6);
  int lane = threadIdx.x & 63;
  if (row >= N) return;
  float bs0 = 0.f, bs1 = 0.f;
#pragma unroll
  for (int t = 0; t < 8; ++t)
    if (tmask & (1 << t)) {
      bs0 += biasl[t * 128 + lane];
      bs1 += biasl[t * 128 + 64 + lane];
    }
  long base = (long)row * 128;
  float v0 = agg[base + lane] + bs0, v1 = agg[base + 64 + lane] + bs1;
  v0 = v0 > 0.f ? v0 : expf(v0) - 1.f;
  v1 = v1 > 0.f ? v1 : expf(v1) - 1.f;
  float x0 = xin[base + lane] + v0, x1 = xin[base + 64 + lane] + v1;
  float s = x0 + x1;
#pragma unroll
  for (int o = 32; o > 0; o >>= 1) s += __shfl_xor(s, o);
  float mu = s * 0.0078125f;
  float dd0 = x0 - mu, dd1 = x1 - mu;
  float q = dd0 * dd0 + dd1 * dd1;
#pragma unroll
  for (int o = 32; o > 0; o >>= 1) q += __shfl_xor(q, o);
  float r = rsqrtf(q * 0.0078125f + 1e-5f);
  xf[base + lane]      = dd0 * r * gam[lane]      + bet[lane];
  xf[base + 64 + lane] = dd1 * r * gam[64 + lane] + bet[64 + lane];
}

// ---------------------------------------------------------------------------
// zgemm stage 1: ONE 64-row n-chunk per block (full parallelism), non-atomic
// partial tile per block: zpart[blk][64][128].
// ---------------------------------------------------------------------------
__global__ __launch_bounds__(256) void zgemm_part(
    const float* __restrict__ batch, const float* __restrict__ x,
    float* __restrict__ zpart, int N)
{
  __shared__ __align__(16) float xl[64 * 128];
  __shared__ __align__(16) float bl[64 * 65];
  int tid = threadIdx.x;
  int n0 = blockIdx.x * 64;
  for (int i = tid; i < 64 * 128; i += 256) {
    int nn = i >> 7;
    xl[i] = (n0 + nn < N) ? x[(long)(n0 + nn) * 128 + (i & 127)] : 0.f;
  }
  for (int i = tid; i < 64 * 64; i += 256) {
    int b = i >> 6, nn = i & 63;
    bl[nn * 65 + b] = (n0 + nn < N) ? batch[(long)b * N + n0 + nn] : 0.f;
  }
  __syncthreads();
  int cg = (tid & 31) * 4;
  int bg = (tid >> 5) * 8;
  float acc[8][4] = {};
  for (int nn = 0; nn < 64; ++nn) {
    float4 xv = *(const float4*)(xl + nn * 128 + cg);
#pragma unroll
    for (int i = 0; i < 8; ++i) {
      float bv = bl[nn * 65 + bg + i];
      acc[i][0] = fmaf(bv, xv.x, acc[i][0]);
      acc[i][1] = fmaf(bv, xv.y, acc[i][1]);
      acc[i][2] = fmaf(bv, xv.z, acc[i][2]);
      acc[i][3] = fmaf(bv, xv.w, acc[i][3]);
    }
  }
  float* zp = zpart + (long)blockIdx.x * 8192;
#pragma unroll
  for (int i = 0; i < 8; ++i) {
    float4 v = {acc[i][0], acc[i][1], acc[i][2], acc[i][3]};
    *(float4*)(zp + (bg + i) * 128 + cg) = v;
  }
}

// ---------------------------------------------------------------------------
// zgemm stage 2: zpre[ty][i] = scale[ty] * sum_g zpart[ty][g][i]
// grid 96 blocks x 256 (ty = blk>>5). Coalesced stride-8192 reads.
// ---------------------------------------------------------------------------
__global__ __launch_bounds__(256) void zreduce(
    const float* __restrict__ zp0, const float* __restrict__ zp1,
    const float* __restrict__ zp2, int G0, int G1, int G2,
    float s0, float s1, float s2, float* __restrict__ zpre)
{
  int blk = blockIdx.x;
  int ty = blk >> 5;
  int i = (blk & 31) * 256 + threadIdx.x;
  const float* zp = ty == 0 ? zp0 : (ty == 1 ? zp1 : zp2);
  int G = ty == 0 ? G0 : (ty == 1 ? G1 : G2);
  float sc = ty == 0 ? s0 : (ty == 1 ? s1 : s2);
  float s = 0.f;
  for (int g = 0; g < G; ++g) s += zp[(long)g * 8192 + i];
  zpre[ty * 8192 + i] = s * sc;
}

// ---------------------------------------------------------------------------
// Final LayerNorm over zpre[3*64,128] -> f32 out. 1 wave/row.
// ---------------------------------------------------------------------------
__global__ __launch_bounds__(256) void final_ln(
    const float* __restrict__ zpre, const float* __restrict__ gam,
    const float* __restrict__ bet, float* __restrict__ out)
{
  int row = blockIdx.x * 4 + (threadIdx.x >> 6);
  int lane = threadIdx.x & 63;
  if (row >= 192) return;
  int ty = row >> 6;
  long base = (long)row * 128;
  float x0 = zpre[base + lane], x1 = zpre[base + 64 + lane];
  float s = x0 + x1;
#pragma unroll
  for (int o = 32; o > 0; o >>= 1) s += __shfl_xor(s, o);
  float mu = s * 0.0078125f;
  float d0 = x0 - mu, d1 = x1 - mu;
  float q = d0 * d0 + d1 * d1;
#pragma unroll
  for (int o = 32; o > 0; o >>= 1) q += __shfl_xor(q, o);
  float r = rsqrtf(q * 0.0078125f + 1e-5f);
  out[base + lane]      = d0 * r * gam[ty * 128 + lane]      + bet[ty * 128 + lane];
  out[base + 64 + lane] = d1 * r * gam[ty * 128 + 64 + lane] + bet[ty * 128 + 64 + lane];
}

// ---------------------------------------------------------------------------
extern "C" void kernel_launch(void* const* d_in, const int* in_sizes, int n_in,
                              void* d_out, int out_size, void* d_ws, size_t ws_size,
                              hipStream_t stream)
{
  const float* batchp[3] = {(const float*)d_in[0], (const float*)d_in[1],
                            (const float*)d_in[2]};
  const float* emb[3] = {(const float*)d_in[3], (const float*)d_in[4],
                         (const float*)d_in[5]};
  const float* Wl   = (const float*)d_in[6];
  const float* Wr   = (const float*)d_in[7];
  const float* att  = (const float*)d_in[8];
  const float* bias = (const float*)d_in[9];
  const float* lng  = (const float*)d_in[10];
  const float* lnb  = (const float*)d_in[11];
  const float* outg = (const float*)d_in[12];
  const float* outb = (const float*)d_in[13];
  const int* eiP[8]; int E[8];
  for (int t = 0; t < 8; ++t) { eiP[t] = (const int*)d_in[14 + t]; E[t] = in_sizes[14 + t] / 2; }
  int Nn[3] = {in_sizes[3] / 128, in_sizes[4] / 128, in_sizes[5] / 128};
  int maxN = Nn[0] > Nn[1] ? Nn[0] : Nn[1]; if (Nn[2] > maxN) maxN = Nn[2];
  long Ntot = (long)Nn[0] + Nn[1] + Nn[2];

  const int SI[5] = {1, 0, 2, 0, 0};
  const int DI[5] = {0, 1, 0, 2, 0};
  const int TMASK[3] = {0x35, 0x42, 0x88};  // gene: t0,t2,t4,t5; cpg: t1,t6; mirna: t3,t7

  char* p = (char*)d_ws;
  auto carve = [&](size_t b) -> void* {
    void* r = (void*)p; p += (b + 255) & ~(size_t)255; return r;
  };
  float* xf[3];
  for (int ty = 0; ty < 3; ++ty) xf[ty] = (float*)carve((size_t)Nn[ty] * 128 * 4);
  float* aggAll = (float*)carve((size_t)Ntot * 128 * 4);
  float* agg[3] = {aggAll, aggAll + (long)Nn[0] * 128, aggAll + ((long)Nn[0] + Nn[1]) * 128};
  float* hsb = (float*)carve((size_t)maxN * 128 * 4);
  float* hdb = (float*)carve((size_t)maxN * 128 * 4);
  float* zpre = (float*)carve(3 * 64 * 128 * 4);
  float* wt = (float*)carve((size_t)32 * 16384 * 4);

  // CSR (deg/cursor regions contiguous for one memset)
  EdgeArgs ea;
  long degTot = 0;
  for (int t = 0; t < 5; ++t) degTot += Nn[DI[t]];
  int* degAll = (int*)carve(degTot * 4);
  {
    int* dp = degAll;
    int boff = 0;
    for (int t = 0; t < 5; ++t) {
      int nd = Nn[DI[t]];
      ea.src[t] = eiP[t];
      ea.dst[t] = eiP[t] + E[t];
      ea.cur[t] = dp; dp += nd;
      ea.rs[t] = (int*)carve((size_t)(nd + 1) * 4);
      ea.csrc[t] = (int*)carve((size_t)E[t] * 4);
      ea.E[t] = E[t];
      ea.Nd[t] = nd;
      ea.blkOff[t] = boff;
      boff += (E[t] + 255) / 256;
      if (t == 4) ea.blkOff[5] = boff;
    }
  }
  if ((size_t)(p - (char*)d_ws) > ws_size) return;  // workspace too small

  // zgemm partials alias hsb+hdb (dead after the layer loop):
  // (nch0+nch1+nch2) tiles x 32 KB = ~41 MB <= hsb+hdb (~61 MB)
  int nch[3], Gty[3];
  for (int ty = 0; ty < 3; ++ty) { nch[ty] = (Nn[ty] + 63) / 64; Gty[ty] = nch[ty]; }
  float* zp[3];
  zp[0] = hsb;
  zp[1] = zp[0] + (long)nch[0] * 8192;
  zp[2] = zp[1] + (long)nch[1] * 8192;

  // 0) transpose weights
  transpose_w<<<2048, 256, 0, stream>>>(Wl, Wr, wt);

  // 1) build CSR for the 5 real edge types (3 launches)
  hipMemsetAsync(degAll, 0, degTot * 4, stream);
  hist_all<<<ea.blkOff[5], 256, 0, stream>>>(ea);
  scan_all<<<5, 1024, 0, stream>>>(ea);
  fill_all<<<ea.blkOff[5], 256, 0, stream>>>(ea);

  for (int l = 0; l < 2; ++l) {
    const float* xin[3] = {l == 0 ? emb[0] : xf[0],
                           l == 0 ? emb[1] : xf[1],
                           l == 0 ? emb[2] : xf[2]};
    for (int t = 0; t < 5; ++t) {
      int si = SI[t], di = DI[t];
      int mb = (l * 8 + t) * 2;
      proj_v2<false><<<(Nn[si] + 63) / 64, 256, 0, stream>>>(
          xin[si], wt + (long)mb * 16384, hsb, Nn[si]);
      proj_v2<false><<<(Nn[di] + 63) / 64, 256, 0, stream>>>(
          xin[di], wt + (long)(mb + 1) * 16384, hdb, Nn[di]);
      const float* attp = att + (long)(l * 8 + t) * 128;
      int gblk = (Nn[di] + 3) / 4;
      if (t == 0 || t == 1 || t == 3)   // first writer of gene/cpg/mirna agg
        gat_gather<true><<<gblk, 256, 0, stream>>>(
            ea.rs[t], ea.csrc[t], hsb, hdb, attp, agg[di], Nn[di]);
      else
        gat_gather<false><<<gblk, 256, 0, stream>>>(
            ea.rs[t], ea.csrc[t], hsb, hdb, attp, agg[di], Nn[di]);
    }
    for (int t = 5; t < 8; ++t) {  // self-loop convs: agg += x @ Wl (alpha == 1)
      int ty = t - 5;
      proj_v2<true><<<(Nn[ty] + 63) / 64, 256, 0, stream>>>(
          xin[ty], wt + (long)((l * 8 + t) * 2) * 16384, agg[ty], Nn[ty]);
    }
    for (int ty = 0; ty < 3; ++ty)
      update_ln<<<(Nn[ty] + 3) / 4, 256, 0, stream>>>(
          xin[ty], xf[ty], agg[ty], bias + (long)l * 8 * 128, TMASK[ty],
          lng + (long)(l * 3 + ty) * 128, lnb + (long)(l * 3 + ty) * 128, Nn[ty]);
  }

  // final: z = LN(batch @ x / sqrt(N)) via one-chunk-per-block partials + reduce
  for (int ty = 0; ty < 3; ++ty)
    zgemm_part<<<nch[ty], 256, 0, stream>>>(batchp[ty], xf[ty], zp[ty], Nn[ty]);
  zreduce<<<96, 256, 0, stream>>>(
      zp[0], zp[1], zp[2], Gty[0], Gty[1], Gty[2],
      (float)(1.0 / sqrt((double)Nn[0])), (float)(1.0 / sqrt((double)Nn[1])),
      (float)(1.0 / sqrt((double)Nn[2])), zpre);
  final_ln<<<48, 256, 0, stream>>>(zpre, outg, outb, (float*)d_out);
}

// Round 7
// 1294.880 us; speedup vs baseline: 1.6035x; 1.6035x over previous
//
#include <hip/hip_runtime.h>
#include <math.h>

struct ProjJob { const float* x; const float* W; float* out; int N; };

// ---------------------------------------------------------------------------
// Shared proj tile body: out[64,128] (=|+=) x[64,128] @ W[128,128] (W row-major
// [k][c] — original layout). Per thread 8 rows x 4 cols. W loads coalesced
// (lanes read 512B contiguous per k); x LDS reads are 2-address broadcasts.
// ---------------------------------------------------------------------------
template<bool ACC>
__device__ __forceinline__ void proj_tile(
    float (*xs)[128], const float* __restrict__ xg, const float* __restrict__ Wg,
    float* __restrict__ out, int N, long r0, int tid)
{
  for (int i = tid; i < 2048; i += 256) {   // 64 rows x 32 float4
    int r = i >> 5, c4 = (i & 31) << 2;
    float4 v = {0.f, 0.f, 0.f, 0.f};
    if (r0 + r < N) v = *(const float4*)(xg + (r0 + r) * 128 + c4);
    *(float4*)&xs[r][c4] = v;
  }
  __syncthreads();
  const int rb = (tid >> 5) * 8, cb = (tid & 31) * 4;
  float acc[8][4] = {};
  for (int kc = 0; kc < 32; ++kc) {
    int k = kc << 2;
    float4 w0 = *(const float4*)(Wg + (k + 0) * 128 + cb);
    float4 w1 = *(const float4*)(Wg + (k + 1) * 128 + cb);
    float4 w2 = *(const float4*)(Wg + (k + 2) * 128 + cb);
    float4 w3 = *(const float4*)(Wg + (k + 3) * 128 + cb);
#pragma unroll
    for (int r = 0; r < 8; ++r) {
      float4 xv = *(const float4*)&xs[rb + r][k];
      acc[r][0] = fmaf(xv.x, w0.x, fmaf(xv.y, w1.x, fmaf(xv.z, w2.x, fmaf(xv.w, w3.x, acc[r][0]))));
      acc[r][1] = fmaf(xv.x, w0.y, fmaf(xv.y, w1.y, fmaf(xv.z, w2.y, fmaf(xv.w, w3.y, acc[r][1]))));
      acc[r][2] = fmaf(xv.x, w0.z, fmaf(xv.y, w1.z, fmaf(xv.z, w2.z, fmaf(xv.w, w3.z, acc[r][2]))));
      acc[r][3] = fmaf(xv.x, w0.w, fmaf(xv.y, w1.w, fmaf(xv.z, w2.w, fmaf(xv.w, w3.w, acc[r][3]))));
    }
  }
#pragma unroll
  for (int r = 0; r < 8; ++r) {
    long row = r0 + rb + r;
    if (row < N) {
      float* op = out + row * 128 + cb;
      if (ACC) {
        float4 cur = *(const float4*)op;
        cur.x += acc[r][0]; cur.y += acc[r][1];
        cur.z += acc[r][2]; cur.w += acc[r][3];
        *(float4*)op = cur;
      } else {
        float4 v = {acc[r][0], acc[r][1], acc[r][2], acc[r][3]};
        *(float4*)op = v;
      }
    }
  }
}

// hs+hd projections for one edge type in a single launch (segmented grid).
__global__ __launch_bounds__(256) void proj_pair(ProjJob a, ProjJob b, int split)
{
  __shared__ __align__(16) float xs[64][128];
  int blk = blockIdx.x;
  if (blk < split)
    proj_tile<false>(xs, a.x, a.W, a.out, a.N, (long)blk * 64, threadIdx.x);
  else
    proj_tile<false>(xs, b.x, b.W, b.out, b.N, (long)(blk - split) * 64, threadIdx.x);
}

// 3 self-loop convs (agg += x @ Wl) in a single launch.
__global__ __launch_bounds__(256) void proj_self(
    ProjJob j0, ProjJob j1, ProjJob j2, int s1, int s2)
{
  __shared__ __align__(16) float xs[64][128];
  int blk = blockIdx.x;
  if (blk < s1)
    proj_tile<true>(xs, j0.x, j0.W, j0.out, j0.N, (long)blk * 64, threadIdx.x);
  else if (blk < s2)
    proj_tile<true>(xs, j1.x, j1.W, j1.out, j1.N, (long)(blk - s1) * 64, threadIdx.x);
  else
    proj_tile<true>(xs, j2.x, j2.W, j2.out, j2.N, (long)(blk - s2) * 64, threadIdx.x);
}

// ---------------------------------------------------------------------------
// Batched CSR build over all 5 edge types (3 launches total).
// ---------------------------------------------------------------------------
struct EdgeArgs {
  const int* src[5]; const int* dst[5];
  int* cur[5];         // degree, then cursor (aliased)
  int* rs[5];          // row_start[nd+1]
  int* csrc[5];
  int E[5]; int Nd[5];
  int blkOff[6];       // block-range per type for hist/fill grids
};

__global__ __launch_bounds__(256) void hist_all(EdgeArgs a)
{
  int blk = blockIdx.x, t = 0;
  while (blk >= a.blkOff[t + 1]) ++t;
  int e = (blk - a.blkOff[t]) * 256 + threadIdx.x;
  if (e < a.E[t]) atomicAdd(&a.cur[t][a.dst[t][e]], 1);
}

__global__ __launch_bounds__(1024) void scan_all(EdgeArgs a)
{
  int t = blockIdx.x;
  int n = a.Nd[t];
  int* deg = a.cur[t];
  int* rs = a.rs[t];
  __shared__ int tile[1024];
  __shared__ int sbase;
  int tid = threadIdx.x;
  if (tid == 0) sbase = 0;
  __syncthreads();
  for (int chunk = 0; chunk < n; chunk += 16384) {
    int idx0 = chunk + tid * 16;
    int v[16], sum = 0;
#pragma unroll
    for (int j = 0; j < 16; ++j) {
      v[j] = (idx0 + j < n) ? deg[idx0 + j] : 0;
      sum += v[j];
    }
    tile[tid] = sum;
    __syncthreads();
    for (int off = 1; off < 1024; off <<= 1) {   // Hillis-Steele inclusive
      int tv = (tid >= off) ? tile[tid - off] : 0;
      __syncthreads();
      tile[tid] += tv;
      __syncthreads();
    }
    int excl = sbase + ((tid > 0) ? tile[tid - 1] : 0);
#pragma unroll
    for (int j = 0; j < 16; ++j) {
      if (idx0 + j < n) { rs[idx0 + j] = excl; deg[idx0 + j] = excl; }
      excl += v[j];
    }
    __syncthreads();
    if (tid == 0) sbase += tile[1023];
    __syncthreads();
  }
  if (tid == 0) rs[n] = sbase;
}

__global__ __launch_bounds__(256) void fill_all(EdgeArgs a)
{
  int blk = blockIdx.x, t = 0;
  while (blk >= a.blkOff[t + 1]) ++t;
  int e = (blk - a.blkOff[t]) * 256 + threadIdx.x;
  if (e < a.E[t]) {
    int pos = atomicAdd(&a.cur[t][a.dst[t][e]], 1);
    a.csrc[t][pos] = a.src[t][e];
  }
}

// ---------------------------------------------------------------------------
// Fused GATv2 aggregate, one wave per dst row, 2-way edge unroll for MLP.
// Lane l owns channels 2l,2l+1; head h = lanes [8h,8h+8).
// agg[d] (=|+=) (sum_e a_e*hs[src_e])/(sum_e a_e+eps).
// ---------------------------------------------------------------------------
template<bool INIT>
__global__ __launch_bounds__(256) void gat_gather(
    const int* __restrict__ row_start, const int* __restrict__ csr_src,
    const float* __restrict__ hs, const float* __restrict__ hd,
    const float* __restrict__ att, float* __restrict__ agg, int Nd)
{
  int d = blockIdx.x * 4 + (threadIdx.x >> 6);
  if (d >= Nd) return;
  int lane = threadIdx.x & 63;
  float2 att2 = *(const float2*)(att + 2 * lane);
  float2 hd2 = *(const float2*)(hd + (long)d * 128 + 2 * lane);
  int beg = row_start[d], end = row_start[d + 1];
  float n0 = 0.f, n1 = 0.f, D = 0.f;
  int i = beg;
  for (; i + 1 < end; i += 2) {
    int s0 = csr_src[i], s1 = csr_src[i + 1];
    float2 ha = *(const float2*)(hs + (long)s0 * 128 + 2 * lane);
    float2 hb = *(const float2*)(hs + (long)s1 * 128 + 2 * lane);
    float va0 = ha.x + hd2.x, va1 = ha.y + hd2.y;
    float vb0 = hb.x + hd2.x, vb1 = hb.y + hd2.y;
    va0 = fmaxf(va0, 0.2f * va0); va1 = fmaxf(va1, 0.2f * va1);
    vb0 = fmaxf(vb0, 0.2f * vb0); vb1 = fmaxf(vb1, 0.2f * vb1);
    float pa = fmaf(va0, att2.x, va1 * att2.y);
    float pb = fmaf(vb0, att2.x, vb1 * att2.y);
    pa += __shfl_xor(pa, 1); pb += __shfl_xor(pb, 1);
    pa += __shfl_xor(pa, 2); pb += __shfl_xor(pb, 2);
    pa += __shfl_xor(pa, 4); pb += __shfl_xor(pb, 4);
    float aa = expf(fminf(pa, 60.f));
    float ab = expf(fminf(pb, 60.f));
    n0 = fmaf(aa, ha.x, n0); n1 = fmaf(aa, ha.y, n1); D += aa;
    n0 = fmaf(ab, hb.x, n0); n1 = fmaf(ab, hb.y, n1); D += ab;
  }
  if (i < end) {
    int s = csr_src[i];
    float2 h = *(const float2*)(hs + (long)s * 128 + 2 * lane);
    float v0 = h.x + hd2.x, v1 = h.y + hd2.y;
    v0 = fmaxf(v0, 0.2f * v0);
    v1 = fmaxf(v1, 0.2f * v1);
    float pp = fmaf(v0, att2.x, v1 * att2.y);
    pp += __shfl_xor(pp, 1);
    pp += __shfl_xor(pp, 2);
    pp += __shfl_xor(pp, 4);
    float a = expf(fminf(pp, 60.f));
    n0 = fmaf(a, h.x, n0);
    n1 = fmaf(a, h.y, n1);
    D += a;
  }
  float inv = 1.f / (D + 1e-16f);
  float* ap = agg + (long)d * 128 + 2 * lane;
  if (INIT) {
    float2 v = {n0 * inv, n1 * inv};
    *(float2*)ap = v;
  } else {
    float2 cur = *(const float2*)ap;
    cur.x += n0 * inv;
    cur.y += n1 * inv;
    *(float2*)ap = cur;
  }
}

// ---------------------------------------------------------------------------
// xf = LayerNorm(xin + elu(agg + sum_masked(bias)));  1 wave per row.
// ---------------------------------------------------------------------------
__global__ __launch_bounds__(256) void update_ln(
    const float* __restrict__ xin, float* __restrict__ xf,
    const float* __restrict__ agg, const float* __restrict__ biasl, int tmask,
    const float* __restrict__ gam, const float* __restrict__ bet, int N)
{
  int row = blockIdx.x * 4 + (threadIdx.x >> 6);
  int lane = threadIdx.x & 63;
  if (row >= N) return;
  float bs0 = 0.f, bs1 = 0.f;
#pragma unroll
  for (int t = 0; t < 8; ++t)
    if (tmask & (1 << t)) {
      bs0 += biasl[t * 128 + lane];
      bs1 += biasl[t * 128 + 64 + lane];
    }
  long base = (long)row * 128;
  float v0 = agg[base + lane] + bs0, v1 = agg[base + 64 + lane] + bs1;
  v0 = v0 > 0.f ? v0 : expf(v0) - 1.f;
  v1 = v1 > 0.f ? v1 : expf(v1) - 1.f;
  float x0 = xin[base + lane] + v0, x1 = xin[base + 64 + lane] + v1;
  float s = x0 + x1;
#pragma unroll
  for (int o = 32; o > 0; o >>= 1) s += __shfl_xor(s, o);
  float mu = s * 0.0078125f;
  float dd0 = x0 - mu, dd1 = x1 - mu;
  float q = dd0 * dd0 + dd1 * dd1;
#pragma unroll
  for (int o = 32; o > 0; o >>= 1) q += __shfl_xor(q, o);
  float r = rsqrtf(q * 0.0078125f + 1e-5f);
  xf[base + lane]      = dd0 * r * gam[lane]      + bet[lane];
  xf[base + 64 + lane] = dd1 * r * gam[64 + lane] + bet[64 + lane];
}

// ---------------------------------------------------------------------------
// zgemm stage 1: ONE 64-row n-chunk per block, non-atomic partial tiles.
// ---------------------------------------------------------------------------
__global__ __launch_bounds__(256) void zgemm_part(
    const float* __restrict__ batch, const float* __restrict__ x,
    float* __restrict__ zpart, int N)
{
  __shared__ __align__(16) float xl[64 * 128];
  __shared__ __align__(16) float bl[64 * 65];
  int tid = threadIdx.x;
  int n0 = blockIdx.x * 64;
  for (int i = tid; i < 64 * 128; i += 256) {
    int nn = i >> 7;
    xl[i] = (n0 + nn < N) ? x[(long)(n0 + nn) * 128 + (i & 127)] : 0.f;
  }
  for (int i = tid; i < 64 * 64; i += 256) {
    int b = i >> 6, nn = i & 63;
    bl[nn * 65 + b] = (n0 + nn < N) ? batch[(long)b * N + n0 + nn] : 0.f;
  }
  __syncthreads();
  int cg = (tid & 31) * 4;
  int bg = (tid >> 5) * 8;
  float acc[8][4] = {};
  for (int nn = 0; nn < 64; ++nn) {
    float4 xv = *(const float4*)(xl + nn * 128 + cg);
#pragma unroll
    for (int i = 0; i < 8; ++i) {
      float bv = bl[nn * 65 + bg + i];
      acc[i][0] = fmaf(bv, xv.x, acc[i][0]);
      acc[i][1] = fmaf(bv, xv.y, acc[i][1]);
      acc[i][2] = fmaf(bv, xv.z, acc[i][2]);
      acc[i][3] = fmaf(bv, xv.w, acc[i][3]);
    }
  }
  float* zp = zpart + (long)blockIdx.x * 8192;
#pragma unroll
  for (int i = 0; i < 8; ++i) {
    float4 v = {acc[i][0], acc[i][1], acc[i][2], acc[i][3]};
    *(float4*)(zp + (bg + i) * 128 + cg) = v;
  }
}

// ---------------------------------------------------------------------------
// zgemm stage 2: zpre[ty][i] = scale[ty] * sum_g zpart[ty][g][i]
// 16 independent accumulators -> 16 loads in flight per thread (MLP fix).
// ---------------------------------------------------------------------------
__global__ __launch_bounds__(256) void zreduce(
    const float* __restrict__ zp0, const float* __restrict__ zp1,
    const float* __restrict__ zp2, int G0, int G1, int G2,
    float s0, float s1, float s2, float* __restrict__ zpre)
{
  int blk = blockIdx.x;
  int ty = blk >> 5;
  int i = (blk & 31) * 256 + threadIdx.x;
  const float* zp = ty == 0 ? zp0 : (ty == 1 ? zp1 : zp2);
  int G = ty == 0 ? G0 : (ty == 1 ? G1 : G2);
  float sc = ty == 0 ? s0 : (ty == 1 ? s1 : s2);
  float a[16];
#pragma unroll
  for (int u = 0; u < 16; ++u) a[u] = 0.f;
  int g = 0;
  for (; g + 16 <= G; g += 16) {
#pragma unroll
    for (int u = 0; u < 16; ++u) a[u] += zp[(long)(g + u) * 8192 + i];
  }
  for (; g < G; ++g) a[0] += zp[(long)g * 8192 + i];
  float s = (((a[0] + a[1]) + (a[2] + a[3])) + ((a[4] + a[5]) + (a[6] + a[7])))
          + (((a[8] + a[9]) + (a[10] + a[11])) + ((a[12] + a[13]) + (a[14] + a[15])));
  zpre[ty * 8192 + i] = s * sc;
}

// ---------------------------------------------------------------------------
// Final LayerNorm over zpre[3*64,128] -> f32 out. 1 wave/row.
// ---------------------------------------------------------------------------
__global__ __launch_bounds__(256) void final_ln(
    const float* __restrict__ zpre, const float* __restrict__ gam,
    const float* __restrict__ bet, float* __restrict__ out)
{
  int row = blockIdx.x * 4 + (threadIdx.x >> 6);
  int lane = threadIdx.x & 63;
  if (row >= 192) return;
  int ty = row >> 6;
  long base = (long)row * 128;
  float x0 = zpre[base + lane], x1 = zpre[base + 64 + lane];
  float s = x0 + x1;
#pragma unroll
  for (int o = 32; o > 0; o >>= 1) s += __shfl_xor(s, o);
  float mu = s * 0.0078125f;
  float d0 = x0 - mu, d1 = x1 - mu;
  float q = d0 * d0 + d1 * d1;
#pragma unroll
  for (int o = 32; o > 0; o >>= 1) q += __shfl_xor(q, o);
  float r = rsqrtf(q * 0.0078125f + 1e-5f);
  out[base + lane]      = d0 * r * gam[ty * 128 + lane]      + bet[ty * 128 + lane];
  out[base + 64 + lane] = d1 * r * gam[ty * 128 + 64 + lane] + bet[ty * 128 + 64 + lane];
}

// ---------------------------------------------------------------------------
extern "C" void kernel_launch(void* const* d_in, const int* in_sizes, int n_in,
                              void* d_out, int out_size, void* d_ws, size_t ws_size,
                              hipStream_t stream)
{
  const float* batchp[3] = {(const float*)d_in[0], (const float*)d_in[1],
                            (const float*)d_in[2]};
  const float* emb[3] = {(const float*)d_in[3], (const float*)d_in[4],
                         (const float*)d_in[5]};
  const float* Wl   = (const float*)d_in[6];
  const float* Wr   = (const float*)d_in[7];
  const float* att  = (const float*)d_in[8];
  const float* bias = (const float*)d_in[9];
  const float* lng  = (const float*)d_in[10];
  const float* lnb  = (const float*)d_in[11];
  const float* outg = (const float*)d_in[12];
  const float* outb = (const float*)d_in[13];
  const int* eiP[8]; int E[8];
  for (int t = 0; t < 8; ++t) { eiP[t] = (const int*)d_in[14 + t]; E[t] = in_sizes[14 + t] / 2; }
  int Nn[3] = {in_sizes[3] / 128, in_sizes[4] / 128, in_sizes[5] / 128};
  int maxN = Nn[0] > Nn[1] ? Nn[0] : Nn[1]; if (Nn[2] > maxN) maxN = Nn[2];
  long Ntot = (long)Nn[0] + Nn[1] + Nn[2];

  const int SI[5] = {1, 0, 2, 0, 0};
  const int DI[5] = {0, 1, 0, 2, 0};
  const int TMASK[3] = {0x35, 0x42, 0x88};  // gene: t0,t2,t4,t5; cpg: t1,t6; mirna: t3,t7

  char* p = (char*)d_ws;
  auto carve = [&](size_t b) -> void* {
    void* r = (void*)p; p += (b + 255) & ~(size_t)255; return r;
  };
  float* xf[3];
  for (int ty = 0; ty < 3; ++ty) xf[ty] = (float*)carve((size_t)Nn[ty] * 128 * 4);
  float* aggAll = (float*)carve((size_t)Ntot * 128 * 4);
  float* agg[3] = {aggAll, aggAll + (long)Nn[0] * 128, aggAll + ((long)Nn[0] + Nn[1]) * 128};
  float* hsb = (float*)carve((size_t)maxN * 128 * 4);
  float* hdb = (float*)carve((size_t)maxN * 128 * 4);
  float* zpre = (float*)carve(3 * 64 * 128 * 4);

  // CSR (deg/cursor regions contiguous for one memset)
  EdgeArgs ea;
  long degTot = 0;
  for (int t = 0; t < 5; ++t) degTot += Nn[DI[t]];
  int* degAll = (int*)carve(degTot * 4);
  {
    int* dp = degAll;
    int boff = 0;
    for (int t = 0; t < 5; ++t) {
      int nd = Nn[DI[t]];
      ea.src[t] = eiP[t];
      ea.dst[t] = eiP[t] + E[t];
      ea.cur[t] = dp; dp += nd;
      ea.rs[t] = (int*)carve((size_t)(nd + 1) * 4);
      ea.csrc[t] = (int*)carve((size_t)E[t] * 4);
      ea.E[t] = E[t];
      ea.Nd[t] = nd;
      ea.blkOff[t] = boff;
      boff += (E[t] + 255) / 256;
      if (t == 4) ea.blkOff[5] = boff;
    }
  }
  if ((size_t)(p - (char*)d_ws) > ws_size) return;  // workspace too small

  // zgemm partials alias hsb+hdb (dead after the layer loop)
  int nch[3];
  for (int ty = 0; ty < 3; ++ty) nch[ty] = (Nn[ty] + 63) / 64;
  float* zp[3];
  zp[0] = hsb;
  zp[1] = zp[0] + (long)nch[0] * 8192;
  zp[2] = zp[1] + (long)nch[1] * 8192;

  auto WlP = [&](int l, int t) { return Wl + ((long)(l * 8 + t) << 14); };
  auto WrP = [&](int l, int t) { return Wr + ((long)(l * 8 + t) << 14); };

  // 1) build CSR for the 5 real edge types (3 launches)
  hipMemsetAsync(degAll, 0, degTot * 4, stream);
  hist_all<<<ea.blkOff[5], 256, 0, stream>>>(ea);
  scan_all<<<5, 1024, 0, stream>>>(ea);
  fill_all<<<ea.blkOff[5], 256, 0, stream>>>(ea);

  for (int l = 0; l < 2; ++l) {
    const float* xin[3] = {l == 0 ? emb[0] : xf[0],
                           l == 0 ? emb[1] : xf[1],
                           l == 0 ? emb[2] : xf[2]};
    for (int t = 0; t < 5; ++t) {
      int si = SI[t], di = DI[t];
      ProjJob A = {xin[si], WlP(l, t), hsb, Nn[si]};
      ProjJob B = {xin[di], WrP(l, t), hdb, Nn[di]};
      int split = (Nn[si] + 63) / 64;
      int nblk = split + (Nn[di] + 63) / 64;
      proj_pair<<<nblk, 256, 0, stream>>>(A, B, split);
      const float* attp = att + (long)(l * 8 + t) * 128;
      int gblk = (Nn[di] + 3) / 4;
      if (t == 0 || t == 1 || t == 3)   // first writer of gene/cpg/mirna agg
        gat_gather<true><<<gblk, 256, 0, stream>>>(
            ea.rs[t], ea.csrc[t], hsb, hdb, attp, agg[di], Nn[di]);
      else
        gat_gather<false><<<gblk, 256, 0, stream>>>(
            ea.rs[t], ea.csrc[t], hsb, hdb, attp, agg[di], Nn[di]);
    }
    {  // self-loop convs: agg += x @ Wl (alpha == 1), one launch
      ProjJob j0 = {xin[0], WlP(l, 5), agg[0], Nn[0]};
      ProjJob j1 = {xin[1], WlP(l, 6), agg[1], Nn[1]};
      ProjJob j2 = {xin[2], WlP(l, 7), agg[2], Nn[2]};
      int s1 = (Nn[0] + 63) / 64;
      int s2 = s1 + (Nn[1] + 63) / 64;
      int nblk = s2 + (Nn[2] + 63) / 64;
      proj_self<<<nblk, 256, 0, stream>>>(j0, j1, j2, s1, s2);
    }
    for (int ty = 0; ty < 3; ++ty)
      update_ln<<<(Nn[ty] + 3) / 4, 256, 0, stream>>>(
          xin[ty], xf[ty], agg[ty], bias + (long)l * 8 * 128, TMASK[ty],
          lng + (long)(l * 3 + ty) * 128, lnb + (long)(l * 3 + ty) * 128, Nn[ty]);
  }

  // final: z = LN(batch @ x / sqrt(N)) via one-chunk-per-block partials + reduce
  for (int ty = 0; ty < 3; ++ty)
    zgemm_part<<<nch[ty], 256, 0, stream>>>(batchp[ty], xf[ty], zp[ty], Nn[ty]);
  zreduce<<<96, 256, 0, stream>>>(
      zp[0], zp[1], zp[2], nch[0], nch[1], nch[2],
      (float)(1.0 / sqrt((double)Nn[0])), (float)(1.0 / sqrt((double)Nn[1])),
      (float)(1.0 / sqrt((double)Nn[2])), zpre);
  final_ln<<<48, 256, 0, stream>>>(zpre, outg, outb, (float*)d_out);
}

// Round 8
// 1170.636 us; speedup vs baseline: 1.7736x; 1.1061x over previous
//
#include <hip/hip_runtime.h>
#include <math.h>

__device__ __forceinline__ float b2f(unsigned short u) {
  return __uint_as_float(((unsigned)u) << 16);
}
__device__ __forceinline__ unsigned short f2b(float f) {
  unsigned x = __float_as_uint(f);
  unsigned r = (x + 0x7FFFu + ((x >> 16) & 1u)) >> 16;
  return (unsigned short)r;
}

struct ProjJob { const float* x; const float* W; void* out; int N; };

// ---------------------------------------------------------------------------
// Proj tile body: out[64,128] op= x[64,128] @ W[128,128] (W row-major [k][c]).
// Per thread 8 rows x 4 cols. W loads coalesced; x LDS reads broadcast.
// MODE: 0 = store f32, 1 = accumulate f32, 2 = store bf16 (packed ushort4).
// ---------------------------------------------------------------------------
template<int MODE>
__device__ __forceinline__ void proj_tile(
    float (*xs)[128], const float* __restrict__ xg, const float* __restrict__ Wg,
    void* __restrict__ outv, int N, long r0, int tid)
{
  for (int i = tid; i < 2048; i += 256) {   // 64 rows x 32 float4
    int r = i >> 5, c4 = (i & 31) << 2;
    float4 v = {0.f, 0.f, 0.f, 0.f};
    if (r0 + r < N) v = *(const float4*)(xg + (r0 + r) * 128 + c4);
    *(float4*)&xs[r][c4] = v;
  }
  __syncthreads();
  const int rb = (tid >> 5) * 8, cb = (tid & 31) * 4;
  float acc[8][4] = {};
  for (int kc = 0; kc < 32; ++kc) {
    int k = kc << 2;
    float4 w0 = *(const float4*)(Wg + (k + 0) * 128 + cb);
    float4 w1 = *(const float4*)(Wg + (k + 1) * 128 + cb);
    float4 w2 = *(const float4*)(Wg + (k + 2) * 128 + cb);
    float4 w3 = *(const float4*)(Wg + (k + 3) * 128 + cb);
#pragma unroll
    for (int r = 0; r < 8; ++r) {
      float4 xv = *(const float4*)&xs[rb + r][k];
      acc[r][0] = fmaf(xv.x, w0.x, fmaf(xv.y, w1.x, fmaf(xv.z, w2.x, fmaf(xv.w, w3.x, acc[r][0]))));
      acc[r][1] = fmaf(xv.x, w0.y, fmaf(xv.y, w1.y, fmaf(xv.z, w2.y, fmaf(xv.w, w3.y, acc[r][1]))));
      acc[r][2] = fmaf(xv.x, w0.z, fmaf(xv.y, w1.z, fmaf(xv.z, w2.z, fmaf(xv.w, w3.z, acc[r][2]))));
      acc[r][3] = fmaf(xv.x, w0.w, fmaf(xv.y, w1.w, fmaf(xv.z, w2.w, fmaf(xv.w, w3.w, acc[r][3]))));
    }
  }
#pragma unroll
  for (int r = 0; r < 8; ++r) {
    long row = r0 + rb + r;
    if (row < N) {
      if (MODE == 2) {
        unsigned short* op = (unsigned short*)outv + row * 128 + cb;
        ushort4 v = {f2b(acc[r][0]), f2b(acc[r][1]), f2b(acc[r][2]), f2b(acc[r][3])};
        *(ushort4*)op = v;
      } else {
        float* op = (float*)outv + row * 128 + cb;
        if (MODE == 1) {
          float4 cur = *(const float4*)op;
          cur.x += acc[r][0]; cur.y += acc[r][1];
          cur.z += acc[r][2]; cur.w += acc[r][3];
          *(float4*)op = cur;
        } else {
          float4 v = {acc[r][0], acc[r][1], acc[r][2], acc[r][3]};
          *(float4*)op = v;
        }
      }
    }
  }
}

// hs (bf16) + hd (f32) projections for one edge type in a single launch.
__global__ __launch_bounds__(256) void proj_pair(ProjJob a, ProjJob b, int split)
{
  __shared__ __align__(16) float xs[64][128];
  int blk = blockIdx.x;
  if (blk < split)
    proj_tile<2>(xs, a.x, a.W, a.out, a.N, (long)blk * 64, threadIdx.x);
  else
    proj_tile<0>(xs, b.x, b.W, b.out, b.N, (long)(blk - split) * 64, threadIdx.x);
}

// 3 self-loop convs (agg += x @ Wl) in a single launch.
__global__ __launch_bounds__(256) void proj_self(
    ProjJob j0, ProjJob j1, ProjJob j2, int s1, int s2)
{
  __shared__ __align__(16) float xs[64][128];
  int blk = blockIdx.x;
  if (blk < s1)
    proj_tile<1>(xs, j0.x, j0.W, j0.out, j0.N, (long)blk * 64, threadIdx.x);
  else if (blk < s2)
    proj_tile<1>(xs, j1.x, j1.W, j1.out, j1.N, (long)(blk - s1) * 64, threadIdx.x);
  else
    proj_tile<1>(xs, j2.x, j2.W, j2.out, j2.N, (long)(blk - s2) * 64, threadIdx.x);
}

// ---------------------------------------------------------------------------
// Batched CSR build over all 5 edge types (3 launches total).
// ---------------------------------------------------------------------------
struct EdgeArgs {
  const int* src[5]; const int* dst[5];
  int* cur[5];         // degree, then cursor (aliased)
  int* rs[5];          // row_start[nd+1]
  int* csrc[5];
  int E[5]; int Nd[5];
  int blkOff[6];       // block-range per type for hist/fill grids
};

__global__ __launch_bounds__(256) void hist_all(EdgeArgs a)
{
  int blk = blockIdx.x, t = 0;
  while (blk >= a.blkOff[t + 1]) ++t;
  int e = (blk - a.blkOff[t]) * 256 + threadIdx.x;
  if (e < a.E[t]) atomicAdd(&a.cur[t][a.dst[t][e]], 1);
}

__global__ __launch_bounds__(1024) void scan_all(EdgeArgs a)
{
  int t = blockIdx.x;
  int n = a.Nd[t];
  int* deg = a.cur[t];
  int* rs = a.rs[t];
  __shared__ int tile[1024];
  __shared__ int sbase;
  int tid = threadIdx.x;
  if (tid == 0) sbase = 0;
  __syncthreads();
  for (int chunk = 0; chunk < n; chunk += 16384) {
    int idx0 = chunk + tid * 16;
    int v[16], sum = 0;
#pragma unroll
    for (int j = 0; j < 16; ++j) {
      v[j] = (idx0 + j < n) ? deg[idx0 + j] : 0;
      sum += v[j];
    }
    tile[tid] = sum;
    __syncthreads();
    for (int off = 1; off < 1024; off <<= 1) {   // Hillis-Steele inclusive
      int tv = (tid >= off) ? tile[tid - off] : 0;
      __syncthreads();
      tile[tid] += tv;
      __syncthreads();
    }
    int excl = sbase + ((tid > 0) ? tile[tid - 1] : 0);
#pragma unroll
    for (int j = 0; j < 16; ++j) {
      if (idx0 + j < n) { rs[idx0 + j] = excl; deg[idx0 + j] = excl; }
      excl += v[j];
    }
    __syncthreads();
    if (tid == 0) sbase += tile[1023];
    __syncthreads();
  }
  if (tid == 0) rs[n] = sbase;
}

__global__ __launch_bounds__(256) void fill_all(EdgeArgs a)
{
  int blk = blockIdx.x, t = 0;
  while (blk >= a.blkOff[t + 1]) ++t;
  int e = (blk - a.blkOff[t]) * 256 + threadIdx.x;
  if (e < a.E[t]) {
    int pos = atomicAdd(&a.cur[t][a.dst[t][e]], 1);
    a.csrc[t][pos] = a.src[t][e];
  }
}

// ---------------------------------------------------------------------------
// Fused GATv2 aggregate, one wave per dst row, 4-way edge unroll.
// hs is bf16-packed (256B/row): lane reads ushort2 (chans 2l,2l+1).
// agg[d] (=|+=) (sum_e a_e*hs[src_e])/(sum_e a_e+eps).
// ---------------------------------------------------------------------------
template<bool INIT>
__global__ __launch_bounds__(256) void gat_gather(
    const int* __restrict__ row_start, const int* __restrict__ csr_src,
    const unsigned short* __restrict__ hs, const float* __restrict__ hd,
    const float* __restrict__ att, float* __restrict__ agg, int Nd)
{
  int d = blockIdx.x * 4 + (threadIdx.x >> 6);
  if (d >= Nd) return;
  int lane = threadIdx.x & 63;
  float2 att2 = *(const float2*)(att + 2 * lane);
  float2 hd2 = *(const float2*)(hd + (long)d * 128 + 2 * lane);
  int beg = row_start[d], end = row_start[d + 1];
  float n0 = 0.f, n1 = 0.f, D = 0.f;
  int i = beg;
  for (; i + 3 < end; i += 4) {
    int s0 = csr_src[i], s1 = csr_src[i + 1];
    int s2 = csr_src[i + 2], s3 = csr_src[i + 3];
    ushort2 u0 = *((const ushort2*)(hs + (long)s0 * 128) + lane);
    ushort2 u1 = *((const ushort2*)(hs + (long)s1 * 128) + lane);
    ushort2 u2 = *((const ushort2*)(hs + (long)s2 * 128) + lane);
    ushort2 u3 = *((const ushort2*)(hs + (long)s3 * 128) + lane);
    float a0x = b2f(u0.x), a0y = b2f(u0.y);
    float a1x = b2f(u1.x), a1y = b2f(u1.y);
    float a2x = b2f(u2.x), a2y = b2f(u2.y);
    float a3x = b2f(u3.x), a3y = b2f(u3.y);
    float v0x = a0x + hd2.x, v0y = a0y + hd2.y;
    float v1x = a1x + hd2.x, v1y = a1y + hd2.y;
    float v2x = a2x + hd2.x, v2y = a2y + hd2.y;
    float v3x = a3x + hd2.x, v3y = a3y + hd2.y;
    v0x = fmaxf(v0x, 0.2f * v0x); v0y = fmaxf(v0y, 0.2f * v0y);
    v1x = fmaxf(v1x, 0.2f * v1x); v1y = fmaxf(v1y, 0.2f * v1y);
    v2x = fmaxf(v2x, 0.2f * v2x); v2y = fmaxf(v2y, 0.2f * v2y);
    v3x = fmaxf(v3x, 0.2f * v3x); v3y = fmaxf(v3y, 0.2f * v3y);
    float p0 = fmaf(v0x, att2.x, v0y * att2.y);
    float p1 = fmaf(v1x, att2.x, v1y * att2.y);
    float p2 = fmaf(v2x, att2.x, v2y * att2.y);
    float p3 = fmaf(v3x, att2.x, v3y * att2.y);
    p0 += __shfl_xor(p0, 1); p1 += __shfl_xor(p1, 1);
    p2 += __shfl_xor(p2, 1); p3 += __shfl_xor(p3, 1);
    p0 += __shfl_xor(p0, 2); p1 += __shfl_xor(p1, 2);
    p2 += __shfl_xor(p2, 2); p3 += __shfl_xor(p3, 2);
    p0 += __shfl_xor(p0, 4); p1 += __shfl_xor(p1, 4);
    p2 += __shfl_xor(p2, 4); p3 += __shfl_xor(p3, 4);
    float e0 = expf(fminf(p0, 60.f)), e1 = expf(fminf(p1, 60.f));
    float e2 = expf(fminf(p2, 60.f)), e3 = expf(fminf(p3, 60.f));
    n0 = fmaf(e0, a0x, n0); n1 = fmaf(e0, a0y, n1); D += e0;
    n0 = fmaf(e1, a1x, n0); n1 = fmaf(e1, a1y, n1); D += e1;
    n0 = fmaf(e2, a2x, n0); n1 = fmaf(e2, a2y, n1); D += e2;
    n0 = fmaf(e3, a3x, n0); n1 = fmaf(e3, a3y, n1); D += e3;
  }
  for (; i < end; ++i) {
    int s = csr_src[i];
    ushort2 u = *((const ushort2*)(hs + (long)s * 128) + lane);
    float hx = b2f(u.x), hy = b2f(u.y);
    float vx = hx + hd2.x, vy = hy + hd2.y;
    vx = fmaxf(vx, 0.2f * vx);
    vy = fmaxf(vy, 0.2f * vy);
    float pp = fmaf(vx, att2.x, vy * att2.y);
    pp += __shfl_xor(pp, 1);
    pp += __shfl_xor(pp, 2);
    pp += __shfl_xor(pp, 4);
    float a = expf(fminf(pp, 60.f));
    n0 = fmaf(a, hx, n0);
    n1 = fmaf(a, hy, n1);
    D += a;
  }
  float inv = 1.f / (D + 1e-16f);
  float* ap = agg + (long)d * 128 + 2 * lane;
  if (INIT) {
    float2 v = {n0 * inv, n1 * inv};
    *(float2*)ap = v;
  } else {
    float2 cur = *(const float2*)ap;
    cur.x += n0 * inv;
    cur.y += n1 * inv;
    *(float2*)ap = cur;
  }
}

// ---------------------------------------------------------------------------
// xf = LayerNorm(xin + elu(agg + sum_masked(bias)));  1 wave per row.
// ---------------------------------------------------------------------------
__global__ __launch_bounds__(256) void update_ln(
    const float* __restrict__ xin, float* __restrict__ xf,
    const float* __restrict__ agg, const float* __restrict__ biasl, int tmask,
    const float* __restrict__ gam, const float* __restrict__ bet, int N)
{
  int row = blockIdx.x * 4 + (threadIdx.x >> 6);
  int lane = threadIdx.x & 63;
  if (row >= N) return;
  float bs0 = 0.f, bs1 = 0.f;
#pragma unroll
  for (int t = 0; t < 8; ++t)
    if (tmask & (1 << t)) {
      bs0 += biasl[t * 128 + lane];
      bs1 += biasl[t * 128 + 64 + lane];
    }
  long base = (long)row * 128;
  float v0 = agg[base + lane] + bs0, v1 = agg[base + 64 + lane] + bs1;
  v0 = v0 > 0.f ? v0 : expf(v0) - 1.f;
  v1 = v1 > 0.f ? v1 : expf(v1) - 1.f;
  float x0 = xin[base + lane] + v0, x1 = xin[base + 64 + lane] + v1;
  float s = x0 + x1;
#pragma unroll
  for (int o = 32; o > 0; o >>= 1) s += __shfl_xor(s, o);
  float mu = s * 0.0078125f;
  float dd0 = x0 - mu, dd1 = x1 - mu;
  float q = dd0 * dd0 + dd1 * dd1;
#pragma unroll
  for (int o = 32; o > 0; o >>= 1) q += __shfl_xor(q, o);
  float r = rsqrtf(q * 0.0078125f + 1e-5f);
  xf[base + lane]      = dd0 * r * gam[lane]      + bet[lane];
  xf[base + 64 + lane] = dd1 * r * gam[64 + lane] + bet[64 + lane];
}

// ---------------------------------------------------------------------------
// zgemm stage 1: ONE 64-row n-chunk per block, non-atomic partial tiles.
// ---------------------------------------------------------------------------
__global__ __launch_bounds__(256) void zgemm_part(
    const float* __restrict__ batch, const float* __restrict__ x,
    float* __restrict__ zpart, int N)
{
  __shared__ __align__(16) float xl[64 * 128];
  __shared__ __align__(16) float bl[64 * 65];
  int tid = threadIdx.x;
  int n0 = blockIdx.x * 64;
  for (int i = tid; i < 64 * 128; i += 256) {
    int nn = i >> 7;
    xl[i] = (n0 + nn < N) ? x[(long)(n0 + nn) * 128 + (i & 127)] : 0.f;
  }
  for (int i = tid; i < 64 * 64; i += 256) {
    int b = i >> 6, nn = i & 63;
    bl[nn * 65 + b] = (n0 + nn < N) ? batch[(long)b * N + n0 + nn] : 0.f;
  }
  __syncthreads();
  int cg = (tid & 31) * 4;
  int bg = (tid >> 5) * 8;
  float acc[8][4] = {};
  for (int nn = 0; nn < 64; ++nn) {
    float4 xv = *(const float4*)(xl + nn * 128 + cg);
#pragma unroll
    for (int i = 0; i < 8; ++i) {
      float bv = bl[nn * 65 + bg + i];
      acc[i][0] = fmaf(bv, xv.x, acc[i][0]);
      acc[i][1] = fmaf(bv, xv.y, acc[i][1]);
      acc[i][2] = fmaf(bv, xv.z, acc[i][2]);
      acc[i][3] = fmaf(bv, xv.w, acc[i][3]);
    }
  }
  float* zp = zpart + (long)blockIdx.x * 8192;
#pragma unroll
  for (int i = 0; i < 8; ++i) {
    float4 v = {acc[i][0], acc[i][1], acc[i][2], acc[i][3]};
    *(float4*)(zp + (bg + i) * 128 + cg) = v;
  }
}

// ---------------------------------------------------------------------------
// zgemm stage 2: zpre[ty][i] = scale[ty] * sum_g zpart[ty][g][i]
// 16 independent accumulators -> 16 loads in flight per thread.
// ---------------------------------------------------------------------------
__global__ __launch_bounds__(256) void zreduce(
    const float* __restrict__ zp0, const float* __restrict__ zp1,
    const float* __restrict__ zp2, int G0, int G1, int G2,
    float s0, float s1, float s2, float* __restrict__ zpre)
{
  int blk = blockIdx.x;
  int ty = blk >> 5;
  int i = (blk & 31) * 256 + threadIdx.x;
  const float* zp = ty == 0 ? zp0 : (ty == 1 ? zp1 : zp2);
  int G = ty == 0 ? G0 : (ty == 1 ? G1 : G2);
  float sc = ty == 0 ? s0 : (ty == 1 ? s1 : s2);
  float a[16];
#pragma unroll
  for (int u = 0; u < 16; ++u) a[u] = 0.f;
  int g = 0;
  for (; g + 16 <= G; g += 16) {
#pragma unroll
    for (int u = 0; u < 16; ++u) a[u] += zp[(long)(g + u) * 8192 + i];
  }
  for (; g < G; ++g) a[0] += zp[(long)g * 8192 + i];
  float s = (((a[0] + a[1]) + (a[2] + a[3])) + ((a[4] + a[5]) + (a[6] + a[7])))
          + (((a[8] + a[9]) + (a[10] + a[11])) + ((a[12] + a[13]) + (a[14] + a[15])));
  zpre[ty * 8192 + i] = s * sc;
}

// ---------------------------------------------------------------------------
// Final LayerNorm over zpre[3*64,128] -> f32 out. 1 wave/row.
// ---------------------------------------------------------------------------
__global__ __launch_bounds__(256) void final_ln(
    const float* __restrict__ zpre, const float* __restrict__ gam,
    const float* __restrict__ bet, float* __restrict__ out)
{
  int row = blockIdx.x * 4 + (threadIdx.x >> 6);
  int lane = threadIdx.x & 63;
  if (row >= 192) return;
  int ty = row >> 6;
  long base = (long)row * 128;
  float x0 = zpre[base + lane], x1 = zpre[base + 64 + lane];
  float s = x0 + x1;
#pragma unroll
  for (int o = 32; o > 0; o >>= 1) s += __shfl_xor(s, o);
  float mu = s * 0.0078125f;
  float d0 = x0 - mu, d1 = x1 - mu;
  float q = d0 * d0 + d1 * d1;
#pragma unroll
  for (int o = 32; o > 0; o >>= 1) q += __shfl_xor(q, o);
  float r = rsqrtf(q * 0.0078125f + 1e-5f);
  out[base + lane]      = d0 * r * gam[ty * 128 + lane]      + bet[ty * 128 + lane];
  out[base + 64 + lane] = d1 * r * gam[ty * 128 + 64 + lane] + bet[ty * 128 + 64 + lane];
}

// ---------------------------------------------------------------------------
extern "C" void kernel_launch(void* const* d_in, const int* in_sizes, int n_in,
                              void* d_out, int out_size, void* d_ws, size_t ws_size,
                              hipStream_t stream)
{
  const float* batchp[3] = {(const float*)d_in[0], (const float*)d_in[1],
                            (const float*)d_in[2]};
  const float* emb[3] = {(const float*)d_in[3], (const float*)d_in[4],
                         (const float*)d_in[5]};
  const float* Wl   = (const float*)d_in[6];
  const float* Wr   = (const float*)d_in[7];
  const float* att  = (const float*)d_in[8];
  const float* bias = (const float*)d_in[9];
  const float* lng  = (const float*)d_in[10];
  const float* lnb  = (const float*)d_in[11];
  const float* outg = (const float*)d_in[12];
  const float* outb = (const float*)d_in[13];
  const int* eiP[8]; int E[8];
  for (int t = 0; t < 8; ++t) { eiP[t] = (const int*)d_in[14 + t]; E[t] = in_sizes[14 + t] / 2; }
  int Nn[3] = {in_sizes[3] / 128, in_sizes[4] / 128, in_sizes[5] / 128};
  int maxN = Nn[0] > Nn[1] ? Nn[0] : Nn[1]; if (Nn[2] > maxN) maxN = Nn[2];
  long Ntot = (long)Nn[0] + Nn[1] + Nn[2];

  const int SI[5] = {1, 0, 2, 0, 0};
  const int DI[5] = {0, 1, 0, 2, 0};
  const int TMASK[3] = {0x35, 0x42, 0x88};  // gene: t0,t2,t4,t5; cpg: t1,t6; mirna: t3,t7

  char* p = (char*)d_ws;
  auto carve = [&](size_t b) -> void* {
    void* r = (void*)p; p += (b + 255) & ~(size_t)255; return r;
  };
  float* xf[3];
  for (int ty = 0; ty < 3; ++ty) xf[ty] = (float*)carve((size_t)Nn[ty] * 128 * 4);
  float* aggAll = (float*)carve((size_t)Ntot * 128 * 4);
  float* agg[3] = {aggAll, aggAll + (long)Nn[0] * 128, aggAll + ((long)Nn[0] + Nn[1]) * 128};
  unsigned short* hsb = (unsigned short*)carve((size_t)maxN * 128 * 2);  // bf16
  float* hdb = (float*)carve((size_t)maxN * 128 * 4);
  float* zpre = (float*)carve(3 * 64 * 128 * 4);

  // CSR (deg/cursor regions contiguous for one memset)
  EdgeArgs ea;
  long degTot = 0;
  for (int t = 0; t < 5; ++t) degTot += Nn[DI[t]];
  int* degAll = (int*)carve(degTot * 4);
  {
    int* dp = degAll;
    int boff = 0;
    for (int t = 0; t < 5; ++t) {
      int nd = Nn[DI[t]];
      ea.src[t] = eiP[t];
      ea.dst[t] = eiP[t] + E[t];
      ea.cur[t] = dp; dp += nd;
      ea.rs[t] = (int*)carve((size_t)(nd + 1) * 4);
      ea.csrc[t] = (int*)carve((size_t)E[t] * 4);
      ea.E[t] = E[t];
      ea.Nd[t] = nd;
      ea.blkOff[t] = boff;
      boff += (E[t] + 255) / 256;
      if (t == 4) ea.blkOff[5] = boff;
    }
  }
  if ((size_t)(p - (char*)d_ws) > ws_size) return;  // workspace too small

  // zgemm partials alias hsb+hdb (dead after the layer loop):
  // sum(nch)*32KB (~41MB) <= maxN*128*(2+4) bytes (~46MB) ✓
  int nch[3];
  for (int ty = 0; ty < 3; ++ty) nch[ty] = (Nn[ty] + 63) / 64;
  float* zp[3];
  zp[0] = (float*)hsb;
  zp[1] = zp[0] + (long)nch[0] * 8192;
  zp[2] = zp[1] + (long)nch[1] * 8192;

  auto WlP = [&](int l, int t) { return Wl + ((long)(l * 8 + t) << 14); };
  auto WrP = [&](int l, int t) { return Wr + ((long)(l * 8 + t) << 14); };

  // 1) build CSR for the 5 real edge types (3 launches)
  hipMemsetAsync(degAll, 0, degTot * 4, stream);
  hist_all<<<ea.blkOff[5], 256, 0, stream>>>(ea);
  scan_all<<<5, 1024, 0, stream>>>(ea);
  fill_all<<<ea.blkOff[5], 256, 0, stream>>>(ea);

  for (int l = 0; l < 2; ++l) {
    const float* xin[3] = {l == 0 ? emb[0] : xf[0],
                           l == 0 ? emb[1] : xf[1],
                           l == 0 ? emb[2] : xf[2]};
    for (int t = 0; t < 5; ++t) {
      int si = SI[t], di = DI[t];
      ProjJob A = {xin[si], WlP(l, t), hsb, Nn[si]};
      ProjJob B = {xin[di], WrP(l, t), hdb, Nn[di]};
      int split = (Nn[si] + 63) / 64;
      int nblk = split + (Nn[di] + 63) / 64;
      proj_pair<<<nblk, 256, 0, stream>>>(A, B, split);
      const float* attp = att + (long)(l * 8 + t) * 128;
      int gblk = (Nn[di] + 3) / 4;
      if (t == 0 || t == 1 || t == 3)   // first writer of gene/cpg/mirna agg
        gat_gather<true><<<gblk, 256, 0, stream>>>(
            ea.rs[t], ea.csrc[t], hsb, hdb, attp, agg[di], Nn[di]);
      else
        gat_gather<false><<<gblk, 256, 0, stream>>>(
            ea.rs[t], ea.csrc[t], hsb, hdb, attp, agg[di], Nn[di]);
    }
    {  // self-loop convs: agg += x @ Wl (alpha == 1), one launch
      ProjJob j0 = {xin[0], WlP(l, 5), agg[0], Nn[0]};
      ProjJob j1 = {xin[1], WlP(l, 6), agg[1], Nn[1]};
      ProjJob j2 = {xin[2], WlP(l, 7), agg[2], Nn[2]};
      int s1 = (Nn[0] + 63) / 64;
      int s2 = s1 + (Nn[1] + 63) / 64;
      int nblk = s2 + (Nn[2] + 63) / 64;
      proj_self<<<nblk, 256, 0, stream>>>(j0, j1, j2, s1, s2);
    }
    for (int ty = 0; ty < 3; ++ty)
      update_ln<<<(Nn[ty] + 3) / 4, 256, 0, stream>>>(
          xin[ty], xf[ty], agg[ty], bias + (long)l * 8 * 128, TMASK[ty],
          lng + (long)(l * 3 + ty) * 128, lnb + (long)(l * 3 + ty) * 128, Nn[ty]);
  }

  // final: z = LN(batch @ x / sqrt(N)) via one-chunk-per-block partials + reduce
  for (int ty = 0; ty < 3; ++ty)
    zgemm_part<<<nch[ty], 256, 0, stream>>>(batchp[ty], xf[ty], zp[ty], Nn[ty]);
  zreduce<<<96, 256, 0, stream>>>(
      zp[0], zp[1], zp[2], nch[0], nch[1], nch[2],
      (float)(1.0 / sqrt((double)Nn[0])), (float)(1.0 / sqrt((double)Nn[1])),
      (float)(1.0 / sqrt((double)Nn[2])), zpre);
  final_ln<<<48, 256, 0, stream>>>(zpre, outg, outb, (float*)d_out);
}

// Round 9
// 984.487 us; speedup vs baseline: 2.1090x; 1.1891x over previous
//
#include <hip/hip_runtime.h>
#include <math.h>

__device__ __forceinline__ float b2f(unsigned short u) {
  return __uint_as_float(((unsigned)u) << 16);
}
__device__ __forceinline__ unsigned short f2b(float f) {
  unsigned x = __float_as_uint(f);
  unsigned r = (x + 0x7FFFu + ((x >> 16) & 1u)) >> 16;
  return (unsigned short)r;
}

struct ProjJob { const float* x; const float* W; void* out; int N; };

// ---------------------------------------------------------------------------
// Proj tile body: out[64,128] op= x[64,128] @ W[128,128] (W row-major [k][c]).
// Per thread 8 rows x 4 cols. W loads coalesced; x LDS reads broadcast.
// MODE: 0 = store f32, 1 = accumulate f32, 2 = store bf16 (packed ushort4).
// ---------------------------------------------------------------------------
template<int MODE>
__device__ __forceinline__ void proj_tile(
    float (*xs)[128], const float* __restrict__ xg, const float* __restrict__ Wg,
    void* __restrict__ outv, int N, long r0, int tid)
{
  for (int i = tid; i < 2048; i += 256) {   // 64 rows x 32 float4
    int r = i >> 5, c4 = (i & 31) << 2;
    float4 v = {0.f, 0.f, 0.f, 0.f};
    if (r0 + r < N) v = *(const float4*)(xg + (r0 + r) * 128 + c4);
    *(float4*)&xs[r][c4] = v;
  }
  __syncthreads();
  const int rb = (tid >> 5) * 8, cb = (tid & 31) * 4;
  float acc[8][4] = {};
  for (int kc = 0; kc < 32; ++kc) {
    int k = kc << 2;
    float4 w0 = *(const float4*)(Wg + (k + 0) * 128 + cb);
    float4 w1 = *(const float4*)(Wg + (k + 1) * 128 + cb);
    float4 w2 = *(const float4*)(Wg + (k + 2) * 128 + cb);
    float4 w3 = *(const float4*)(Wg + (k + 3) * 128 + cb);
#pragma unroll
    for (int r = 0; r < 8; ++r) {
      float4 xv = *(const float4*)&xs[rb + r][k];
      acc[r][0] = fmaf(xv.x, w0.x, fmaf(xv.y, w1.x, fmaf(xv.z, w2.x, fmaf(xv.w, w3.x, acc[r][0]))));
      acc[r][1] = fmaf(xv.x, w0.y, fmaf(xv.y, w1.y, fmaf(xv.z, w2.y, fmaf(xv.w, w3.y, acc[r][1]))));
      acc[r][2] = fmaf(xv.x, w0.z, fmaf(xv.y, w1.z, fmaf(xv.z, w2.z, fmaf(xv.w, w3.z, acc[r][2]))));
      acc[r][3] = fmaf(xv.x, w0.w, fmaf(xv.y, w1.w, fmaf(xv.z, w2.w, fmaf(xv.w, w3.w, acc[r][3]))));
    }
  }
#pragma unroll
  for (int r = 0; r < 8; ++r) {
    long row = r0 + rb + r;
    if (row < N) {
      if (MODE == 2) {
        unsigned short* op = (unsigned short*)outv + row * 128 + cb;
        ushort4 v = {f2b(acc[r][0]), f2b(acc[r][1]), f2b(acc[r][2]), f2b(acc[r][3])};
        *(ushort4*)op = v;
      } else {
        float* op = (float*)outv + row * 128 + cb;
        if (MODE == 1) {
          float4 cur = *(const float4*)op;
          cur.x += acc[r][0]; cur.y += acc[r][1];
          cur.z += acc[r][2]; cur.w += acc[r][3];
          *(float4*)op = cur;
        } else {
          float4 v = {acc[r][0], acc[r][1], acc[r][2], acc[r][3]};
          *(float4*)op = v;
        }
      }
    }
  }
}

// hs (bf16) + hd (f32) projections for one edge type in a single launch.
__global__ __launch_bounds__(256) void proj_pair(ProjJob a, ProjJob b, int split)
{
  __shared__ __align__(16) float xs[64][128];
  int blk = blockIdx.x;
  if (blk < split)
    proj_tile<2>(xs, a.x, a.W, a.out, a.N, (long)blk * 64, threadIdx.x);
  else
    proj_tile<0>(xs, b.x, b.W, b.out, b.N, (long)(blk - split) * 64, threadIdx.x);
}

// 3 self-loop convs (agg += x @ Wl) in a single launch.
__global__ __launch_bounds__(256) void proj_self(
    ProjJob j0, ProjJob j1, ProjJob j2, int s1, int s2)
{
  __shared__ __align__(16) float xs[64][128];
  int blk = blockIdx.x;
  if (blk < s1)
    proj_tile<1>(xs, j0.x, j0.W, j0.out, j0.N, (long)blk * 64, threadIdx.x);
  else if (blk < s2)
    proj_tile<1>(xs, j1.x, j1.W, j1.out, j1.N, (long)(blk - s1) * 64, threadIdx.x);
  else
    proj_tile<1>(xs, j2.x, j2.W, j2.out, j2.N, (long)(blk - s2) * 64, threadIdx.x);
}

// ---------------------------------------------------------------------------
// Atomic-free bucketed CSR build (bucket = 128 dst nodes, 4096 edges/block).
// Packing: tmp = (dstLocal<<16) | src   (requires node ids < 65536).
// ---------------------------------------------------------------------------
struct BArgs {
  const int* src[5]; const int* dst[5];
  int* cnt[5];       // [B][NB] counts -> exclusive scan (bucket-major)
  int* tmp[5];       // E packed (dstLocal<<16 | src), bucket-sorted
  int* rs[5];        // row_start[Nd+1]
  int* csrc[5];      // E src ids, dst-sorted
  int E[5], Nd[5], NB[5], B[5];
  int cOff[6];       // block offsets for count/scatter grids (cumsum NB)
  int fOff[6];       // block offsets for finalize grid (cumsum B)
};

__global__ __launch_bounds__(256) void bucket_count(BArgs a)
{
  __shared__ int h[512];
  int blk = blockIdx.x, t = 0;
  while (blk >= a.cOff[t + 1]) ++t;
  int lb = blk - a.cOff[t];
  int B = a.B[t], NB = a.NB[t], E = a.E[t];
  for (int i = threadIdx.x; i < B; i += 256) h[i] = 0;
  __syncthreads();
  const int* dst = a.dst[t];
  int base = lb * 4096;
#pragma unroll
  for (int j = 0; j < 16; ++j) {
    int e = base + j * 256 + threadIdx.x;
    if (e < E) atomicAdd(&h[dst[e] >> 7], 1);   // LDS atomic (workgroup scope)
  }
  __syncthreads();
  int* cnt = a.cnt[t];
  for (int b = threadIdx.x; b < B; b += 256) cnt[b * NB + lb] = h[b];
}

__global__ __launch_bounds__(1024) void bucket_scan(BArgs a)
{
  int t = blockIdx.x;
  int n = a.B[t] * a.NB[t];
  int* dp = a.cnt[t];
  __shared__ int tile[1024];
  __shared__ int sbase;
  int tid = threadIdx.x;
  if (tid == 0) sbase = 0;
  __syncthreads();
  for (int chunk = 0; chunk < n; chunk += 16384) {
    int idx0 = chunk + tid * 16;
    int v[16], sum = 0;
#pragma unroll
    for (int j = 0; j < 16; ++j) {
      v[j] = (idx0 + j < n) ? dp[idx0 + j] : 0;
      sum += v[j];
    }
    tile[tid] = sum;
    __syncthreads();
    for (int off = 1; off < 1024; off <<= 1) {
      int tv = (tid >= off) ? tile[tid - off] : 0;
      __syncthreads();
      tile[tid] += tv;
      __syncthreads();
    }
    int excl = sbase + ((tid > 0) ? tile[tid - 1] : 0);
#pragma unroll
    for (int j = 0; j < 16; ++j) {
      if (idx0 + j < n) dp[idx0 + j] = excl;
      excl += v[j];
    }
    __syncthreads();
    if (tid == 0) sbase += tile[1023];
    __syncthreads();
  }
}

__global__ __launch_bounds__(256) void bucket_scatter(BArgs a)
{
  __shared__ int cur[512];
  int blk = blockIdx.x, t = 0;
  while (blk >= a.cOff[t + 1]) ++t;
  int lb = blk - a.cOff[t];
  int B = a.B[t], NB = a.NB[t], E = a.E[t];
  const int* cnt = a.cnt[t];
  for (int b = threadIdx.x; b < B; b += 256) cur[b] = cnt[b * NB + lb];
  __syncthreads();
  const int* src = a.src[t];
  const int* dst = a.dst[t];
  int* tmp = a.tmp[t];
  int base = lb * 4096;
#pragma unroll
  for (int j = 0; j < 16; ++j) {
    int e = base + j * 256 + threadIdx.x;
    if (e < E) {
      int dv = dst[e];
      int pos = atomicAdd(&cur[dv >> 7], 1);    // LDS atomic
      tmp[pos] = ((dv & 127) << 16) | src[e];
    }
  }
}

__global__ __launch_bounds__(256) void bucket_finalize(BArgs a)
{
  __shared__ int h[128], sc[128], ex[128], cur[128];
  int blk = blockIdx.x, t = 0;
  while (blk >= a.fOff[t + 1]) ++t;
  int b = blk - a.fOff[t];
  int B = a.B[t], NB = a.NB[t], E = a.E[t], Nd = a.Nd[t];
  const int* cnt = a.cnt[t];
  const int* tmp = a.tmp[t];
  int* rs = a.rs[t];
  int* csrc = a.csrc[t];
  int tid = threadIdx.x;
  int beg = cnt[b * NB];
  int end = (b + 1 < B) ? cnt[(b + 1) * NB] : E;
  if (tid < 128) h[tid] = 0;
  __syncthreads();
  for (int i = beg + tid; i < end; i += 256)
    atomicAdd(&h[tmp[i] >> 16], 1);             // LDS atomic
  __syncthreads();
  if (tid < 128) sc[tid] = h[tid];
  __syncthreads();
#pragma unroll
  for (int off = 1; off < 128; off <<= 1) {
    int v = (tid < 128 && tid >= off) ? sc[tid - off] : 0;
    __syncthreads();
    if (tid < 128) sc[tid] += v;
    __syncthreads();
  }
  if (tid < 128) {
    ex[tid] = sc[tid] - h[tid];
    cur[tid] = 0;
    int dg = b * 128 + tid;
    if (dg < Nd) rs[dg] = beg + ex[tid];
  }
  if (b == B - 1 && tid == 0) rs[Nd] = E;
  __syncthreads();
  for (int i = beg + tid; i < end; i += 256) {
    int v = tmp[i];
    int d = v >> 16;
    int r = atomicAdd(&cur[d], 1);              // LDS atomic
    csrc[beg + ex[d] + r] = v & 0xFFFF;
  }
}

// ---------------------------------------------------------------------------
// Fused GATv2 aggregate, one wave per dst row, 4-way edge unroll.
// hs is bf16-packed (256B/row): lane reads ushort2 (chans 2l,2l+1).
// agg[d] (=|+=) (sum_e a_e*hs[src_e])/(sum_e a_e+eps).
// ---------------------------------------------------------------------------
template<bool INIT>
__global__ __launch_bounds__(256) void gat_gather(
    const int* __restrict__ row_start, const int* __restrict__ csr_src,
    const unsigned short* __restrict__ hs, const float* __restrict__ hd,
    const float* __restrict__ att, float* __restrict__ agg, int Nd)
{
  int d = blockIdx.x * 4 + (threadIdx.x >> 6);
  if (d >= Nd) return;
  int lane = threadIdx.x & 63;
  float2 att2 = *(const float2*)(att + 2 * lane);
  float2 hd2 = *(const float2*)(hd + (long)d * 128 + 2 * lane);
  int beg = row_start[d], end = row_start[d + 1];
  float n0 = 0.f, n1 = 0.f, D = 0.f;
  int i = beg;
  for (; i + 3 < end; i += 4) {
    int s0 = csr_src[i], s1 = csr_src[i + 1];
    int s2 = csr_src[i + 2], s3 = csr_src[i + 3];
    ushort2 u0 = *((const ushort2*)(hs + (long)s0 * 128) + lane);
    ushort2 u1 = *((const ushort2*)(hs + (long)s1 * 128) + lane);
    ushort2 u2 = *((const ushort2*)(hs + (long)s2 * 128) + lane);
    ushort2 u3 = *((const ushort2*)(hs + (long)s3 * 128) + lane);
    float a0x = b2f(u0.x), a0y = b2f(u0.y);
    float a1x = b2f(u1.x), a1y = b2f(u1.y);
    float a2x = b2f(u2.x), a2y = b2f(u2.y);
    float a3x = b2f(u3.x), a3y = b2f(u3.y);
    float v0x = a0x + hd2.x, v0y = a0y + hd2.y;
    float v1x = a1x + hd2.x, v1y = a1y + hd2.y;
    float v2x = a2x + hd2.x, v2y = a2y + hd2.y;
    float v3x = a3x + hd2.x, v3y = a3y + hd2.y;
    v0x = fmaxf(v0x, 0.2f * v0x); v0y = fmaxf(v0y, 0.2f * v0y);
    v1x = fmaxf(v1x, 0.2f * v1x); v1y = fmaxf(v1y, 0.2f * v1y);
    v2x = fmaxf(v2x, 0.2f * v2x); v2y = fmaxf(v2y, 0.2f * v2y);
    v3x = fmaxf(v3x, 0.2f * v3x); v3y = fmaxf(v3y, 0.2f * v3y);
    float p0 = fmaf(v0x, att2.x, v0y * att2.y);
    float p1 = fmaf(v1x, att2.x, v1y * att2.y);
    float p2 = fmaf(v2x, att2.x, v2y * att2.y);
    float p3 = fmaf(v3x, att2.x, v3y * att2.y);
    p0 += __shfl_xor(p0, 1); p1 += __shfl_xor(p1, 1);
    p2 += __shfl_xor(p2, 1); p3 += __shfl_xor(p3, 1);
    p0 += __shfl_xor(p0, 2); p1 += __shfl_xor(p1, 2);
    p2 += __shfl_xor(p2, 2); p3 += __shfl_xor(p3, 2);
    p0 += __shfl_xor(p0, 4); p1 += __shfl_xor(p1, 4);
    p2 += __shfl_xor(p2, 4); p3 += __shfl_xor(p3, 4);
    float e0 = expf(fminf(p0, 60.f)), e1 = expf(fminf(p1, 60.f));
    float e2 = expf(fminf(p2, 60.f)), e3 = expf(fminf(p3, 60.f));
    n0 = fmaf(e0, a0x, n0); n1 = fmaf(e0, a0y, n1); D += e0;
    n0 = fmaf(e1, a1x, n0); n1 = fmaf(e1, a1y, n1); D += e1;
    n0 = fmaf(e2, a2x, n0); n1 = fmaf(e2, a2y, n1); D += e2;
    n0 = fmaf(e3, a3x, n0); n1 = fmaf(e3, a3y, n1); D += e3;
  }
  for (; i < end; ++i) {
    int s = csr_src[i];
    ushort2 u = *((const ushort2*)(hs + (long)s * 128) + lane);
    float hx = b2f(u.x), hy = b2f(u.y);
    float vx = hx + hd2.x, vy = hy + hd2.y;
    vx = fmaxf(vx, 0.2f * vx);
    vy = fmaxf(vy, 0.2f * vy);
    float pp = fmaf(vx, att2.x, vy * att2.y);
    pp += __shfl_xor(pp, 1);
    pp += __shfl_xor(pp, 2);
    pp += __shfl_xor(pp, 4);
    float a = expf(fminf(pp, 60.f));
    n0 = fmaf(a, hx, n0);
    n1 = fmaf(a, hy, n1);
    D += a;
  }
  float inv = 1.f / (D + 1e-16f);
  float* ap = agg + (long)d * 128 + 2 * lane;
  if (INIT) {
    float2 v = {n0 * inv, n1 * inv};
    *(float2*)ap = v;
  } else {
    float2 cur = *(const float2*)ap;
    cur.x += n0 * inv;
    cur.y += n1 * inv;
    *(float2*)ap = cur;
  }
}

// ---------------------------------------------------------------------------
// xf = LayerNorm(xin + elu(agg + sum_masked(bias)));  1 wave per row.
// ---------------------------------------------------------------------------
__global__ __launch_bounds__(256) void update_ln(
    const float* __restrict__ xin, float* __restrict__ xf,
    const float* __restrict__ agg, const float* __restrict__ biasl, int tmask,
    const float* __restrict__ gam, const float* __restrict__ bet, int N)
{
  int row = blockIdx.x * 4 + (threadIdx.x >> 6);
  int lane = threadIdx.x & 63;
  if (row >= N) return;
  float bs0 = 0.f, bs1 = 0.f;
#pragma unroll
  for (int t = 0; t < 8; ++t)
    if (tmask & (1 << t)) {
      bs0 += biasl[t * 128 + lane];
      bs1 += biasl[t * 128 + 64 + lane];
    }
  long base = (long)row * 128;
  float v0 = agg[base + lane] + bs0, v1 = agg[base + 64 + lane] + bs1;
  v0 = v0 > 0.f ? v0 : expf(v0) - 1.f;
  v1 = v1 > 0.f ? v1 : expf(v1) - 1.f;
  float x0 = xin[base + lane] + v0, x1 = xin[base + 64 + lane] + v1;
  float s = x0 + x1;
#pragma unroll
  for (int o = 32; o > 0; o >>= 1) s += __shfl_xor(s, o);
  float mu = s * 0.0078125f;
  float dd0 = x0 - mu, dd1 = x1 - mu;
  float q = dd0 * dd0 + dd1 * dd1;
#pragma unroll
  for (int o = 32; o > 0; o >>= 1) q += __shfl_xor(q, o);
  float r = rsqrtf(q * 0.0078125f + 1e-5f);
  xf[base + lane]      = dd0 * r * gam[lane]      + bet[lane];
  xf[base + 64 + lane] = dd1 * r * gam[64 + lane] + bet[64 + lane];
}

// ---------------------------------------------------------------------------
// zgemm stage 1: ONE 64-row n-chunk per block, non-atomic partial tiles.
// ---------------------------------------------------------------------------
__global__ __launch_bounds__(256) void zgemm_part(
    const float* __restrict__ batch, const float* __restrict__ x,
    float* __restrict__ zpart, int N)
{
  __shared__ __align__(16) float xl[64 * 128];
  __shared__ __align__(16) float bl[64 * 65];
  int tid = threadIdx.x;
  int n0 = blockIdx.x * 64;
  for (int i = tid; i < 64 * 128; i += 256) {
    int nn = i >> 7;
    xl[i] = (n0 + nn < N) ? x[(long)(n0 + nn) * 128 + (i & 127)] : 0.f;
  }
  for (int i = tid; i < 64 * 64; i += 256) {
    int b = i >> 6, nn = i & 63;
    bl[nn * 65 + b] = (n0 + nn < N) ? batch[(long)b * N + n0 + nn] : 0.f;
  }
  __syncthreads();
  int cg = (tid & 31) * 4;
  int bg = (tid >> 5) * 8;
  float acc[8][4] = {};
  for (int nn = 0; nn < 64; ++nn) {
    float4 xv = *(const float4*)(xl + nn * 128 + cg);
#pragma unroll
    for (int i = 0; i < 8; ++i) {
      float bv = bl[nn * 65 + bg + i];
      acc[i][0] = fmaf(bv, xv.x, acc[i][0]);
      acc[i][1] = fmaf(bv, xv.y, acc[i][1]);
      acc[i][2] = fmaf(bv, xv.z, acc[i][2]);
      acc[i][3] = fmaf(bv, xv.w, acc[i][3]);
    }
  }
  float* zp = zpart + (long)blockIdx.x * 8192;
#pragma unroll
  for (int i = 0; i < 8; ++i) {
    float4 v = {acc[i][0], acc[i][1], acc[i][2], acc[i][3]};
    *(float4*)(zp + (bg + i) * 128 + cg) = v;
  }
}

// ---------------------------------------------------------------------------
// zgemm stage 2: zpre[ty][i] = scale[ty] * sum_g zpart[ty][g][i]
// 16 independent accumulators -> 16 loads in flight per thread.
// ---------------------------------------------------------------------------
__global__ __launch_bounds__(256) void zreduce(
    const float* __restrict__ zp0, const float* __restrict__ zp1,
    const float* __restrict__ zp2, int G0, int G1, int G2,
    float s0, float s1, float s2, float* __restrict__ zpre)
{
  int blk = blockIdx.x;
  int ty = blk >> 5;
  int i = (blk & 31) * 256 + threadIdx.x;
  const float* zp = ty == 0 ? zp0 : (ty == 1 ? zp1 : zp2);
  int G = ty == 0 ? G0 : (ty == 1 ? G1 : G2);
  float sc = ty == 0 ? s0 : (ty == 1 ? s1 : s2);
  float a[16];
#pragma unroll
  for (int u = 0; u < 16; ++u) a[u] = 0.f;
  int g = 0;
  for (; g + 16 <= G; g += 16) {
#pragma unroll
    for (int u = 0; u < 16; ++u) a[u] += zp[(long)(g + u) * 8192 + i];
  }
  for (; g < G; ++g) a[0] += zp[(long)g * 8192 + i];
  float s = (((a[0] + a[1]) + (a[2] + a[3])) + ((a[4] + a[5]) + (a[6] + a[7])))
          + (((a[8] + a[9]) + (a[10] + a[11])) + ((a[12] + a[13]) + (a[14] + a[15])));
  zpre[ty * 8192 + i] = s * sc;
}

// ---------------------------------------------------------------------------
// Final LayerNorm over zpre[3*64,128] -> f32 out. 1 wave/row.
// ---------------------------------------------------------------------------
__global__ __launch_bounds__(256) void final_ln(
    const float* __restrict__ zpre, const float* __restrict__ gam,
    const float* __restrict__ bet, float* __restrict__ out)
{
  int row = blockIdx.x * 4 + (threadIdx.x >> 6);
  int lane = threadIdx.x & 63;
  if (row >= 192) return;
  int ty = row >> 6;
  long base = (long)row * 128;
  float x0 = zpre[base + lane], x1 = zpre[base + 64 + lane];
  float s = x0 + x1;
#pragma unroll
  for (int o = 32; o > 0; o >>= 1) s += __shfl_xor(s, o);
  float mu = s * 0.0078125f;
  float d0 = x0 - mu, d1 = x1 - mu;
  float q = d0 * d0 + d1 * d1;
#pragma unroll
  for (int o = 32; o > 0; o >>= 1) q += __shfl_xor(q, o);
  float r = rsqrtf(q * 0.0078125f + 1e-5f);
  out[base + lane]      = d0 * r * gam[ty * 128 + lane]      + bet[ty * 128 + lane];
  out[base + 64 + lane] = d1 * r * gam[ty * 128 + 64 + lane] + bet[ty * 128 + 64 + lane];
}

// ---------------------------------------------------------------------------
extern "C" void kernel_launch(void* const* d_in, const int* in_sizes, int n_in,
                              void* d_out, int out_size, void* d_ws, size_t ws_size,
                              hipStream_t stream)
{
  const float* batchp[3] = {(const float*)d_in[0], (const float*)d_in[1],
                            (const float*)d_in[2]};
  const float* emb[3] = {(const float*)d_in[3], (const float*)d_in[4],
                         (const float*)d_in[5]};
  const float* Wl   = (const float*)d_in[6];
  const float* Wr   = (const float*)d_in[7];
  const float* att  = (const float*)d_in[8];
  const float* bias = (const float*)d_in[9];
  const float* lng  = (const float*)d_in[10];
  const float* lnb  = (const float*)d_in[11];
  const float* outg = (const float*)d_in[12];
  const float* outb = (const float*)d_in[13];
  const int* eiP[8]; int E[8];
  for (int t = 0; t < 8; ++t) { eiP[t] = (const int*)d_in[14 + t]; E[t] = in_sizes[14 + t] / 2; }
  int Nn[3] = {in_sizes[3] / 128, in_sizes[4] / 128, in_sizes[5] / 128};
  int maxN = Nn[0] > Nn[1] ? Nn[0] : Nn[1]; if (Nn[2] > maxN) maxN = Nn[2];
  long Ntot = (long)Nn[0] + Nn[1] + Nn[2];

  const int SI[5] = {1, 0, 2, 0, 0};
  const int DI[5] = {0, 1, 0, 2, 0};
  const int TMASK[3] = {0x35, 0x42, 0x88};  // gene: t0,t2,t4,t5; cpg: t1,t6; mirna: t3,t7

  char* p = (char*)d_ws;
  auto carve = [&](size_t b) -> void* {
    void* r = (void*)p; p += (b + 255) & ~(size_t)255; return r;
  };
  float* xf[3];
  for (int ty = 0; ty < 3; ++ty) xf[ty] = (float*)carve((size_t)Nn[ty] * 128 * 4);
  float* aggAll = (float*)carve((size_t)Ntot * 128 * 4);
  float* agg[3] = {aggAll, aggAll + (long)Nn[0] * 128, aggAll + ((long)Nn[0] + Nn[1]) * 128};
  unsigned short* hsb = (unsigned short*)carve((size_t)maxN * 128 * 2);  // bf16
  float* hdb = (float*)carve((size_t)maxN * 128 * 4);
  float* zpre = (float*)carve(3 * 64 * 128 * 4);

  // bucketed CSR build (no global atomics)
  BArgs ba;
  {
    int cOff = 0, fOff = 0;
    for (int t = 0; t < 5; ++t) {
      int nd = Nn[DI[t]];
      ba.src[t] = eiP[t];
      ba.dst[t] = eiP[t] + E[t];
      ba.E[t] = E[t];
      ba.Nd[t] = nd;
      ba.NB[t] = (E[t] + 4095) / 4096;
      ba.B[t] = (nd + 127) / 128;
      ba.cnt[t] = (int*)carve((size_t)ba.B[t] * ba.NB[t] * 4);
      ba.tmp[t] = (int*)carve((size_t)E[t] * 4);
      ba.rs[t] = (int*)carve((size_t)(nd + 1) * 4);
      ba.csrc[t] = (int*)carve((size_t)E[t] * 4);
      ba.cOff[t] = cOff; cOff += ba.NB[t];
      ba.fOff[t] = fOff; fOff += ba.B[t];
    }
    ba.cOff[5] = cOff;
    ba.fOff[5] = fOff;
  }
  if ((size_t)(p - (char*)d_ws) > ws_size) return;  // workspace too small

  // zgemm partials alias hsb+hdb (dead after the layer loop)
  int nch[3];
  for (int ty = 0; ty < 3; ++ty) nch[ty] = (Nn[ty] + 63) / 64;
  float* zp[3];
  zp[0] = (float*)hsb;
  zp[1] = zp[0] + (long)nch[0] * 8192;
  zp[2] = zp[1] + (long)nch[1] * 8192;

  auto WlP = [&](int l, int t) { return Wl + ((long)(l * 8 + t) << 14); };
  auto WrP = [&](int l, int t) { return Wr + ((long)(l * 8 + t) << 14); };

  // 1) build CSR for the 5 real edge types (4 launches, zero global atomics)
  bucket_count<<<ba.cOff[5], 256, 0, stream>>>(ba);
  bucket_scan<<<5, 1024, 0, stream>>>(ba);
  bucket_scatter<<<ba.cOff[5], 256, 0, stream>>>(ba);
  bucket_finalize<<<ba.fOff[5], 256, 0, stream>>>(ba);

  for (int l = 0; l < 2; ++l) {
    const float* xin[3] = {l == 0 ? emb[0] : xf[0],
                           l == 0 ? emb[1] : xf[1],
                           l == 0 ? emb[2] : xf[2]};
    for (int t = 0; t < 5; ++t) {
      int si = SI[t], di = DI[t];
      ProjJob A = {xin[si], WlP(l, t), hsb, Nn[si]};
      ProjJob B = {xin[di], WrP(l, t), hdb, Nn[di]};
      int split = (Nn[si] + 63) / 64;
      int nblk = split + (Nn[di] + 63) / 64;
      proj_pair<<<nblk, 256, 0, stream>>>(A, B, split);
      const float* attp = att + (long)(l * 8 + t) * 128;
      int gblk = (Nn[di] + 3) / 4;
      if (t == 0 || t == 1 || t == 3)   // first writer of gene/cpg/mirna agg
        gat_gather<true><<<gblk, 256, 0, stream>>>(
            ba.rs[t], ba.csrc[t], hsb, hdb, attp, agg[di], Nn[di]);
      else
        gat_gather<false><<<gblk, 256, 0, stream>>>(
            ba.rs[t], ba.csrc[t], hsb, hdb, attp, agg[di], Nn[di]);
    }
    {  // self-loop convs: agg += x @ Wl (alpha == 1), one launch
      ProjJob j0 = {xin[0], WlP(l, 5), agg[0], Nn[0]};
      ProjJob j1 = {xin[1], WlP(l, 6), agg[1], Nn[1]};
      ProjJob j2 = {xin[2], WlP(l, 7), agg[2], Nn[2]};
      int s1 = (Nn[0] + 63) / 64;
      int s2 = s1 + (Nn[1] + 63) / 64;
      int nblk = s2 + (Nn[2] + 63) / 64;
      proj_self<<<nblk, 256, 0, stream>>>(j0, j1, j2, s1, s2);
    }
    for (int ty = 0; ty < 3; ++ty)
      update_ln<<<(Nn[ty] + 3) / 4, 256, 0, stream>>>(
          xin[ty], xf[ty], agg[ty], bias + (long)l * 8 * 128, TMASK[ty],
          lng + (long)(l * 3 + ty) * 128, lnb + (long)(l * 3 + ty) * 128, Nn[ty]);
  }

  // final: z = LN(batch @ x / sqrt(N)) via one-chunk-per-block partials + reduce
  for (int ty = 0; ty < 3; ++ty)
    zgemm_part<<<nch[ty], 256, 0, stream>>>(batchp[ty], xf[ty], zp[ty], Nn[ty]);
  zreduce<<<96, 256, 0, stream>>>(
      zp[0], zp[1], zp[2], nch[0], nch[1], nch[2],
      (float)(1.0 / sqrt((double)Nn[0])), (float)(1.0 / sqrt((double)Nn[1])),
      (float)(1.0 / sqrt((double)Nn[2])), zpre);
  final_ln<<<48, 256, 0, stream>>>(zpre, outg, outb, (float*)d_out);
}

// Round 10
// 798.677 us; speedup vs baseline: 2.5997x; 1.2326x over previous
//
#include <hip/hip_runtime.h>
#include <math.h>

typedef __attribute__((ext_vector_type(4))) float f32x4;
typedef __attribute__((ext_vector_type(8))) short bf16x8;

__device__ __forceinline__ float b2f(unsigned short u) {
  return __uint_as_float(((unsigned)u) << 16);
}
__device__ __forceinline__ unsigned short f2b(float f) {
  unsigned x = __float_as_uint(f);
  unsigned r = (x + 0x7FFFu + ((x >> 16) & 1u)) >> 16;
  return (unsigned short)r;
}

// ---------------------------------------------------------------------------
// Weight prep: wt[mat][c][k] = bf16(W[mat>>1][k][c]);  mat=(l*8+t)*2+which
// ---------------------------------------------------------------------------
__global__ __launch_bounds__(256) void prep_w(
    const float* __restrict__ Wl, const float* __restrict__ Wr,
    unsigned short* __restrict__ wt)
{
  int elem = blockIdx.x * 256 + threadIdx.x;   // 0 .. 32*16384-1
  int mat = elem >> 14;
  int c = (elem >> 7) & 127;
  int k = elem & 127;
  const float* srcb = (mat & 1) ? Wr : Wl;
  wt[elem] = f2b(srcb[((long)(mat >> 1) << 14) + (k << 7) + c]);
}

// ---------------------------------------------------------------------------
// Cast emb (f32) -> xb (bf16), all 3 types fused. i indexes float4 chunks.
// ---------------------------------------------------------------------------
__global__ __launch_bounds__(256) void cast_all(
    const float* __restrict__ e0, const float* __restrict__ e1,
    const float* __restrict__ e2, unsigned short* __restrict__ x0,
    unsigned short* __restrict__ x1, unsigned short* __restrict__ x2,
    int n0, int n1, int n2)
{
  int i = blockIdx.x * 256 + threadIdx.x;
  const float* s; unsigned short* d; int loc = i;
  if (loc < n0) { s = e0; d = x0; }
  else {
    loc -= n0;
    if (loc < n1) { s = e1; d = x1; }
    else { loc -= n1; if (loc >= n2) return; s = e2; d = x2; }
  }
  float4 v = *(const float4*)(s + (long)loc * 4);
  ushort4 o = {f2b(v.x), f2b(v.y), f2b(v.z), f2b(v.w)};
  *(ushort4*)(d + (long)loc * 4) = o;
}

// ---------------------------------------------------------------------------
// MFMA projection tile: out[128,128] op= x[128,128](bf16) @ W (wt[c][k] bf16).
// 256 thr = 4 waves; wave w covers rows w*32..w*32+32 x all 128 cols.
// XOR-swizzled LDS (byte ^= (row&7)<<4) -> conflict-free b128 reads.
// MODE: 0 store f32, 1 accumulate f32, 2 store bf16.
// Fragment layouts (verified m89/m91): A row=lane&15,k-half=lane>>4;
// B col=lane&15; C/D col=lane&15,row=(lane>>4)*4+q.
// ---------------------------------------------------------------------------
template<int MODE>
__device__ __forceinline__ void mproj_tile(
    char* lx, char* lw, const unsigned short* __restrict__ xb,
    const unsigned short* __restrict__ wt, void* __restrict__ outv,
    int N, long r0, int tid)
{
#pragma unroll
  for (int i = 0; i < 8; ++i) {
    int ch = i * 256 + tid;              // 0..2047
    int row = ch >> 4, k0 = (ch & 15) << 3;
    uint4 xv = {0u, 0u, 0u, 0u};
    if (r0 + row < N) xv = *(const uint4*)(xb + (r0 + row) * 128 + k0);
    *(uint4*)(lx + ((row * 256 + k0 * 2) ^ ((row & 7) << 4))) = xv;
    uint4 wv = *(const uint4*)(wt + (long)ch * 8);   // c=ch>>4, k0=(ch&15)*8
    *(uint4*)(lw + ((ch * 16) ^ ((row & 7) << 4))) = wv;
  }
  __syncthreads();

  const int lane = tid & 63;
  const int lr = lane & 15, lk = lane >> 4;
  const int rbase = (tid >> 6) * 32;
  f32x4 acc[2][8] = {};
#pragma unroll
  for (int kb = 0; kb < 4; ++kb) {
    int k = kb * 32 + lk * 8;
    int ra = rbase + lr;
    bf16x8 a0 = *(const bf16x8*)(lx + ((ra * 256 + k * 2) ^ ((ra & 7) << 4)));
    int rb = rbase + 16 + lr;
    bf16x8 a1 = *(const bf16x8*)(lx + ((rb * 256 + k * 2) ^ ((rb & 7) << 4)));
#pragma unroll
    for (int cc = 0; cc < 8; ++cc) {
      int col = cc * 16 + lr;
      bf16x8 bfr = *(const bf16x8*)(lw + ((col * 256 + k * 2) ^ ((col & 7) << 4)));
      acc[0][cc] = __builtin_amdgcn_mfma_f32_16x16x32_bf16(a0, bfr, acc[0][cc], 0, 0, 0);
      acc[1][cc] = __builtin_amdgcn_mfma_f32_16x16x32_bf16(a1, bfr, acc[1][cc], 0, 0, 0);
    }
  }
  __syncthreads();   // safe LDS reuse across segmented jobs
#pragma unroll
  for (int rt = 0; rt < 2; ++rt) {
    int rowb = rbase + rt * 16 + lk * 4;
#pragma unroll
    for (int cc = 0; cc < 8; ++cc) {
      int col = cc * 16 + lr;
#pragma unroll
      for (int q = 0; q < 4; ++q) {
        long row = r0 + rowb + q;
        if (row < N) {
          if (MODE == 2)
            ((unsigned short*)outv)[row * 128 + col] = f2b(acc[rt][cc][q]);
          else if (MODE == 1)
            ((float*)outv)[row * 128 + col] += acc[rt][cc][q];
          else
            ((float*)outv)[row * 128 + col] = acc[rt][cc][q];
        }
      }
    }
  }
}

struct MJob { const unsigned short* x; const unsigned short* wt; void* out; int N; };

// hs (bf16 out) + hd (f32 out) projections, one launch per edge type.
__global__ __launch_bounds__(256) void mproj_pair(MJob a, MJob b, int split)
{
  __shared__ __align__(16) char lx[32768];
  __shared__ __align__(16) char lw[32768];
  int blk = blockIdx.x;
  if (blk < split)
    mproj_tile<2>(lx, lw, a.x, a.wt, a.out, a.N, (long)blk * 128, threadIdx.x);
  else
    mproj_tile<0>(lx, lw, b.x, b.wt, b.out, b.N, (long)(blk - split) * 128, threadIdx.x);
}

// 3 self-loop convs (agg += x @ Wl) in one launch.
__global__ __launch_bounds__(256) void mproj_self(
    MJob j0, MJob j1, MJob j2, int s1, int s2)
{
  __shared__ __align__(16) char lx[32768];
  __shared__ __align__(16) char lw[32768];
  int blk = blockIdx.x;
  if (blk < s1)
    mproj_tile<1>(lx, lw, j0.x, j0.wt, j0.out, j0.N, (long)blk * 128, threadIdx.x);
  else if (blk < s2)
    mproj_tile<1>(lx, lw, j1.x, j1.wt, j1.out, j1.N, (long)(blk - s1) * 128, threadIdx.x);
  else
    mproj_tile<1>(lx, lw, j2.x, j2.wt, j2.out, j2.N, (long)(blk - s2) * 128, threadIdx.x);
}

// ---------------------------------------------------------------------------
// Atomic-free bucketed CSR build (bucket = 128 dst nodes, 4096 edges/block).
// ---------------------------------------------------------------------------
struct BArgs {
  const int* src[5]; const int* dst[5];
  int* cnt[5];       // [B][NB] counts -> exclusive scan (bucket-major)
  int* tmp[5];       // E packed (dstLocal<<16 | src), bucket-sorted
  int* rs[5];        // row_start[Nd+1]
  int* csrc[5];      // E src ids, dst-sorted
  int E[5], Nd[5], NB[5], B[5];
  int cOff[6], fOff[6];
};

__global__ __launch_bounds__(256) void bucket_count(BArgs a)
{
  __shared__ int h[512];
  int blk = blockIdx.x, t = 0;
  while (blk >= a.cOff[t + 1]) ++t;
  int lb = blk - a.cOff[t];
  int B = a.B[t], NB = a.NB[t], E = a.E[t];
  for (int i = threadIdx.x; i < B; i += 256) h[i] = 0;
  __syncthreads();
  const int* dst = a.dst[t];
  int base = lb * 4096;
#pragma unroll
  for (int j = 0; j < 16; ++j) {
    int e = base + j * 256 + threadIdx.x;
    if (e < E) atomicAdd(&h[dst[e] >> 7], 1);   // LDS atomic
  }
  __syncthreads();
  int* cnt = a.cnt[t];
  for (int b = threadIdx.x; b < B; b += 256) cnt[b * NB + lb] = h[b];
}

__global__ __launch_bounds__(1024) void bucket_scan(BArgs a)
{
  int t = blockIdx.x;
  int n = a.B[t] * a.NB[t];
  int* dp = a.cnt[t];
  __shared__ int tile[1024];
  __shared__ int sbase;
  int tid = threadIdx.x;
  if (tid == 0) sbase = 0;
  __syncthreads();
  for (int chunk = 0; chunk < n; chunk += 16384) {
    int idx0 = chunk + tid * 16;
    int v[16], sum = 0;
#pragma unroll
    for (int j = 0; j < 16; ++j) {
      v[j] = (idx0 + j < n) ? dp[idx0 + j] : 0;
      sum += v[j];
    }
    tile[tid] = sum;
    __syncthreads();
    for (int off = 1; off < 1024; off <<= 1) {
      int tv = (tid >= off) ? tile[tid - off] : 0;
      __syncthreads();
      tile[tid] += tv;
      __syncthreads();
    }
    int excl = sbase + ((tid > 0) ? tile[tid - 1] : 0);
#pragma unroll
    for (int j = 0; j < 16; ++j) {
      if (idx0 + j < n) dp[idx0 + j] = excl;
      excl += v[j];
    }
    __syncthreads();
    if (tid == 0) sbase += tile[1023];
    __syncthreads();
  }
}

__global__ __launch_bounds__(256) void bucket_scatter(BArgs a)
{
  __shared__ int cur[512];
  int blk = blockIdx.x, t = 0;
  while (blk >= a.cOff[t + 1]) ++t;
  int lb = blk - a.cOff[t];
  int B = a.B[t], NB = a.NB[t], E = a.E[t];
  const int* cnt = a.cnt[t];
  for (int b = threadIdx.x; b < B; b += 256) cur[b] = cnt[b * NB + lb];
  __syncthreads();
  const int* src = a.src[t];
  const int* dst = a.dst[t];
  int* tmp = a.tmp[t];
  int base = lb * 4096;
#pragma unroll
  for (int j = 0; j < 16; ++j) {
    int e = base + j * 256 + threadIdx.x;
    if (e < E) {
      int dv = dst[e];
      int pos = atomicAdd(&cur[dv >> 7], 1);    // LDS atomic
      tmp[pos] = ((dv & 127) << 16) | src[e];
    }
  }
}

__global__ __launch_bounds__(256) void bucket_finalize(BArgs a)
{
  __shared__ int h[128], sc[128], ex[128], cur[128];
  int blk = blockIdx.x, t = 0;
  while (blk >= a.fOff[t + 1]) ++t;
  int b = blk - a.fOff[t];
  int B = a.B[t], NB = a.NB[t], E = a.E[t], Nd = a.Nd[t];
  const int* cnt = a.cnt[t];
  const int* tmp = a.tmp[t];
  int* rs = a.rs[t];
  int* csrc = a.csrc[t];
  int tid = threadIdx.x;
  int beg = cnt[b * NB];
  int end = (b + 1 < B) ? cnt[(b + 1) * NB] : E;
  if (tid < 128) h[tid] = 0;
  __syncthreads();
  for (int i = beg + tid; i < end; i += 256)
    atomicAdd(&h[tmp[i] >> 16], 1);             // LDS atomic
  __syncthreads();
  if (tid < 128) sc[tid] = h[tid];
  __syncthreads();
#pragma unroll
  for (int off = 1; off < 128; off <<= 1) {
    int v = (tid < 128 && tid >= off) ? sc[tid - off] : 0;
    __syncthreads();
    if (tid < 128) sc[tid] += v;
    __syncthreads();
  }
  if (tid < 128) {
    ex[tid] = sc[tid] - h[tid];
    cur[tid] = 0;
    int dg = b * 128 + tid;
    if (dg < Nd) rs[dg] = beg + ex[tid];
  }
  if (b == B - 1 && tid == 0) rs[Nd] = E;
  __syncthreads();
  for (int i = beg + tid; i < end; i += 256) {
    int v = tmp[i];
    int d = v >> 16;
    int r = atomicAdd(&cur[d], 1);              // LDS atomic
    csrc[beg + ex[d] + r] = v & 0xFFFF;
  }
}

// ---------------------------------------------------------------------------
// Fused GATv2 aggregate, one wave per dst row, 4-way edge unroll.
// hs bf16-packed (256B/row); agg[d] (=|+=) (sum a_e*hs[src_e])/(sum a_e+eps).
// ---------------------------------------------------------------------------
template<bool INIT>
__global__ __launch_bounds__(256) void gat_gather(
    const int* __restrict__ row_start, const int* __restrict__ csr_src,
    const unsigned short* __restrict__ hs, const float* __restrict__ hd,
    const float* __restrict__ att, float* __restrict__ agg, int Nd)
{
  int d = blockIdx.x * 4 + (threadIdx.x >> 6);
  if (d >= Nd) return;
  int lane = threadIdx.x & 63;
  float2 att2 = *(const float2*)(att + 2 * lane);
  float2 hd2 = *(const float2*)(hd + (long)d * 128 + 2 * lane);
  int beg = row_start[d], end = row_start[d + 1];
  float n0 = 0.f, n1 = 0.f, D = 0.f;
  int i = beg;
  for (; i + 3 < end; i += 4) {
    int s0 = csr_src[i], s1 = csr_src[i + 1];
    int s2 = csr_src[i + 2], s3 = csr_src[i + 3];
    ushort2 u0 = *((const ushort2*)(hs + (long)s0 * 128) + lane);
    ushort2 u1 = *((const ushort2*)(hs + (long)s1 * 128) + lane);
    ushort2 u2 = *((const ushort2*)(hs + (long)s2 * 128) + lane);
    ushort2 u3 = *((const ushort2*)(hs + (long)s3 * 128) + lane);
    float a0x = b2f(u0.x), a0y = b2f(u0.y);
    float a1x = b2f(u1.x), a1y = b2f(u1.y);
    float a2x = b2f(u2.x), a2y = b2f(u2.y);
    float a3x = b2f(u3.x), a3y = b2f(u3.y);
    float v0x = a0x + hd2.x, v0y = a0y + hd2.y;
    float v1x = a1x + hd2.x, v1y = a1y + hd2.y;
    float v2x = a2x + hd2.x, v2y = a2y + hd2.y;
    float v3x = a3x + hd2.x, v3y = a3y + hd2.y;
    v0x = fmaxf(v0x, 0.2f * v0x); v0y = fmaxf(v0y, 0.2f * v0y);
    v1x = fmaxf(v1x, 0.2f * v1x); v1y = fmaxf(v1y, 0.2f * v1y);
    v2x = fmaxf(v2x, 0.2f * v2x); v2y = fmaxf(v2y, 0.2f * v2y);
    v3x = fmaxf(v3x, 0.2f * v3x); v3y = fmaxf(v3y, 0.2f * v3y);
    float p0 = fmaf(v0x, att2.x, v0y * att2.y);
    float p1 = fmaf(v1x, att2.x, v1y * att2.y);
    float p2 = fmaf(v2x, att2.x, v2y * att2.y);
    float p3 = fmaf(v3x, att2.x, v3y * att2.y);
    p0 += __shfl_xor(p0, 1); p1 += __shfl_xor(p1, 1);
    p2 += __shfl_xor(p2, 1); p3 += __shfl_xor(p3, 1);
    p0 += __shfl_xor(p0, 2); p1 += __shfl_xor(p1, 2);
    p2 += __shfl_xor(p2, 2); p3 += __shfl_xor(p3, 2);
    p0 += __shfl_xor(p0, 4); p1 += __shfl_xor(p1, 4);
    p2 += __shfl_xor(p2, 4); p3 += __shfl_xor(p3, 4);
    float e0 = expf(fminf(p0, 60.f)), e1 = expf(fminf(p1, 60.f));
    float e2 = expf(fminf(p2, 60.f)), e3 = expf(fminf(p3, 60.f));
    n0 = fmaf(e0, a0x, n0); n1 = fmaf(e0, a0y, n1); D += e0;
    n0 = fmaf(e1, a1x, n0); n1 = fmaf(e1, a1y, n1); D += e1;
    n0 = fmaf(e2, a2x, n0); n1 = fmaf(e2, a2y, n1); D += e2;
    n0 = fmaf(e3, a3x, n0); n1 = fmaf(e3, a3y, n1); D += e3;
  }
  for (; i < end; ++i) {
    int s = csr_src[i];
    ushort2 u = *((const ushort2*)(hs + (long)s * 128) + lane);
    float hx = b2f(u.x), hy = b2f(u.y);
    float vx = hx + hd2.x, vy = hy + hd2.y;
    vx = fmaxf(vx, 0.2f * vx);
    vy = fmaxf(vy, 0.2f * vy);
    float pp = fmaf(vx, att2.x, vy * att2.y);
    pp += __shfl_xor(pp, 1);
    pp += __shfl_xor(pp, 2);
    pp += __shfl_xor(pp, 4);
    float a = expf(fminf(pp, 60.f));
    n0 = fmaf(a, hx, n0);
    n1 = fmaf(a, hy, n1);
    D += a;
  }
  float inv = 1.f / (D + 1e-16f);
  float* ap = agg + (long)d * 128 + 2 * lane;
  if (INIT) {
    float2 v = {n0 * inv, n1 * inv};
    *(float2*)ap = v;
  } else {
    float2 cur = *(const float2*)ap;
    cur.x += n0 * inv;
    cur.y += n1 * inv;
    *(float2*)ap = cur;
  }
}

// ---------------------------------------------------------------------------
// x = LayerNorm(xin + elu(agg + bias_sum)); writes f32 (xf) + bf16 (xb).
// ---------------------------------------------------------------------------
__global__ __launch_bounds__(256) void update_ln(
    const float* __restrict__ xin, float* __restrict__ xf,
    unsigned short* __restrict__ xbo, const float* __restrict__ agg,
    const float* __restrict__ biasl, int tmask,
    const float* __restrict__ gam, const float* __restrict__ bet, int N)
{
  int row = blockIdx.x * 4 + (threadIdx.x >> 6);
  int lane = threadIdx.x & 63;
  if (row >= N) return;
  float bs0 = 0.f, bs1 = 0.f;
#pragma unroll
  for (int t = 0; t < 8; ++t)
    if (tmask & (1 << t)) {
      bs0 += biasl[t * 128 + lane];
      bs1 += biasl[t * 128 + 64 + lane];
    }
  long base = (long)row * 128;
  float v0 = agg[base + lane] + bs0, v1 = agg[base + 64 + lane] + bs1;
  v0 = v0 > 0.f ? v0 : expf(v0) - 1.f;
  v1 = v1 > 0.f ? v1 : expf(v1) - 1.f;
  float x0 = xin[base + lane] + v0, x1 = xin[base + 64 + lane] + v1;
  float s = x0 + x1;
#pragma unroll
  for (int o = 32; o > 0; o >>= 1) s += __shfl_xor(s, o);
  float mu = s * 0.0078125f;
  float dd0 = x0 - mu, dd1 = x1 - mu;
  float q = dd0 * dd0 + dd1 * dd1;
#pragma unroll
  for (int o = 32; o > 0; o >>= 1) q += __shfl_xor(q, o);
  float r = rsqrtf(q * 0.0078125f + 1e-5f);
  float y0 = dd0 * r * gam[lane] + bet[lane];
  float y1 = dd1 * r * gam[64 + lane] + bet[64 + lane];
  xf[base + lane] = y0; xf[base + 64 + lane] = y1;
  xbo[base + lane] = f2b(y0); xbo[base + 64 + lane] = f2b(y1);
}

// ---------------------------------------------------------------------------
// zgemm stage 1: ONE 64-row n-chunk per block, non-atomic partial tiles.
// ---------------------------------------------------------------------------
__global__ __launch_bounds__(256) void zgemm_part(
    const float* __restrict__ batch, const float* __restrict__ x,
    float* __restrict__ zpart, int N)
{
  __shared__ __align__(16) float xl[64 * 128];
  __shared__ __align__(16) float bl[64 * 65];
  int tid = threadIdx.x;
  int n0 = blockIdx.x * 64;
  for (int i = tid; i < 64 * 128; i += 256) {
    int nn = i >> 7;
    xl[i] = (n0 + nn < N) ? x[(long)(n0 + nn) * 128 + (i & 127)] : 0.f;
  }
  for (int i = tid; i < 64 * 64; i += 256) {
    int b = i >> 6, nn = i & 63;
    bl[nn * 65 + b] = (n0 + nn < N) ? batch[(long)b * N + n0 + nn] : 0.f;
  }
  __syncthreads();
  int cg = (tid & 31) * 4;
  int bg = (tid >> 5) * 8;
  float acc[8][4] = {};
  for (int nn = 0; nn < 64; ++nn) {
    float4 xv = *(const float4*)(xl + nn * 128 + cg);
#pragma unroll
    for (int i = 0; i < 8; ++i) {
      float bv = bl[nn * 65 + bg + i];
      acc[i][0] = fmaf(bv, xv.x, acc[i][0]);
      acc[i][1] = fmaf(bv, xv.y, acc[i][1]);
      acc[i][2] = fmaf(bv, xv.z, acc[i][2]);
      acc[i][3] = fmaf(bv, xv.w, acc[i][3]);
    }
  }
  float* zp = zpart + (long)blockIdx.x * 8192;
#pragma unroll
  for (int i = 0; i < 8; ++i) {
    float4 v = {acc[i][0], acc[i][1], acc[i][2], acc[i][3]};
    *(float4*)(zp + (bg + i) * 128 + cg) = v;
  }
}

// ---------------------------------------------------------------------------
// zgemm stage 2: 16 independent accumulators -> 16 loads in flight.
// ---------------------------------------------------------------------------
__global__ __launch_bounds__(256) void zreduce(
    const float* __restrict__ zp0, const float* __restrict__ zp1,
    const float* __restrict__ zp2, int G0, int G1, int G2,
    float s0, float s1, float s2, float* __restrict__ zpre)
{
  int blk = blockIdx.x;
  int ty = blk >> 5;
  int i = (blk & 31) * 256 + threadIdx.x;
  const float* zp = ty == 0 ? zp0 : (ty == 1 ? zp1 : zp2);
  int G = ty == 0 ? G0 : (ty == 1 ? G1 : G2);
  float sc = ty == 0 ? s0 : (ty == 1 ? s1 : s2);
  float a[16];
#pragma unroll
  for (int u = 0; u < 16; ++u) a[u] = 0.f;
  int g = 0;
  for (; g + 16 <= G; g += 16) {
#pragma unroll
    for (int u = 0; u < 16; ++u) a[u] += zp[(long)(g + u) * 8192 + i];
  }
  for (; g < G; ++g) a[0] += zp[(long)g * 8192 + i];
  float s = (((a[0] + a[1]) + (a[2] + a[3])) + ((a[4] + a[5]) + (a[6] + a[7])))
          + (((a[8] + a[9]) + (a[10] + a[11])) + ((a[12] + a[13]) + (a[14] + a[15])));
  zpre[ty * 8192 + i] = s * sc;
}

// ---------------------------------------------------------------------------
// Final LayerNorm over zpre[3*64,128] -> f32 out. 1 wave/row.
// ---------------------------------------------------------------------------
__global__ __launch_bounds__(256) void final_ln(
    const float* __restrict__ zpre, const float* __restrict__ gam,
    const float* __restrict__ bet, float* __restrict__ out)
{
  int row = blockIdx.x * 4 + (threadIdx.x >> 6);
  int lane = threadIdx.x & 63;
  if (row >= 192) return;
  int ty = row >> 6;
  long base = (long)row * 128;
  float x0 = zpre[base + lane], x1 = zpre[base + 64 + lane];
  float s = x0 + x1;
#pragma unroll
  for (int o = 32; o > 0; o >>= 1) s += __shfl_xor(s, o);
  float mu = s * 0.0078125f;
  float d0 = x0 - mu, d1 = x1 - mu;
  float q = d0 * d0 + d1 * d1;
#pragma unroll
  for (int o = 32; o > 0; o >>= 1) q += __shfl_xor(q, o);
  float r = rsqrtf(q * 0.0078125f + 1e-5f);
  out[base + lane]      = d0 * r * gam[ty * 128 + lane]      + bet[ty * 128 + lane];
  out[base + 64 + lane] = d1 * r * gam[ty * 128 + 64 + lane] + bet[ty * 128 + 64 + lane];
}

// ---------------------------------------------------------------------------
extern "C" void kernel_launch(void* const* d_in, const int* in_sizes, int n_in,
                              void* d_out, int out_size, void* d_ws, size_t ws_size,
                              hipStream_t stream)
{
  const float* batchp[3] = {(const float*)d_in[0], (const float*)d_in[1],
                            (const float*)d_in[2]};
  const float* emb[3] = {(const float*)d_in[3], (const float*)d_in[4],
                         (const float*)d_in[5]};
  const float* Wl   = (const float*)d_in[6];
  const float* Wr   = (const float*)d_in[7];
  const float* att  = (const float*)d_in[8];
  const float* bias = (const float*)d_in[9];
  const float* lng  = (const float*)d_in[10];
  const float* lnb  = (const float*)d_in[11];
  const float* outg = (const float*)d_in[12];
  const float* outb = (const float*)d_in[13];
  const int* eiP[8]; int E[8];
  for (int t = 0; t < 8; ++t) { eiP[t] = (const int*)d_in[14 + t]; E[t] = in_sizes[14 + t] / 2; }
  int Nn[3] = {in_sizes[3] / 128, in_sizes[4] / 128, in_sizes[5] / 128};
  int maxN = Nn[0] > Nn[1] ? Nn[0] : Nn[1]; if (Nn[2] > maxN) maxN = Nn[2];
  long Ntot = (long)Nn[0] + Nn[1] + Nn[2];

  const int SI[5] = {1, 0, 2, 0, 0};
  const int DI[5] = {0, 1, 0, 2, 0};
  const int TMASK[3] = {0x35, 0x42, 0x88};  // gene: t0,t2,t4,t5; cpg: t1,t6; mirna: t3,t7

  char* p = (char*)d_ws;
  auto carve = [&](size_t b) -> void* {
    void* r = (void*)p; p += (b + 255) & ~(size_t)255; return r;
  };
  float* xf[3];
  for (int ty = 0; ty < 3; ++ty) xf[ty] = (float*)carve((size_t)Nn[ty] * 128 * 4);
  unsigned short* xb[3];
  for (int ty = 0; ty < 3; ++ty) xb[ty] = (unsigned short*)carve((size_t)Nn[ty] * 128 * 2);
  float* aggAll = (float*)carve((size_t)Ntot * 128 * 4);
  float* agg[3] = {aggAll, aggAll + (long)Nn[0] * 128, aggAll + ((long)Nn[0] + Nn[1]) * 128};
  unsigned short* hsb = (unsigned short*)carve((size_t)maxN * 128 * 2);  // bf16
  float* hdb = (float*)carve((size_t)maxN * 128 * 4);
  float* zpre = (float*)carve(3 * 64 * 128 * 4);
  unsigned short* wtb = (unsigned short*)carve((size_t)32 * 16384 * 2);

  // bucketed CSR build (no global atomics)
  BArgs ba;
  {
    int cOff = 0, fOff = 0;
    for (int t = 0; t < 5; ++t) {
      int nd = Nn[DI[t]];
      ba.src[t] = eiP[t];
      ba.dst[t] = eiP[t] + E[t];
      ba.E[t] = E[t];
      ba.Nd[t] = nd;
      ba.NB[t] = (E[t] + 4095) / 4096;
      ba.B[t] = (nd + 127) / 128;
      ba.cnt[t] = (int*)carve((size_t)ba.B[t] * ba.NB[t] * 4);
      ba.tmp[t] = (int*)carve((size_t)E[t] * 4);
      ba.rs[t] = (int*)carve((size_t)(nd + 1) * 4);
      ba.csrc[t] = (int*)carve((size_t)E[t] * 4);
      ba.cOff[t] = cOff; cOff += ba.NB[t];
      ba.fOff[t] = fOff; fOff += ba.B[t];
    }
    ba.cOff[5] = cOff;
    ba.fOff[5] = fOff;
  }
  if ((size_t)(p - (char*)d_ws) > ws_size) return;  // workspace too small

  // zgemm partials alias hsb..hdb region (dead after the layer loop):
  // sum(nch)*32KB (~41MB) <= maxN*128*(2+4) bytes (~46MB) ✓
  int nch[3];
  for (int ty = 0; ty < 3; ++ty) nch[ty] = (Nn[ty] + 63) / 64;
  float* zp[3];
  zp[0] = (float*)hsb;
  zp[1] = zp[0] + (long)nch[0] * 8192;
  zp[2] = zp[1] + (long)nch[1] * 8192;

  auto WTB = [&](int l, int t, int which) {
    return wtb + ((long)((l * 8 + t) * 2 + which) << 14);
  };

  // 0) weight prep + emb casts
  prep_w<<<2048, 256, 0, stream>>>(Wl, Wr, wtb);
  {
    int n0 = Nn[0] * 32, n1 = Nn[1] * 32, n2 = Nn[2] * 32;
    cast_all<<<(int)((n0 + n1 + n2 + 255) / 256), 256, 0, stream>>>(
        emb[0], emb[1], emb[2], xb[0], xb[1], xb[2], n0, n1, n2);
  }

  // 1) build CSR for the 5 real edge types (4 launches, zero global atomics)
  bucket_count<<<ba.cOff[5], 256, 0, stream>>>(ba);
  bucket_scan<<<5, 1024, 0, stream>>>(ba);
  bucket_scatter<<<ba.cOff[5], 256, 0, stream>>>(ba);
  bucket_finalize<<<ba.fOff[5], 256, 0, stream>>>(ba);

  for (int l = 0; l < 2; ++l) {
    const float* xinf[3] = {l == 0 ? emb[0] : xf[0],
                            l == 0 ? emb[1] : xf[1],
                            l == 0 ? emb[2] : xf[2]};
    for (int t = 0; t < 5; ++t) {
      int si = SI[t], di = DI[t];
      MJob A = {xb[si], WTB(l, t, 0), hsb, Nn[si]};
      MJob B = {xb[di], WTB(l, t, 1), hdb, Nn[di]};
      int split = (Nn[si] + 127) / 128;
      int nblk = split + (Nn[di] + 127) / 128;
      mproj_pair<<<nblk, 256, 0, stream>>>(A, B, split);
      const float* attp = att + (long)(l * 8 + t) * 128;
      int gblk = (Nn[di] + 3) / 4;
      if (t == 0 || t == 1 || t == 3)   // first writer of gene/cpg/mirna agg
        gat_gather<true><<<gblk, 256, 0, stream>>>(
            ba.rs[t], ba.csrc[t], hsb, hdb, attp, agg[di], Nn[di]);
      else
        gat_gather<false><<<gblk, 256, 0, stream>>>(
            ba.rs[t], ba.csrc[t], hsb, hdb, attp, agg[di], Nn[di]);
    }
    {  // self-loop convs: agg += x @ Wl (alpha == 1), one launch
      MJob j0 = {xb[0], WTB(l, 5, 0), agg[0], Nn[0]};
      MJob j1 = {xb[1], WTB(l, 6, 0), agg[1], Nn[1]};
      MJob j2 = {xb[2], WTB(l, 7, 0), agg[2], Nn[2]};
      int s1 = (Nn[0] + 127) / 128;
      int s2 = s1 + (Nn[1] + 127) / 128;
      int nblk = s2 + (Nn[2] + 127) / 128;
      mproj_self<<<nblk, 256, 0, stream>>>(j0, j1, j2, s1, s2);
    }
    for (int ty = 0; ty < 3; ++ty)
      update_ln<<<(Nn[ty] + 3) / 4, 256, 0, stream>>>(
          xinf[ty], xf[ty], xb[ty], agg[ty], bias + (long)l * 8 * 128, TMASK[ty],
          lng + (long)(l * 3 + ty) * 128, lnb + (long)(l * 3 + ty) * 128, Nn[ty]);
  }

  // final: z = LN(batch @ x / sqrt(N)) via partial tiles + reduce
  for (int ty = 0; ty < 3; ++ty)
    zgemm_part<<<nch[ty], 256, 0, stream>>>(batchp[ty], xf[ty], zp[ty], Nn[ty]);
  zreduce<<<96, 256, 0, stream>>>(
      zp[0], zp[1], zp[2], nch[0], nch[1], nch[2],
      (float)(1.0 / sqrt((double)Nn[0])), (float)(1.0 / sqrt((double)Nn[1])),
      (float)(1.0 / sqrt((double)Nn[2])), zpre);
  final_ln<<<48, 256, 0, stream>>>(zpre, outg, outb, (float*)d_out);
}

// Round 11
// 624.094 us; speedup vs baseline: 3.3269x; 1.2797x over previous
//
#include <hip/hip_runtime.h>
#include <math.h>

typedef __attribute__((ext_vector_type(4))) float f32x4;
typedef __attribute__((ext_vector_type(8))) short bf16x8;

__device__ __forceinline__ float b2f(unsigned short u) {
  return __uint_as_float(((unsigned)u) << 16);
}
__device__ __forceinline__ unsigned short f2b(float f) {
  unsigned x = __float_as_uint(f);
  unsigned r = (x + 0x7FFFu + ((x >> 16) & 1u)) >> 16;
  return (unsigned short)r;
}

// ---------------------------------------------------------------------------
// Weight prep: wt[mat][c][k] = bf16(W[mat>>1][k][c]);  mat=(l*8+t)*2+which
// ---------------------------------------------------------------------------
__global__ __launch_bounds__(256) void prep_w(
    const float* __restrict__ Wl, const float* __restrict__ Wr,
    unsigned short* __restrict__ wt)
{
  int elem = blockIdx.x * 256 + threadIdx.x;   // 0 .. 32*16384-1
  int mat = elem >> 14;
  int c = (elem >> 7) & 127;
  int k = elem & 127;
  const float* srcb = (mat & 1) ? Wr : Wl;
  wt[elem] = f2b(srcb[((long)(mat >> 1) << 14) + (k << 7) + c]);
}

// ---------------------------------------------------------------------------
// Cast emb (f32) -> xb (bf16), all 3 types fused (float4 chunks).
// ---------------------------------------------------------------------------
__global__ __launch_bounds__(256) void cast_all(
    const float* __restrict__ e0, const float* __restrict__ e1,
    const float* __restrict__ e2, unsigned short* __restrict__ x0,
    unsigned short* __restrict__ x1, unsigned short* __restrict__ x2,
    int n0, int n1, int n2)
{
  int i = blockIdx.x * 256 + threadIdx.x;
  const float* s; unsigned short* d; int loc = i;
  if (loc < n0) { s = e0; d = x0; }
  else {
    loc -= n0;
    if (loc < n1) { s = e1; d = x1; }
    else { loc -= n1; if (loc >= n2) return; s = e2; d = x2; }
  }
  float4 v = *(const float4*)(s + (long)loc * 4);
  ushort4 o = {f2b(v.x), f2b(v.y), f2b(v.z), f2b(v.w)};
  *(ushort4*)(d + (long)loc * 4) = o;
}

// ---------------------------------------------------------------------------
// MFMA projection tile (as r10, mode now runtime: 0 store f32, 2 store bf16).
// ---------------------------------------------------------------------------
__device__ __forceinline__ void mproj_tile(
    char* lx, char* lw, const unsigned short* __restrict__ xb,
    const unsigned short* __restrict__ wt, void* __restrict__ outv,
    int N, long r0, int tid, int mode)
{
#pragma unroll
  for (int i = 0; i < 8; ++i) {
    int ch = i * 256 + tid;              // 0..2047
    int row = ch >> 4, k0 = (ch & 15) << 3;
    uint4 xv = {0u, 0u, 0u, 0u};
    if (r0 + row < N) xv = *(const uint4*)(xb + (r0 + row) * 128 + k0);
    *(uint4*)(lx + ((row * 256 + k0 * 2) ^ ((row & 7) << 4))) = xv;
    uint4 wv = *(const uint4*)(wt + (long)ch * 8);
    *(uint4*)(lw + ((ch * 16) ^ ((row & 7) << 4))) = wv;
  }
  __syncthreads();

  const int lane = tid & 63;
  const int lr = lane & 15, lk = lane >> 4;
  const int rbase = (tid >> 6) * 32;
  f32x4 acc[2][8] = {};
#pragma unroll
  for (int kb = 0; kb < 4; ++kb) {
    int k = kb * 32 + lk * 8;
    int ra = rbase + lr;
    bf16x8 a0 = *(const bf16x8*)(lx + ((ra * 256 + k * 2) ^ ((ra & 7) << 4)));
    int rb = rbase + 16 + lr;
    bf16x8 a1 = *(const bf16x8*)(lx + ((rb * 256 + k * 2) ^ ((rb & 7) << 4)));
#pragma unroll
    for (int cc = 0; cc < 8; ++cc) {
      int col = cc * 16 + lr;
      bf16x8 bfr = *(const bf16x8*)(lw + ((col * 256 + k * 2) ^ ((col & 7) << 4)));
      acc[0][cc] = __builtin_amdgcn_mfma_f32_16x16x32_bf16(a0, bfr, acc[0][cc], 0, 0, 0);
      acc[1][cc] = __builtin_amdgcn_mfma_f32_16x16x32_bf16(a1, bfr, acc[1][cc], 0, 0, 0);
    }
  }
  __syncthreads();   // safe LDS reuse across segmented jobs
#pragma unroll
  for (int rt = 0; rt < 2; ++rt) {
    int rowb = rbase + rt * 16 + lk * 4;
#pragma unroll
    for (int cc = 0; cc < 8; ++cc) {
      int col = cc * 16 + lr;
#pragma unroll
      for (int q = 0; q < 4; ++q) {
        long row = r0 + rowb + q;
        if (row < N) {
          if (mode == 2)
            ((unsigned short*)outv)[row * 128 + col] = f2b(acc[rt][cc][q]);
          else
            ((float*)outv)[row * 128 + col] = acc[rt][cc][q];
        }
      }
    }
  }
}

struct PJob { const unsigned short* x; const unsigned short* wt; void* out; int N; int mode; };
struct PArgs { PJob j[13]; int off[14]; };

// All 13 projections of one layer in a single launch.
__global__ __launch_bounds__(256) void mproj_all(PArgs a)
{
  __shared__ __align__(16) char lx[32768];
  __shared__ __align__(16) char lw[32768];
  int blk = blockIdx.x, t = 0;
  while (blk >= a.off[t + 1]) ++t;
  const PJob& J = a.j[t];
  mproj_tile(lx, lw, J.x, J.wt, J.out, J.N, (long)(blk - a.off[t]) * 128,
             threadIdx.x, J.mode);
}

// ---------------------------------------------------------------------------
// Atomic-free bucketed CSR build (bucket = 128 dst nodes, 4096 edges/block).
// ---------------------------------------------------------------------------
struct BArgs {
  const int* src[5]; const int* dst[5];
  int* cnt[5];       // [B][NB] counts -> exclusive scan (bucket-major)
  int* tmp[5];       // E packed (dstLocal<<16 | src), bucket-sorted
  int* rs[5];        // row_start[Nd+1]
  int* csrc[5];      // E src ids, dst-sorted
  int E[5], Nd[5], NB[5], B[5];
  int cOff[6], fOff[6];
};

__global__ __launch_bounds__(256) void bucket_count(BArgs a)
{
  __shared__ int h[512];
  int blk = blockIdx.x, t = 0;
  while (blk >= a.cOff[t + 1]) ++t;
  int lb = blk - a.cOff[t];
  int B = a.B[t], NB = a.NB[t], E = a.E[t];
  for (int i = threadIdx.x; i < B; i += 256) h[i] = 0;
  __syncthreads();
  const int* dst = a.dst[t];
  int base = lb * 4096;
#pragma unroll
  for (int j = 0; j < 16; ++j) {
    int e = base + j * 256 + threadIdx.x;
    if (e < E) atomicAdd(&h[dst[e] >> 7], 1);   // LDS atomic
  }
  __syncthreads();
  int* cnt = a.cnt[t];
  for (int b = threadIdx.x; b < B; b += 256) cnt[b * NB + lb] = h[b];
}

// wave-shfl scan: 4 barriers per 16K chunk (was ~20 with Hillis-Steele)
__global__ __launch_bounds__(1024) void bucket_scan(BArgs a)
{
  int t = blockIdx.x;
  int n = a.B[t] * a.NB[t];
  int* dp = a.cnt[t];
  __shared__ int wsum[16];
  __shared__ int sbase, ctot;
  int tid = threadIdx.x;
  int lane = tid & 63, wid = tid >> 6;
  if (tid == 0) sbase = 0;
  __syncthreads();
  for (int chunk = 0; chunk < n; chunk += 16384) {
    int idx0 = chunk + tid * 16;
    int v[16], lsum = 0;
#pragma unroll
    for (int j = 0; j < 16; ++j) {
      v[j] = (idx0 + j < n) ? dp[idx0 + j] : 0;
      lsum += v[j];
    }
    int sc = lsum;                      // inclusive wave scan
#pragma unroll
    for (int o = 1; o < 64; o <<= 1) {
      int u = __shfl_up(sc, o);
      if (lane >= o) sc += u;
    }
    if (lane == 63) wsum[wid] = sc;
    __syncthreads();
    if (wid == 0) {
      int w = (lane < 16) ? wsum[lane] : 0;
      int s2 = w;
#pragma unroll
      for (int o = 1; o < 16; o <<= 1) {
        int u = __shfl_up(s2, o);
        if (lane >= o) s2 += u;
      }
      if (lane < 16) wsum[lane] = s2 - w;   // exclusive wave prefix
      if (lane == 15) ctot = s2;            // chunk total
    }
    __syncthreads();
    int excl = sbase + wsum[wid] + (sc - lsum);
#pragma unroll
    for (int j = 0; j < 16; ++j) {
      if (idx0 + j < n) dp[idx0 + j] = excl;
      excl += v[j];
    }
    __syncthreads();
    if (tid == 0) sbase += ctot;
    __syncthreads();
  }
}

__global__ __launch_bounds__(256) void bucket_scatter(BArgs a)
{
  __shared__ int cur[512];
  int blk = blockIdx.x, t = 0;
  while (blk >= a.cOff[t + 1]) ++t;
  int lb = blk - a.cOff[t];
  int B = a.B[t], NB = a.NB[t], E = a.E[t];
  const int* cnt = a.cnt[t];
  for (int b = threadIdx.x; b < B; b += 256) cur[b] = cnt[b * NB + lb];
  __syncthreads();
  const int* src = a.src[t];
  const int* dst = a.dst[t];
  int* tmp = a.tmp[t];
  int base = lb * 4096;
#pragma unroll
  for (int j = 0; j < 16; ++j) {
    int e = base + j * 256 + threadIdx.x;
    if (e < E) {
      int dv = dst[e];
      int pos = atomicAdd(&cur[dv >> 7], 1);    // LDS atomic
      tmp[pos] = ((dv & 127) << 16) | src[e];
    }
  }
}

__global__ __launch_bounds__(256) void bucket_finalize(BArgs a)
{
  __shared__ int h[128], sc[128], ex[128], cur[128];
  int blk = blockIdx.x, t = 0;
  while (blk >= a.fOff[t + 1]) ++t;
  int b = blk - a.fOff[t];
  int B = a.B[t], NB = a.NB[t], E = a.E[t], Nd = a.Nd[t];
  const int* cnt = a.cnt[t];
  const int* tmp = a.tmp[t];
  int* rs = a.rs[t];
  int* csrc = a.csrc[t];
  int tid = threadIdx.x;
  int beg = cnt[b * NB];
  int end = (b + 1 < B) ? cnt[(b + 1) * NB] : E;
  if (tid < 128) h[tid] = 0;
  __syncthreads();
  for (int i = beg + tid; i < end; i += 256)
    atomicAdd(&h[tmp[i] >> 16], 1);             // LDS atomic
  __syncthreads();
  if (tid < 128) sc[tid] = h[tid];
  __syncthreads();
#pragma unroll
  for (int off = 1; off < 128; off <<= 1) {
    int v = (tid < 128 && tid >= off) ? sc[tid - off] : 0;
    __syncthreads();
    if (tid < 128) sc[tid] += v;
    __syncthreads();
  }
  if (tid < 128) {
    ex[tid] = sc[tid] - h[tid];
    cur[tid] = 0;
    int dg = b * 128 + tid;
    if (dg < Nd) rs[dg] = beg + ex[tid];
  }
  if (b == B - 1 && tid == 0) rs[Nd] = E;
  __syncthreads();
  for (int i = beg + tid; i < end; i += 256) {
    int v = tmp[i];
    int d = v >> 16;
    int r = atomicAdd(&cur[d], 1);              // LDS atomic
    csrc[beg + ex[d] + r] = v & 0xFFFF;
  }
}

// ---------------------------------------------------------------------------
// Fused gather over ALL edge types: wave owns one dst row; iterates its node
// type's incident edge-type list (gene: t0,t2,t4; cpg: t1; mirna: t3); single
// non-atomic agg[d] += total at the end (agg pre-filled by self-proj store).
// hs, hd both bf16 (256B rows).
// ---------------------------------------------------------------------------
struct GSeg {
  const int* rs[3]; const int* csrc[3];
  const unsigned short* hs[3]; const unsigned short* hd[3];
  const float* att[3];
  float* agg; int Nd; int ntypes;
};
struct GArgs { GSeg s[3]; int off[4]; };

__global__ __launch_bounds__(256) void gat_gather_all(GArgs g)
{
  int blk = blockIdx.x, si = 0;
  while (blk >= g.off[si + 1]) ++si;
  const GSeg& sg = g.s[si];
  int d = (blk - g.off[si]) * 4 + (threadIdx.x >> 6);
  if (d >= sg.Nd) return;
  int lane = threadIdx.x & 63;
  float tot0 = 0.f, tot1 = 0.f;
  for (int k = 0; k < sg.ntypes; ++k) {
    float2 att2 = *(const float2*)(sg.att[k] + 2 * lane);
    ushort2 hu = *((const ushort2*)(sg.hd[k] + (long)d * 128) + lane);
    float hdx = b2f(hu.x), hdy = b2f(hu.y);
    const int* rsk = sg.rs[k];
    const int* cs = sg.csrc[k];
    const unsigned short* hsk = sg.hs[k];
    int beg = rsk[d], end = rsk[d + 1];
    float n0 = 0.f, n1 = 0.f, D = 0.f;
    int i = beg;
    for (; i + 3 < end; i += 4) {
      int s0 = cs[i], s1 = cs[i + 1], s2 = cs[i + 2], s3 = cs[i + 3];
      ushort2 u0 = *((const ushort2*)(hsk + (long)s0 * 128) + lane);
      ushort2 u1 = *((const ushort2*)(hsk + (long)s1 * 128) + lane);
      ushort2 u2 = *((const ushort2*)(hsk + (long)s2 * 128) + lane);
      ushort2 u3 = *((const ushort2*)(hsk + (long)s3 * 128) + lane);
      float a0x = b2f(u0.x), a0y = b2f(u0.y);
      float a1x = b2f(u1.x), a1y = b2f(u1.y);
      float a2x = b2f(u2.x), a2y = b2f(u2.y);
      float a3x = b2f(u3.x), a3y = b2f(u3.y);
      float v0x = a0x + hdx, v0y = a0y + hdy;
      float v1x = a1x + hdx, v1y = a1y + hdy;
      float v2x = a2x + hdx, v2y = a2y + hdy;
      float v3x = a3x + hdx, v3y = a3y + hdy;
      v0x = fmaxf(v0x, 0.2f * v0x); v0y = fmaxf(v0y, 0.2f * v0y);
      v1x = fmaxf(v1x, 0.2f * v1x); v1y = fmaxf(v1y, 0.2f * v1y);
      v2x = fmaxf(v2x, 0.2f * v2x); v2y = fmaxf(v2y, 0.2f * v2y);
      v3x = fmaxf(v3x, 0.2f * v3x); v3y = fmaxf(v3y, 0.2f * v3y);
      float p0 = fmaf(v0x, att2.x, v0y * att2.y);
      float p1 = fmaf(v1x, att2.x, v1y * att2.y);
      float p2 = fmaf(v2x, att2.x, v2y * att2.y);
      float p3 = fmaf(v3x, att2.x, v3y * att2.y);
      p0 += __shfl_xor(p0, 1); p1 += __shfl_xor(p1, 1);
      p2 += __shfl_xor(p2, 1); p3 += __shfl_xor(p3, 1);
      p0 += __shfl_xor(p0, 2); p1 += __shfl_xor(p1, 2);
      p2 += __shfl_xor(p2, 2); p3 += __shfl_xor(p3, 2);
      p0 += __shfl_xor(p0, 4); p1 += __shfl_xor(p1, 4);
      p2 += __shfl_xor(p2, 4); p3 += __shfl_xor(p3, 4);
      float e0 = expf(fminf(p0, 60.f)), e1 = expf(fminf(p1, 60.f));
      float e2 = expf(fminf(p2, 60.f)), e3 = expf(fminf(p3, 60.f));
      n0 = fmaf(e0, a0x, n0); n1 = fmaf(e0, a0y, n1); D += e0;
      n0 = fmaf(e1, a1x, n0); n1 = fmaf(e1, a1y, n1); D += e1;
      n0 = fmaf(e2, a2x, n0); n1 = fmaf(e2, a2y, n1); D += e2;
      n0 = fmaf(e3, a3x, n0); n1 = fmaf(e3, a3y, n1); D += e3;
    }
    for (; i < end; ++i) {
      int s = cs[i];
      ushort2 u = *((const ushort2*)(hsk + (long)s * 128) + lane);
      float hx = b2f(u.x), hy = b2f(u.y);
      float vx = hx + hdx, vy = hy + hdy;
      vx = fmaxf(vx, 0.2f * vx);
      vy = fmaxf(vy, 0.2f * vy);
      float pp = fmaf(vx, att2.x, vy * att2.y);
      pp += __shfl_xor(pp, 1);
      pp += __shfl_xor(pp, 2);
      pp += __shfl_xor(pp, 4);
      float a = expf(fminf(pp, 60.f));
      n0 = fmaf(a, hx, n0);
      n1 = fmaf(a, hy, n1);
      D += a;
    }
    float inv = 1.f / (D + 1e-16f);
    tot0 = fmaf(n0, inv, tot0);
    tot1 = fmaf(n1, inv, tot1);
  }
  float* ap = sg.agg + (long)d * 128 + 2 * lane;
  float2 cur = *(const float2*)ap;
  cur.x += tot0;
  cur.y += tot1;
  *(float2*)ap = cur;
}

// ---------------------------------------------------------------------------
// Fused LayerNorm update for all 3 node types in one launch.
// ---------------------------------------------------------------------------
struct LJob {
  const float* xin; float* xf; unsigned short* xb;
  const float* agg; const float* biasl; int tmask;
  const float* gam; const float* bet; int N;
};
struct LArgs { LJob j[3]; int off[4]; };

__global__ __launch_bounds__(256) void update_ln_all(LArgs a)
{
  int blk = blockIdx.x, t = 0;
  while (blk >= a.off[t + 1]) ++t;
  const LJob& J = a.j[t];
  int row = (blk - a.off[t]) * 4 + (threadIdx.x >> 6);
  int lane = threadIdx.x & 63;
  if (row >= J.N) return;
  float bs0 = 0.f, bs1 = 0.f;
#pragma unroll
  for (int tt = 0; tt < 8; ++tt)
    if (J.tmask & (1 << tt)) {
      bs0 += J.biasl[tt * 128 + lane];
      bs1 += J.biasl[tt * 128 + 64 + lane];
    }
  long base = (long)row * 128;
  float v0 = J.agg[base + lane] + bs0, v1 = J.agg[base + 64 + lane] + bs1;
  v0 = v0 > 0.f ? v0 : expf(v0) - 1.f;
  v1 = v1 > 0.f ? v1 : expf(v1) - 1.f;
  float x0 = J.xin[base + lane] + v0, x1 = J.xin[base + 64 + lane] + v1;
  float s = x0 + x1;
#pragma unroll
  for (int o = 32; o > 0; o >>= 1) s += __shfl_xor(s, o);
  float mu = s * 0.0078125f;
  float dd0 = x0 - mu, dd1 = x1 - mu;
  float q = dd0 * dd0 + dd1 * dd1;
#pragma unroll
  for (int o = 32; o > 0; o >>= 1) q += __shfl_xor(q, o);
  float r = rsqrtf(q * 0.0078125f + 1e-5f);
  float y0 = dd0 * r * J.gam[lane] + J.bet[lane];
  float y1 = dd1 * r * J.gam[64 + lane] + J.bet[64 + lane];
  J.xf[base + lane] = y0; J.xf[base + 64 + lane] = y1;
  J.xb[base + lane] = f2b(y0); J.xb[base + 64 + lane] = f2b(y1);
}

// ---------------------------------------------------------------------------
// zgemm stage 1 fused over 3 types: one 64-row chunk per block, non-atomic.
// ---------------------------------------------------------------------------
struct ZArgs {
  const float* batch[3]; const float* x[3]; float* zp[3]; int N[3];
  int off[4];
};

__global__ __launch_bounds__(256) void zgemm_all(ZArgs z)
{
  __shared__ __align__(16) float xl[64 * 128];
  __shared__ __align__(16) float bl[64 * 65];
  int blk = blockIdx.x, s = 0;
  while (blk >= z.off[s + 1]) ++s;
  int chunk = blk - z.off[s];
  const float* batch = z.batch[s];
  const float* x = z.x[s];
  int N = z.N[s];
  int tid = threadIdx.x;
  int n0 = chunk * 64;
  for (int i = tid; i < 64 * 128; i += 256) {
    int nn = i >> 7;
    xl[i] = (n0 + nn < N) ? x[(long)(n0 + nn) * 128 + (i & 127)] : 0.f;
  }
  for (int i = tid; i < 64 * 64; i += 256) {
    int b = i >> 6, nn = i & 63;
    bl[nn * 65 + b] = (n0 + nn < N) ? batch[(long)b * N + n0 + nn] : 0.f;
  }
  __syncthreads();
  int cg = (tid & 31) * 4;
  int bg = (tid >> 5) * 8;
  float acc[8][4] = {};
  for (int nn = 0; nn < 64; ++nn) {
    float4 xv = *(const float4*)(xl + nn * 128 + cg);
#pragma unroll
    for (int i = 0; i < 8; ++i) {
      float bv = bl[nn * 65 + bg + i];
      acc[i][0] = fmaf(bv, xv.x, acc[i][0]);
      acc[i][1] = fmaf(bv, xv.y, acc[i][1]);
      acc[i][2] = fmaf(bv, xv.z, acc[i][2]);
      acc[i][3] = fmaf(bv, xv.w, acc[i][3]);
    }
  }
  float* zp = z.zp[s] + (long)chunk * 8192;
#pragma unroll
  for (int i = 0; i < 8; ++i) {
    float4 v = {acc[i][0], acc[i][1], acc[i][2], acc[i][3]};
    *(float4*)(zp + (bg + i) * 128 + cg) = v;
  }
}

// ---------------------------------------------------------------------------
// zgemm stage 2: 16 independent accumulators -> 16 loads in flight.
// ---------------------------------------------------------------------------
__global__ __launch_bounds__(256) void zreduce(
    const float* __restrict__ zp0, const float* __restrict__ zp1,
    const float* __restrict__ zp2, int G0, int G1, int G2,
    float s0, float s1, float s2, float* __restrict__ zpre)
{
  int blk = blockIdx.x;
  int ty = blk >> 5;
  int i = (blk & 31) * 256 + threadIdx.x;
  const float* zp = ty == 0 ? zp0 : (ty == 1 ? zp1 : zp2);
  int G = ty == 0 ? G0 : (ty == 1 ? G1 : G2);
  float sc = ty == 0 ? s0 : (ty == 1 ? s1 : s2);
  float a[16];
#pragma unroll
  for (int u = 0; u < 16; ++u) a[u] = 0.f;
  int g = 0;
  for (; g + 16 <= G; g += 16) {
#pragma unroll
    for (int u = 0; u < 16; ++u) a[u] += zp[(long)(g + u) * 8192 + i];
  }
  for (; g < G; ++g) a[0] += zp[(long)g * 8192 + i];
  float s = (((a[0] + a[1]) + (a[2] + a[3])) + ((a[4] + a[5]) + (a[6] + a[7])))
          + (((a[8] + a[9]) + (a[10] + a[11])) + ((a[12] + a[13]) + (a[14] + a[15])));
  zpre[ty * 8192 + i] = s * sc;
}

// ---------------------------------------------------------------------------
// Final LayerNorm over zpre[3*64,128] -> f32 out. 1 wave/row.
// ---------------------------------------------------------------------------
__global__ __launch_bounds__(256) void final_ln(
    const float* __restrict__ zpre, const float* __restrict__ gam,
    const float* __restrict__ bet, float* __restrict__ out)
{
  int row = blockIdx.x * 4 + (threadIdx.x >> 6);
  int lane = threadIdx.x & 63;
  if (row >= 192) return;
  int ty = row >> 6;
  long base = (long)row * 128;
  float x0 = zpre[base + lane], x1 = zpre[base + 64 + lane];
  float s = x0 + x1;
#pragma unroll
  for (int o = 32; o > 0; o >>= 1) s += __shfl_xor(s, o);
  float mu = s * 0.0078125f;
  float d0 = x0 - mu, d1 = x1 - mu;
  float q = d0 * d0 + d1 * d1;
#pragma unroll
  for (int o = 32; o > 0; o >>= 1) q += __shfl_xor(q, o);
  float r = rsqrtf(q * 0.0078125f + 1e-5f);
  out[base + lane]      = d0 * r * gam[ty * 128 + lane]      + bet[ty * 128 + lane];
  out[base + 64 + lane] = d1 * r * gam[ty * 128 + 64 + lane] + bet[ty * 128 + 64 + lane];
}

// ---------------------------------------------------------------------------
extern "C" void kernel_launch(void* const* d_in, const int* in_sizes, int n_in,
                              void* d_out, int out_size, void* d_ws, size_t ws_size,
                              hipStream_t stream)
{
  const float* batchp[3] = {(const float*)d_in[0], (const float*)d_in[1],
                            (const float*)d_in[2]};
  const float* emb[3] = {(const float*)d_in[3], (const float*)d_in[4],
                         (const float*)d_in[5]};
  const float* Wl   = (const float*)d_in[6];
  const float* Wr   = (const float*)d_in[7];
  const float* att  = (const float*)d_in[8];
  const float* bias = (const float*)d_in[9];
  const float* lng  = (const float*)d_in[10];
  const float* lnb  = (const float*)d_in[11];
  const float* outg = (const float*)d_in[12];
  const float* outb = (const float*)d_in[13];
  const int* eiP[8]; int E[8];
  for (int t = 0; t < 8; ++t) { eiP[t] = (const int*)d_in[14 + t]; E[t] = in_sizes[14 + t] / 2; }
  int Nn[3] = {in_sizes[3] / 128, in_sizes[4] / 128, in_sizes[5] / 128};
  long Ntot = (long)Nn[0] + Nn[1] + Nn[2];

  const int SI[5] = {1, 0, 2, 0, 0};
  const int DI[5] = {0, 1, 0, 2, 0};
  const int TMASK[3] = {0x35, 0x42, 0x88};  // gene: t0,t2,t4,t5; cpg: t1,t6; mirna: t3,t7

  char* p = (char*)d_ws;
  auto carve = [&](size_t b) -> void* {
    void* r = (void*)p; p += (b + 255) & ~(size_t)255; return r;
  };
  float* xf[3];
  for (int ty = 0; ty < 3; ++ty) xf[ty] = (float*)carve((size_t)Nn[ty] * 128 * 4);
  unsigned short* xb[3];
  for (int ty = 0; ty < 3; ++ty) xb[ty] = (unsigned short*)carve((size_t)Nn[ty] * 128 * 2);
  float* aggAll = (float*)carve((size_t)Ntot * 128 * 4);
  float* agg[3] = {aggAll, aggAll + (long)Nn[0] * 128, aggAll + ((long)Nn[0] + Nn[1]) * 128};
  // per-edge-type hs/hd (both bf16)
  unsigned short* hsT[5];
  unsigned short* hdT[5];
  char* projRegion = p;
  for (int t = 0; t < 5; ++t) hsT[t] = (unsigned short*)carve((size_t)Nn[SI[t]] * 128 * 2);
  for (int t = 0; t < 5; ++t) hdT[t] = (unsigned short*)carve((size_t)Nn[DI[t]] * 128 * 2);
  size_t projBytes = (size_t)(p - projRegion);
  float* zpre = (float*)carve(3 * 64 * 128 * 4);
  unsigned short* wtb = (unsigned short*)carve((size_t)32 * 16384 * 2);

  // bucketed CSR build (no global atomics)
  BArgs ba;
  {
    int cOff = 0, fOff = 0;
    for (int t = 0; t < 5; ++t) {
      int nd = Nn[DI[t]];
      ba.src[t] = eiP[t];
      ba.dst[t] = eiP[t] + E[t];
      ba.E[t] = E[t];
      ba.Nd[t] = nd;
      ba.NB[t] = (E[t] + 4095) / 4096;
      ba.B[t] = (nd + 127) / 128;
      ba.cnt[t] = (int*)carve((size_t)ba.B[t] * ba.NB[t] * 4);
      ba.tmp[t] = (int*)carve((size_t)E[t] * 4);
      ba.rs[t] = (int*)carve((size_t)(nd + 1) * 4);
      ba.csrc[t] = (int*)carve((size_t)E[t] * 4);
      ba.cOff[t] = cOff; cOff += ba.NB[t];
      ba.fOff[t] = fOff; fOff += ba.B[t];
    }
    ba.cOff[5] = cOff;
    ba.fOff[5] = fOff;
  }
  if ((size_t)(p - (char*)d_ws) > ws_size) return;  // workspace too small

  // zgemm partials alias the hs/hd region (dead after the layer loop)
  int nch[3];
  for (int ty = 0; ty < 3; ++ty) nch[ty] = (Nn[ty] + 63) / 64;
  float* zp[3];
  zp[0] = (float*)projRegion;
  zp[1] = zp[0] + (long)nch[0] * 8192;
  zp[2] = zp[1] + (long)nch[1] * 8192;
  // sanity: required partial bytes <= projBytes
  if ((size_t)(nch[0] + nch[1] + nch[2]) * 8192 * 4 > projBytes) return;

  auto WTB = [&](int l, int t, int which) {
    return wtb + ((long)((l * 8 + t) * 2 + which) << 14);
  };

  // 0) weight prep + emb casts
  prep_w<<<2048, 256, 0, stream>>>(Wl, Wr, wtb);
  {
    int n0 = Nn[0] * 32, n1 = Nn[1] * 32, n2 = Nn[2] * 32;
    cast_all<<<(int)((n0 + n1 + n2 + 255) / 256), 256, 0, stream>>>(
        emb[0], emb[1], emb[2], xb[0], xb[1], xb[2], n0, n1, n2);
  }

  // 1) CSR build (4 launches, zero global atomics)
  bucket_count<<<ba.cOff[5], 256, 0, stream>>>(ba);
  bucket_scan<<<5, 1024, 0, stream>>>(ba);
  bucket_scatter<<<ba.cOff[5], 256, 0, stream>>>(ba);
  bucket_finalize<<<ba.fOff[5], 256, 0, stream>>>(ba);

  const int GT[3][3] = {{0, 2, 4}, {1, -1, -1}, {3, -1, -1}};
  const int GN[3] = {3, 1, 1};

  for (int l = 0; l < 2; ++l) {
    const float* xinf[3] = {l == 0 ? emb[0] : xf[0],
                            l == 0 ? emb[1] : xf[1],
                            l == 0 ? emb[2] : xf[2]};
    // A) all 13 projections in one launch (self-convs STORE into agg)
    PArgs pa;
    {
      int off = 0, j = 0;
      auto add = [&](const unsigned short* x, const unsigned short* wt,
                     void* out, int N, int mode) {
        pa.j[j] = {x, wt, out, N, mode};
        pa.off[j] = off;
        off += (N + 127) / 128;
        ++j;
      };
      for (int t = 0; t < 5; ++t) add(xb[SI[t]], WTB(l, t, 0), hsT[t], Nn[SI[t]], 2);
      for (int t = 0; t < 5; ++t) add(xb[DI[t]], WTB(l, t, 1), hdT[t], Nn[DI[t]], 2);
      for (int ty = 0; ty < 3; ++ty) add(xb[ty], WTB(l, 5 + ty, 0), agg[ty], Nn[ty], 0);
      pa.off[13] = off;
      mproj_all<<<off, 256, 0, stream>>>(pa);
    }
    // B) all gathers in one launch (per-dst-row over its incident edge types)
    GArgs ga;
    {
      int off = 0;
      for (int s = 0; s < 3; ++s) {
        GSeg& sg = ga.s[s];
        sg.agg = agg[s];
        sg.Nd = Nn[s];
        sg.ntypes = GN[s];
        for (int k = 0; k < GN[s]; ++k) {
          int t = GT[s][k];
          sg.rs[k] = ba.rs[t];
          sg.csrc[k] = ba.csrc[t];
          sg.hs[k] = hsT[t];
          sg.hd[k] = hdT[t];
          sg.att[k] = att + (long)(l * 8 + t) * 128;
        }
        ga.off[s] = off;
        off += (Nn[s] + 3) / 4;
      }
      ga.off[3] = off;
      gat_gather_all<<<off, 256, 0, stream>>>(ga);
    }
    // C) LN update for all 3 types in one launch
    LArgs la;
    {
      int off = 0;
      for (int ty = 0; ty < 3; ++ty) {
        la.j[ty] = {xinf[ty], xf[ty], xb[ty], agg[ty],
                    bias + (long)l * 8 * 128, TMASK[ty],
                    lng + (long)(l * 3 + ty) * 128,
                    lnb + (long)(l * 3 + ty) * 128, Nn[ty]};
        la.off[ty] = off;
        off += (Nn[ty] + 3) / 4;
      }
      la.off[3] = off;
      update_ln_all<<<off, 256, 0, stream>>>(la);
    }
  }

  // final: z = LN(batch @ x / sqrt(N))
  ZArgs za;
  {
    int off = 0;
    for (int ty = 0; ty < 3; ++ty) {
      za.batch[ty] = batchp[ty];
      za.x[ty] = xf[ty];
      za.zp[ty] = zp[ty];
      za.N[ty] = Nn[ty];
      za.off[ty] = off;
      off += nch[ty];
    }
    za.off[3] = off;
    zgemm_all<<<off, 256, 0, stream>>>(za);
  }
  zreduce<<<96, 256, 0, stream>>>(
      zp[0], zp[1], zp[2], nch[0], nch[1], nch[2],
      (float)(1.0 / sqrt((double)Nn[0])), (float)(1.0 / sqrt((double)Nn[1])),
      (float)(1.0 / sqrt((double)Nn[2])), zpre);
  final_ln<<<48, 256, 0, stream>>>(zpre, outg, outb, (float*)d_out);
}

// Round 12
// 586.929 us; speedup vs baseline: 3.5376x; 1.0633x over previous
//
#include <hip/hip_runtime.h>
#include <math.h>

typedef __attribute__((ext_vector_type(4))) float f32x4;
typedef __attribute__((ext_vector_type(2))) float f32x2;
typedef __attribute__((ext_vector_type(8))) short bf16x8;

__device__ __forceinline__ float b2f(unsigned short u) {
  return __uint_as_float(((unsigned)u) << 16);
}
__device__ __forceinline__ unsigned short f2b(float f) {
  unsigned x = __float_as_uint(f);
  unsigned r = (x + 0x7FFFu + ((x >> 16) & 1u)) >> 16;
  return (unsigned short)r;
}
// unpack a uint holding 2 bf16 (lo = ch c, hi = ch c+1) to packed f32x2
__device__ __forceinline__ f32x2 bf2x2(unsigned u) {
  f32x2 r;
  r.x = __uint_as_float(u << 16);
  r.y = __uint_as_float(u & 0xFFFF0000u);
  return r;
}
__device__ __forceinline__ f32x2 pk_max(f32x2 a, f32x2 b) {
#if __has_builtin(__builtin_elementwise_max)
  return __builtin_elementwise_max(a, b);
#else
  f32x2 r; r.x = fmaxf(a.x, b.x); r.y = fmaxf(a.y, b.y); return r;
#endif
}
__device__ __forceinline__ f32x2 pk_fma(f32x2 a, f32x2 b, f32x2 c) {
#if __has_builtin(__builtin_elementwise_fma)
  return __builtin_elementwise_fma(a, b, c);
#else
  f32x2 r; r.x = fmaf(a.x, b.x, c.x); r.y = fmaf(a.y, b.y, c.y); return r;
#endif
}

// ---------------------------------------------------------------------------
// Weight prep: wt[mat][c][k] = bf16(W[mat>>1][k][c]);  mat=(l*8+t)*2+which
// ---------------------------------------------------------------------------
__global__ __launch_bounds__(256) void prep_w(
    const float* __restrict__ Wl, const float* __restrict__ Wr,
    unsigned short* __restrict__ wt)
{
  int elem = blockIdx.x * 256 + threadIdx.x;   // 0 .. 32*16384-1
  int mat = elem >> 14;
  int c = (elem >> 7) & 127;
  int k = elem & 127;
  const float* srcb = (mat & 1) ? Wr : Wl;
  wt[elem] = f2b(srcb[((long)(mat >> 1) << 14) + (k << 7) + c]);
}

// ---------------------------------------------------------------------------
// Cast emb (f32) -> xb (bf16), all 3 types fused (float4 chunks).
// ---------------------------------------------------------------------------
__global__ __launch_bounds__(256) void cast_all(
    const float* __restrict__ e0, const float* __restrict__ e1,
    const float* __restrict__ e2, unsigned short* __restrict__ x0,
    unsigned short* __restrict__ x1, unsigned short* __restrict__ x2,
    int n0, int n1, int n2)
{
  int i = blockIdx.x * 256 + threadIdx.x;
  const float* s; unsigned short* d; int loc = i;
  if (loc < n0) { s = e0; d = x0; }
  else {
    loc -= n0;
    if (loc < n1) { s = e1; d = x1; }
    else { loc -= n1; if (loc >= n2) return; s = e2; d = x2; }
  }
  float4 v = *(const float4*)(s + (long)loc * 4);
  ushort4 o = {f2b(v.x), f2b(v.y), f2b(v.z), f2b(v.w)};
  *(ushort4*)(d + (long)loc * 4) = o;
}

// ---------------------------------------------------------------------------
// MFMA projection tile (mode: 0 store f32, 2 store bf16).
// ---------------------------------------------------------------------------
__device__ __forceinline__ void mproj_tile(
    char* lx, char* lw, const unsigned short* __restrict__ xb,
    const unsigned short* __restrict__ wt, void* __restrict__ outv,
    int N, long r0, int tid, int mode)
{
#pragma unroll
  for (int i = 0; i < 8; ++i) {
    int ch = i * 256 + tid;              // 0..2047
    int row = ch >> 4, k0 = (ch & 15) << 3;
    uint4 xv = {0u, 0u, 0u, 0u};
    if (r0 + row < N) xv = *(const uint4*)(xb + (r0 + row) * 128 + k0);
    *(uint4*)(lx + ((row * 256 + k0 * 2) ^ ((row & 7) << 4))) = xv;
    uint4 wv = *(const uint4*)(wt + (long)ch * 8);
    *(uint4*)(lw + ((ch * 16) ^ ((row & 7) << 4))) = wv;
  }
  __syncthreads();

  const int lane = tid & 63;
  const int lr = lane & 15, lk = lane >> 4;
  const int rbase = (tid >> 6) * 32;
  f32x4 acc[2][8] = {};
#pragma unroll
  for (int kb = 0; kb < 4; ++kb) {
    int k = kb * 32 + lk * 8;
    int ra = rbase + lr;
    bf16x8 a0 = *(const bf16x8*)(lx + ((ra * 256 + k * 2) ^ ((ra & 7) << 4)));
    int rb = rbase + 16 + lr;
    bf16x8 a1 = *(const bf16x8*)(lx + ((rb * 256 + k * 2) ^ ((rb & 7) << 4)));
#pragma unroll
    for (int cc = 0; cc < 8; ++cc) {
      int col = cc * 16 + lr;
      bf16x8 bfr = *(const bf16x8*)(lw + ((col * 256 + k * 2) ^ ((col & 7) << 4)));
      acc[0][cc] = __builtin_amdgcn_mfma_f32_16x16x32_bf16(a0, bfr, acc[0][cc], 0, 0, 0);
      acc[1][cc] = __builtin_amdgcn_mfma_f32_16x16x32_bf16(a1, bfr, acc[1][cc], 0, 0, 0);
    }
  }
  __syncthreads();   // safe LDS reuse across segmented jobs
#pragma unroll
  for (int rt = 0; rt < 2; ++rt) {
    int rowb = rbase + rt * 16 + lk * 4;
#pragma unroll
    for (int cc = 0; cc < 8; ++cc) {
      int col = cc * 16 + lr;
#pragma unroll
      for (int q = 0; q < 4; ++q) {
        long row = r0 + rowb + q;
        if (row < N) {
          if (mode == 2)
            ((unsigned short*)outv)[row * 128 + col] = f2b(acc[rt][cc][q]);
          else
            ((float*)outv)[row * 128 + col] = acc[rt][cc][q];
        }
      }
    }
  }
}

struct PJob { const unsigned short* x; const unsigned short* wt; void* out; int N; int mode; };
struct PArgs { PJob j[13]; int off[14]; };

// All 13 projections of one layer in a single launch.
__global__ __launch_bounds__(256) void mproj_all(PArgs a)
{
  __shared__ __align__(16) char lx[32768];
  __shared__ __align__(16) char lw[32768];
  int blk = blockIdx.x, t = 0;
  while (blk >= a.off[t + 1]) ++t;
  const PJob& J = a.j[t];
  mproj_tile(lx, lw, J.x, J.wt, J.out, J.N, (long)(blk - a.off[t]) * 128,
             threadIdx.x, J.mode);
}

// ---------------------------------------------------------------------------
// Atomic-free bucketed CSR build (bucket = 128 dst nodes, 4096 edges/block).
// ---------------------------------------------------------------------------
struct BArgs {
  const int* src[5]; const int* dst[5];
  int* cnt[5];       // [B][NB] counts -> exclusive scan (bucket-major)
  int* tmp[5];       // E packed (dstLocal<<16 | src), bucket-sorted
  int* rs[5];        // row_start[Nd+1]
  int* csrc[5];      // E src ids, dst-sorted
  int E[5], Nd[5], NB[5], B[5];
  int cOff[6], fOff[6];
};

__global__ __launch_bounds__(256) void bucket_count(BArgs a)
{
  __shared__ int h[512];
  int blk = blockIdx.x, t = 0;
  while (blk >= a.cOff[t + 1]) ++t;
  int lb = blk - a.cOff[t];
  int B = a.B[t], NB = a.NB[t], E = a.E[t];
  for (int i = threadIdx.x; i < B; i += 256) h[i] = 0;
  __syncthreads();
  const int* dst = a.dst[t];
  int base = lb * 4096;
#pragma unroll
  for (int j = 0; j < 16; ++j) {
    int e = base + j * 256 + threadIdx.x;
    if (e < E) atomicAdd(&h[dst[e] >> 7], 1);   // LDS atomic
  }
  __syncthreads();
  int* cnt = a.cnt[t];
  for (int b = threadIdx.x; b < B; b += 256) cnt[b * NB + lb] = h[b];
}

// wave-shfl scan: 4 barriers per 16K chunk
__global__ __launch_bounds__(1024) void bucket_scan(BArgs a)
{
  int t = blockIdx.x;
  int n = a.B[t] * a.NB[t];
  int* dp = a.cnt[t];
  __shared__ int wsum[16];
  __shared__ int sbase, ctot;
  int tid = threadIdx.x;
  int lane = tid & 63, wid = tid >> 6;
  if (tid == 0) sbase = 0;
  __syncthreads();
  for (int chunk = 0; chunk < n; chunk += 16384) {
    int idx0 = chunk + tid * 16;
    int v[16], lsum = 0;
#pragma unroll
    for (int j = 0; j < 16; ++j) {
      v[j] = (idx0 + j < n) ? dp[idx0 + j] : 0;
      lsum += v[j];
    }
    int sc = lsum;                      // inclusive wave scan
#pragma unroll
    for (int o = 1; o < 64; o <<= 1) {
      int u = __shfl_up(sc, o);
      if (lane >= o) sc += u;
    }
    if (lane == 63) wsum[wid] = sc;
    __syncthreads();
    if (wid == 0) {
      int w = (lane < 16) ? wsum[lane] : 0;
      int s2 = w;
#pragma unroll
      for (int o = 1; o < 16; o <<= 1) {
        int u = __shfl_up(s2, o);
        if (lane >= o) s2 += u;
      }
      if (lane < 16) wsum[lane] = s2 - w;   // exclusive wave prefix
      if (lane == 15) ctot = s2;            // chunk total
    }
    __syncthreads();
    int excl = sbase + wsum[wid] + (sc - lsum);
#pragma unroll
    for (int j = 0; j < 16; ++j) {
      if (idx0 + j < n) dp[idx0 + j] = excl;
      excl += v[j];
    }
    __syncthreads();
    if (tid == 0) sbase += ctot;
    __syncthreads();
  }
}

__global__ __launch_bounds__(256) void bucket_scatter(BArgs a)
{
  __shared__ int cur[512];
  int blk = blockIdx.x, t = 0;
  while (blk >= a.cOff[t + 1]) ++t;
  int lb = blk - a.cOff[t];
  int B = a.B[t], NB = a.NB[t], E = a.E[t];
  const int* cnt = a.cnt[t];
  for (int b = threadIdx.x; b < B; b += 256) cur[b] = cnt[b * NB + lb];
  __syncthreads();
  const int* src = a.src[t];
  const int* dst = a.dst[t];
  int* tmp = a.tmp[t];
  int base = lb * 4096;
#pragma unroll
  for (int j = 0; j < 16; ++j) {
    int e = base + j * 256 + threadIdx.x;
    if (e < E) {
      int dv = dst[e];
      int pos = atomicAdd(&cur[dv >> 7], 1);    // LDS atomic
      tmp[pos] = ((dv & 127) << 16) | src[e];
    }
  }
}

__global__ __launch_bounds__(256) void bucket_finalize(BArgs a)
{
  __shared__ int h[128], sc[128], ex[128], cur[128];
  int blk = blockIdx.x, t = 0;
  while (blk >= a.fOff[t + 1]) ++t;
  int b = blk - a.fOff[t];
  int B = a.B[t], NB = a.NB[t], E = a.E[t], Nd = a.Nd[t];
  const int* cnt = a.cnt[t];
  const int* tmp = a.tmp[t];
  int* rs = a.rs[t];
  int* csrc = a.csrc[t];
  int tid = threadIdx.x;
  int beg = cnt[b * NB];
  int end = (b + 1 < B) ? cnt[(b + 1) * NB] : E;
  if (tid < 128) h[tid] = 0;
  __syncthreads();
  for (int i = beg + tid; i < end; i += 256)
    atomicAdd(&h[tmp[i] >> 16], 1);             // LDS atomic
  __syncthreads();
  if (tid < 128) sc[tid] = h[tid];
  __syncthreads();
#pragma unroll
  for (int off = 1; off < 128; off <<= 1) {
    int v = (tid < 128 && tid >= off) ? sc[tid - off] : 0;
    __syncthreads();
    if (tid < 128) sc[tid] += v;
    __syncthreads();
  }
  if (tid < 128) {
    ex[tid] = sc[tid] - h[tid];
    cur[tid] = 0;
    int dg = b * 128 + tid;
    if (dg < Nd) rs[dg] = beg + ex[tid];
  }
  if (b == B - 1 && tid == 0) rs[Nd] = E;
  __syncthreads();
  for (int i = beg + tid; i < end; i += 256) {
    int v = tmp[i];
    int d = v >> 16;
    int r = atomicAdd(&cur[d], 1);              // LDS atomic
    csrc[beg + ex[d] + r] = v & 0xFFFF;
  }
}

// ---------------------------------------------------------------------------
// Fused gather v2: wave owns one dst row; 16 lanes per edge (8 ch each),
// 4 edges concurrently per wave (quarter-waves). Packed-f32 channel math;
// one shfl_xor(1) per edge for the head logit; quarter streams combined per
// row via shfl_xor(16/32). Single non-atomic agg[d] += total.
// ---------------------------------------------------------------------------
struct GSeg {
  const int* rs[3]; const int* csrc[3];
  const unsigned short* hs[3]; const unsigned short* hd[3];
  const float* att[3];
  float* agg; int Nd; int ntypes;
};
struct GArgs { GSeg s[3]; int off[4]; };

__global__ __launch_bounds__(256) void gat_gather_all(GArgs g)
{
  int blk = blockIdx.x, si = 0;
  while (blk >= g.off[si + 1]) ++si;
  const GSeg& sg = g.s[si];
  int d = (blk - g.off[si]) * 4 + (threadIdx.x >> 6);
  if (d >= sg.Nd) return;
  int lane = threadIdx.x & 63;
  int q = lane >> 4, j = lane & 15;   // lane owns channels 8j..8j+7 (head j>>1)
  f32x2 T0 = {0.f, 0.f}, T1 = {0.f, 0.f}, T2 = {0.f, 0.f}, T3 = {0.f, 0.f};
  for (int k = 0; k < sg.ntypes; ++k) {
    const float* ap = sg.att[k] + 8 * j;
    float4 aa = *(const float4*)ap;
    float4 ab = *(const float4*)(ap + 4);
    f32x2 A0 = {aa.x, aa.y}, A1 = {aa.z, aa.w};
    f32x2 A2 = {ab.x, ab.y}, A3 = {ab.z, ab.w};
    uint4 hu = *((const uint4*)(sg.hd[k] + (long)d * 128) + j);
    f32x2 H0 = bf2x2(hu.x), H1 = bf2x2(hu.y);
    f32x2 H2 = bf2x2(hu.z), H3 = bf2x2(hu.w);
    const int* cs = sg.csrc[k];
    const unsigned short* hsk = sg.hs[k];
    int beg = sg.rs[k][d], end = sg.rs[k][d + 1];
    f32x2 n0 = {0.f, 0.f}, n1 = {0.f, 0.f}, n2 = {0.f, 0.f}, n3 = {0.f, 0.f};
    float D = 0.f;
    for (int i = beg + q; i < end; i += 4) {
      int s = cs[i];
      uint4 u = *((const uint4*)(hsk + (long)s * 128) + j);
      f32x2 h0 = bf2x2(u.x), h1 = bf2x2(u.y);
      f32x2 h2 = bf2x2(u.z), h3 = bf2x2(u.w);
      f32x2 v0 = h0 + H0, v1 = h1 + H1, v2 = h2 + H2, v3 = h3 + H3;
      v0 = pk_max(v0, v0 * 0.2f);
      v1 = pk_max(v1, v1 * 0.2f);
      v2 = pk_max(v2, v2 * 0.2f);
      v3 = pk_max(v3, v3 * 0.2f);
      f32x2 pv = pk_fma(v0, A0, pk_fma(v1, A1, pk_fma(v2, A2, v3 * A3)));
      float p = pv.x + pv.y;
      p += __shfl_xor(p, 1);            // head pair: lanes 2m, 2m+1
      float a = __expf(fminf(p, 60.f));
      f32x2 av = {a, a};
      n0 = pk_fma(h0, av, n0);
      n1 = pk_fma(h1, av, n1);
      n2 = pk_fma(h2, av, n2);
      n3 = pk_fma(h3, av, n3);
      D += a;
    }
    // combine the 4 quarter streams (flip lane bits 4 and 5)
#pragma unroll
    for (int o = 16; o < 64; o <<= 1) {
      n0.x += __shfl_xor(n0.x, o); n0.y += __shfl_xor(n0.y, o);
      n1.x += __shfl_xor(n1.x, o); n1.y += __shfl_xor(n1.y, o);
      n2.x += __shfl_xor(n2.x, o); n2.y += __shfl_xor(n2.y, o);
      n3.x += __shfl_xor(n3.x, o); n3.y += __shfl_xor(n3.y, o);
      D += __shfl_xor(D, o);
    }
    float inv = 1.f / (D + 1e-16f);
    f32x2 iv = {inv, inv};
    T0 = pk_fma(n0, iv, T0);
    T1 = pk_fma(n1, iv, T1);
    T2 = pk_fma(n2, iv, T2);
    T3 = pk_fma(n3, iv, T3);
  }
  if (q == 0) {                          // lanes 0..15 hold the full row
    float* apg = sg.agg + (long)d * 128 + 8 * j;
    float4 c0 = *(const float4*)apg;
    float4 c1 = *(const float4*)(apg + 4);
    c0.x += T0.x; c0.y += T0.y; c0.z += T1.x; c0.w += T1.y;
    c1.x += T2.x; c1.y += T2.y; c1.z += T3.x; c1.w += T3.y;
    *(float4*)apg = c0;
    *(float4*)(apg + 4) = c1;
  }
}

// ---------------------------------------------------------------------------
// Fused LayerNorm update for all 3 node types in one launch.
// ---------------------------------------------------------------------------
struct LJob {
  const float* xin; float* xf; unsigned short* xb;
  const float* agg; const float* biasl; int tmask;
  const float* gam; const float* bet; int N;
};
struct LArgs { LJob j[3]; int off[4]; };

__global__ __launch_bounds__(256) void update_ln_all(LArgs a)
{
  int blk = blockIdx.x, t = 0;
  while (blk >= a.off[t + 1]) ++t;
  const LJob& J = a.j[t];
  int row = (blk - a.off[t]) * 4 + (threadIdx.x >> 6);
  int lane = threadIdx.x & 63;
  if (row >= J.N) return;
  float bs0 = 0.f, bs1 = 0.f;
#pragma unroll
  for (int tt = 0; tt < 8; ++tt)
    if (J.tmask & (1 << tt)) {
      bs0 += J.biasl[tt * 128 + lane];
      bs1 += J.biasl[tt * 128 + 64 + lane];
    }
  long base = (long)row * 128;
  float v0 = J.agg[base + lane] + bs0, v1 = J.agg[base + 64 + lane] + bs1;
  v0 = v0 > 0.f ? v0 : __expf(v0) - 1.f;
  v1 = v1 > 0.f ? v1 : __expf(v1) - 1.f;
  float x0 = J.xin[base + lane] + v0, x1 = J.xin[base + 64 + lane] + v1;
  float s = x0 + x1;
#pragma unroll
  for (int o = 32; o > 0; o >>= 1) s += __shfl_xor(s, o);
  float mu = s * 0.0078125f;
  float dd0 = x0 - mu, dd1 = x1 - mu;
  float q = dd0 * dd0 + dd1 * dd1;
#pragma unroll
  for (int o = 32; o > 0; o >>= 1) q += __shfl_xor(q, o);
  float r = rsqrtf(q * 0.0078125f + 1e-5f);
  float y0 = dd0 * r * J.gam[lane] + J.bet[lane];
  float y1 = dd1 * r * J.gam[64 + lane] + J.bet[64 + lane];
  J.xf[base + lane] = y0; J.xf[base + 64 + lane] = y1;
  J.xb[base + lane] = f2b(y0); J.xb[base + 64 + lane] = f2b(y1);
}

// ---------------------------------------------------------------------------
// zgemm stage 1 fused over 3 types: one 64-row chunk per block, non-atomic.
// ---------------------------------------------------------------------------
struct ZArgs {
  const float* batch[3]; const float* x[3]; float* zp[3]; int N[3];
  int off[4];
};

__global__ __launch_bounds__(256) void zgemm_all(ZArgs z)
{
  __shared__ __align__(16) float xl[64 * 128];
  __shared__ __align__(16) float bl[64 * 65];
  int blk = blockIdx.x, s = 0;
  while (blk >= z.off[s + 1]) ++s;
  int chunk = blk - z.off[s];
  const float* batch = z.batch[s];
  const float* x = z.x[s];
  int N = z.N[s];
  int tid = threadIdx.x;
  int n0 = chunk * 64;
  for (int i = tid; i < 64 * 128; i += 256) {
    int nn = i >> 7;
    xl[i] = (n0 + nn < N) ? x[(long)(n0 + nn) * 128 + (i & 127)] : 0.f;
  }
  for (int i = tid; i < 64 * 64; i += 256) {
    int b = i >> 6, nn = i & 63;
    bl[nn * 65 + b] = (n0 + nn < N) ? batch[(long)b * N + n0 + nn] : 0.f;
  }
  __syncthreads();
  int cg = (tid & 31) * 4;
  int bg = (tid >> 5) * 8;
  float acc[8][4] = {};
  for (int nn = 0; nn < 64; ++nn) {
    float4 xv = *(const float4*)(xl + nn * 128 + cg);
#pragma unroll
    for (int i = 0; i < 8; ++i) {
      float bv = bl[nn * 65 + bg + i];
      acc[i][0] = fmaf(bv, xv.x, acc[i][0]);
      acc[i][1] = fmaf(bv, xv.y, acc[i][1]);
      acc[i][2] = fmaf(bv, xv.z, acc[i][2]);
      acc[i][3] = fmaf(bv, xv.w, acc[i][3]);
    }
  }
  float* zp = z.zp[s] + (long)chunk * 8192;
#pragma unroll
  for (int i = 0; i < 8; ++i) {
    float4 v = {acc[i][0], acc[i][1], acc[i][2], acc[i][3]};
    *(float4*)(zp + (bg + i) * 128 + cg) = v;
  }
}

// ---------------------------------------------------------------------------
// zgemm stage 2: 16 independent accumulators -> 16 loads in flight.
// ---------------------------------------------------------------------------
__global__ __launch_bounds__(256) void zreduce(
    const float* __restrict__ zp0, const float* __restrict__ zp1,
    const float* __restrict__ zp2, int G0, int G1, int G2,
    float s0, float s1, float s2, float* __restrict__ zpre)
{
  int blk = blockIdx.x;
  int ty = blk >> 5;
  int i = (blk & 31) * 256 + threadIdx.x;
  const float* zp = ty == 0 ? zp0 : (ty == 1 ? zp1 : zp2);
  int G = ty == 0 ? G0 : (ty == 1 ? G1 : G2);
  float sc = ty == 0 ? s0 : (ty == 1 ? s1 : s2);
  float a[16];
#pragma unroll
  for (int u = 0; u < 16; ++u) a[u] = 0.f;
  int g = 0;
  for (; g + 16 <= G; g += 16) {
#pragma unroll
    for (int u = 0; u < 16; ++u) a[u] += zp[(long)(g + u) * 8192 + i];
  }
  for (; g < G; ++g) a[0] += zp[(long)g * 8192 + i];
  float s = (((a[0] + a[1]) + (a[2] + a[3])) + ((a[4] + a[5]) + (a[6] + a[7])))
          + (((a[8] + a[9]) + (a[10] + a[11])) + ((a[12] + a[13]) + (a[14] + a[15])));
  zpre[ty * 8192 + i] = s * sc;
}

// ---------------------------------------------------------------------------
// Final LayerNorm over zpre[3*64,128] -> f32 out. 1 wave/row.
// ---------------------------------------------------------------------------
__global__ __launch_bounds__(256) void final_ln(
    const float* __restrict__ zpre, const float* __restrict__ gam,
    const float* __restrict__ bet, float* __restrict__ out)
{
  int row = blockIdx.x * 4 + (threadIdx.x >> 6);
  int lane = threadIdx.x & 63;
  if (row >= 192) return;
  int ty = row >> 6;
  long base = (long)row * 128;
  float x0 = zpre[base + lane], x1 = zpre[base + 64 + lane];
  float s = x0 + x1;
#pragma unroll
  for (int o = 32; o > 0; o >>= 1) s += __shfl_xor(s, o);
  float mu = s * 0.0078125f;
  float d0 = x0 - mu, d1 = x1 - mu;
  float q = d0 * d0 + d1 * d1;
#pragma unroll
  for (int o = 32; o > 0; o >>= 1) q += __shfl_xor(q, o);
  float r = rsqrtf(q * 0.0078125f + 1e-5f);
  out[base + lane]      = d0 * r * gam[ty * 128 + lane]      + bet[ty * 128 + lane];
  out[base + 64 + lane] = d1 * r * gam[ty * 128 + 64 + lane] + bet[ty * 128 + 64 + lane];
}

// ---------------------------------------------------------------------------
extern "C" void kernel_launch(void* const* d_in, const int* in_sizes, int n_in,
                              void* d_out, int out_size, void* d_ws, size_t ws_size,
                              hipStream_t stream)
{
  const float* batchp[3] = {(const float*)d_in[0], (const float*)d_in[1],
                            (const float*)d_in[2]};
  const float* emb[3] = {(const float*)d_in[3], (const float*)d_in[4],
                         (const float*)d_in[5]};
  const float* Wl   = (const float*)d_in[6];
  const float* Wr   = (const float*)d_in[7];
  const float* att  = (const float*)d_in[8];
  const float* bias = (const float*)d_in[9];
  const float* lng  = (const float*)d_in[10];
  const float* lnb  = (const float*)d_in[11];
  const float* outg = (const float*)d_in[12];
  const float* outb = (const float*)d_in[13];
  const int* eiP[8]; int E[8];
  for (int t = 0; t < 8; ++t) { eiP[t] = (const int*)d_in[14 + t]; E[t] = in_sizes[14 + t] / 2; }
  int Nn[3] = {in_sizes[3] / 128, in_sizes[4] / 128, in_sizes[5] / 128};
  long Ntot = (long)Nn[0] + Nn[1] + Nn[2];

  const int SI[5] = {1, 0, 2, 0, 0};
  const int DI[5] = {0, 1, 0, 2, 0};
  const int TMASK[3] = {0x35, 0x42, 0x88};  // gene: t0,t2,t4,t5; cpg: t1,t6; mirna: t3,t7

  char* p = (char*)d_ws;
  auto carve = [&](size_t b) -> void* {
    void* r = (void*)p; p += (b + 255) & ~(size_t)255; return r;
  };
  float* xf[3];
  for (int ty = 0; ty < 3; ++ty) xf[ty] = (float*)carve((size_t)Nn[ty] * 128 * 4);
  unsigned short* xb[3];
  for (int ty = 0; ty < 3; ++ty) xb[ty] = (unsigned short*)carve((size_t)Nn[ty] * 128 * 2);
  float* aggAll = (float*)carve((size_t)Ntot * 128 * 4);
  float* agg[3] = {aggAll, aggAll + (long)Nn[0] * 128, aggAll + ((long)Nn[0] + Nn[1]) * 128};
  // per-edge-type hs/hd (both bf16)
  unsigned short* hsT[5];
  unsigned short* hdT[5];
  char* projRegion = p;
  for (int t = 0; t < 5; ++t) hsT[t] = (unsigned short*)carve((size_t)Nn[SI[t]] * 128 * 2);
  for (int t = 0; t < 5; ++t) hdT[t] = (unsigned short*)carve((size_t)Nn[DI[t]] * 128 * 2);
  size_t projBytes = (size_t)(p - projRegion);
  float* zpre = (float*)carve(3 * 64 * 128 * 4);
  unsigned short* wtb = (unsigned short*)carve((size_t)32 * 16384 * 2);

  // bucketed CSR build (no global atomics)
  BArgs ba;
  {
    int cOff = 0, fOff = 0;
    for (int t = 0; t < 5; ++t) {
      int nd = Nn[DI[t]];
      ba.src[t] = eiP[t];
      ba.dst[t] = eiP[t] + E[t];
      ba.E[t] = E[t];
      ba.Nd[t] = nd;
      ba.NB[t] = (E[t] + 4095) / 4096;
      ba.B[t] = (nd + 127) / 128;
      ba.cnt[t] = (int*)carve((size_t)ba.B[t] * ba.NB[t] * 4);
      ba.tmp[t] = (int*)carve((size_t)E[t] * 4);
      ba.rs[t] = (int*)carve((size_t)(nd + 1) * 4);
      ba.csrc[t] = (int*)carve((size_t)E[t] * 4);
      ba.cOff[t] = cOff; cOff += ba.NB[t];
      ba.fOff[t] = fOff; fOff += ba.B[t];
    }
    ba.cOff[5] = cOff;
    ba.fOff[5] = fOff;
  }
  if ((size_t)(p - (char*)d_ws) > ws_size) return;  // workspace too small

  // zgemm partials alias the hs/hd region (dead after the layer loop)
  int nch[3];
  for (int ty = 0; ty < 3; ++ty) nch[ty] = (Nn[ty] + 63) / 64;
  float* zp[3];
  zp[0] = (float*)projRegion;
  zp[1] = zp[0] + (long)nch[0] * 8192;
  zp[2] = zp[1] + (long)nch[1] * 8192;
  if ((size_t)(nch[0] + nch[1] + nch[2]) * 8192 * 4 > projBytes) return;

  auto WTB = [&](int l, int t, int which) {
    return wtb + ((long)((l * 8 + t) * 2 + which) << 14);
  };

  // 0) weight prep + emb casts
  prep_w<<<2048, 256, 0, stream>>>(Wl, Wr, wtb);
  {
    int n0 = Nn[0] * 32, n1 = Nn[1] * 32, n2 = Nn[2] * 32;
    cast_all<<<(int)((n0 + n1 + n2 + 255) / 256), 256, 0, stream>>>(
        emb[0], emb[1], emb[2], xb[0], xb[1], xb[2], n0, n1, n2);
  }

  // 1) CSR build (4 launches, zero global atomics)
  bucket_count<<<ba.cOff[5], 256, 0, stream>>>(ba);
  bucket_scan<<<5, 1024, 0, stream>>>(ba);
  bucket_scatter<<<ba.cOff[5], 256, 0, stream>>>(ba);
  bucket_finalize<<<ba.fOff[5], 256, 0, stream>>>(ba);

  const int GT[3][3] = {{0, 2, 4}, {1, -1, -1}, {3, -1, -1}};
  const int GN[3] = {3, 1, 1};

  for (int l = 0; l < 2; ++l) {
    const float* xinf[3] = {l == 0 ? emb[0] : xf[0],
                            l == 0 ? emb[1] : xf[1],
                            l == 0 ? emb[2] : xf[2]};
    // A) all 13 projections in one launch (self-convs STORE into agg)
    PArgs pa;
    {
      int off = 0, j = 0;
      auto add = [&](const unsigned short* x, const unsigned short* wt,
                     void* out, int N, int mode) {
        pa.j[j] = {x, wt, out, N, mode};
        pa.off[j] = off;
        off += (N + 127) / 128;
        ++j;
      };
      for (int t = 0; t < 5; ++t) add(xb[SI[t]], WTB(l, t, 0), hsT[t], Nn[SI[t]], 2);
      for (int t = 0; t < 5; ++t) add(xb[DI[t]], WTB(l, t, 1), hdT[t], Nn[DI[t]], 2);
      for (int ty = 0; ty < 3; ++ty) add(xb[ty], WTB(l, 5 + ty, 0), agg[ty], Nn[ty], 0);
      pa.off[13] = off;
      mproj_all<<<off, 256, 0, stream>>>(pa);
    }
    // B) all gathers in one launch (per-dst-row over its incident edge types)
    GArgs ga;
    {
      int off = 0;
      for (int s = 0; s < 3; ++s) {
        GSeg& sg = ga.s[s];
        sg.agg = agg[s];
        sg.Nd = Nn[s];
        sg.ntypes = GN[s];
        for (int k = 0; k < GN[s]; ++k) {
          int t = GT[s][k];
          sg.rs[k] = ba.rs[t];
          sg.csrc[k] = ba.csrc[t];
          sg.hs[k] = hsT[t];
          sg.hd[k] = hdT[t];
          sg.att[k] = att + (long)(l * 8 + t) * 128;
        }
        ga.off[s] = off;
        off += (Nn[s] + 3) / 4;
      }
      ga.off[3] = off;
      gat_gather_all<<<off, 256, 0, stream>>>(ga);
    }
    // C) LN update for all 3 types in one launch
    LArgs la;
    {
      int off = 0;
      for (int ty = 0; ty < 3; ++ty) {
        la.j[ty] = {xinf[ty], xf[ty], xb[ty], agg[ty],
                    bias + (long)l * 8 * 128, TMASK[ty],
                    lng + (long)(l * 3 + ty) * 128,
                    lnb + (long)(l * 3 + ty) * 128, Nn[ty]};
        la.off[ty] = off;
        off += (Nn[ty] + 3) / 4;
      }
      la.off[3] = off;
      update_ln_all<<<off, 256, 0, stream>>>(la);
    }
  }

  // final: z = LN(batch @ x / sqrt(N))
  ZArgs za;
  {
    int off = 0;
    for (int ty = 0; ty < 3; ++ty) {
      za.batch[ty] = batchp[ty];
      za.x[ty] = xf[ty];
      za.zp[ty] = zp[ty];
      za.N[ty] = Nn[ty];
      za.off[ty] = off;
      off += nch[ty];
    }
    za.off[3] = off;
    zgemm_all<<<off, 256, 0, stream>>>(za);
  }
  zreduce<<<96, 256, 0, stream>>>(
      zp[0], zp[1], zp[2], nch[0], nch[1], nch[2],
      (float)(1.0 / sqrt((double)Nn[0])), (float)(1.0 / sqrt((double)Nn[1])),
      (float)(1.0 / sqrt((double)Nn[2])), zpre);
  final_ln<<<48, 256, 0, stream>>>(zpre, outg, outb, (float*)d_out);
}

// Round 14
// 578.324 us; speedup vs baseline: 3.5902x; 1.0149x over previous
//
#include <hip/hip_runtime.h>
#include <math.h>

typedef __attribute__((ext_vector_type(4))) float f32x4;
typedef __attribute__((ext_vector_type(2))) float f32x2;
typedef __attribute__((ext_vector_type(8))) short bf16x8;

__device__ __forceinline__ float b2f(unsigned short u) {
  return __uint_as_float(((unsigned)u) << 16);
}
__device__ __forceinline__ unsigned short f2b(float f) {
  unsigned x = __float_as_uint(f);
  unsigned r = (x + 0x7FFFu + ((x >> 16) & 1u)) >> 16;
  return (unsigned short)r;
}
// unpack a uint holding 2 bf16 (lo = ch c, hi = ch c+1) to packed f32x2
__device__ __forceinline__ f32x2 bf2x2(unsigned u) {
  f32x2 r;
  r.x = __uint_as_float(u << 16);
  r.y = __uint_as_float(u & 0xFFFF0000u);
  return r;
}
__device__ __forceinline__ f32x2 pk_max(f32x2 a, f32x2 b) {
#if __has_builtin(__builtin_elementwise_max)
  return __builtin_elementwise_max(a, b);
#else
  f32x2 r; r.x = fmaxf(a.x, b.x); r.y = fmaxf(a.y, b.y); return r;
#endif
}
__device__ __forceinline__ f32x2 pk_fma(f32x2 a, f32x2 b, f32x2 c) {
#if __has_builtin(__builtin_elementwise_fma)
  return __builtin_elementwise_fma(a, b, c);
#else
  f32x2 r; r.x = fmaf(a.x, b.x, c.x); r.y = fmaf(a.y, b.y, c.y); return r;
#endif
}

// ---- fp8 e4m3 (OCP) helpers: HW cvt on gfx950 (hi-select must be a
// compile-time constant -> template), software fallback otherwise ----------
#if __has_builtin(__builtin_amdgcn_cvt_pk_f32_fp8)
template<bool HI>
__device__ __forceinline__ f32x2 fp8x2_dec(unsigned w) {
  return __builtin_amdgcn_cvt_pk_f32_fp8(w, HI);
}
#else
__device__ __forceinline__ float fp8_dec1(unsigned b) {
  unsigned s = b >> 7, e = (b >> 3) & 15, m = b & 7;
  float v = (e == 0) ? (float)m * 0.001953125f
                     : __uint_as_float(((e - 7 + 127) << 23) | (m << 20));
  return s ? -v : v;
}
template<bool HI>
__device__ __forceinline__ f32x2 fp8x2_dec(unsigned w) {
  unsigned h = HI ? (w >> 16) : w;
  f32x2 r; r.x = fp8_dec1(h & 0xFF); r.y = fp8_dec1((h >> 8) & 0xFF);
  return r;
}
#endif
#if __has_builtin(__builtin_amdgcn_cvt_pk_fp8_f32)
template<bool HI>
__device__ __forceinline__ int fp8x2_enc(float a, float b, int old) {
  return __builtin_amdgcn_cvt_pk_fp8_f32(a, b, old, HI);
}
#else
__device__ __forceinline__ unsigned fp8_enc1(float f) {
  unsigned s = (__float_as_uint(f) >> 31) << 7;
  float a = fabsf(f);
  if (a >= 448.f) return s | 0x7E;
  if (a < 0.015625f) {                       // below min normal 2^-6
    int m = (int)(a * 512.f + 0.5f);         // subnormal m * 2^-9
    return s | (unsigned)(m > 7 ? 7 : m);
  }
  int ex; (void)frexpf(a, &ex);
  int E = ex - 1;
  float sig = a * exp2f((float)(-E));
  int m = (int)((sig - 1.f) * 8.f + 0.5f);
  if (m == 8) { m = 0; E += 1; }
  if (E > 8) return s | 0x7E;
  return s | (unsigned)((E + 7) << 3) | (unsigned)m;
}
template<bool HI>
__device__ __forceinline__ int fp8x2_enc(float a, float b, int old) {
  unsigned pk = fp8_enc1(a) | (fp8_enc1(b) << 8);
  return HI ? ((old & 0x0000FFFF) | (int)(pk << 16))
            : ((old & (int)0xFFFF0000) | (int)pk);
}
#endif

// ---------------------------------------------------------------------------
// Weight prep: wt[mat][c][k] = bf16(W[mat>>1][k][c]);  mat=(l*8+t)*2+which
// ---------------------------------------------------------------------------
__global__ __launch_bounds__(256) void prep_w(
    const float* __restrict__ Wl, const float* __restrict__ Wr,
    unsigned short* __restrict__ wt)
{
  int elem = blockIdx.x * 256 + threadIdx.x;   // 0 .. 32*16384-1
  int mat = elem >> 14;
  int c = (elem >> 7) & 127;
  int k = elem & 127;
  const float* srcb = (mat & 1) ? Wr : Wl;
  wt[elem] = f2b(srcb[((long)(mat >> 1) << 14) + (k << 7) + c]);
}

// ---------------------------------------------------------------------------
// Cast emb (f32) -> xb (bf16), all 3 types fused (float4 chunks).
// ---------------------------------------------------------------------------
__global__ __launch_bounds__(256) void cast_all(
    const float* __restrict__ e0, const float* __restrict__ e1,
    const float* __restrict__ e2, unsigned short* __restrict__ x0,
    unsigned short* __restrict__ x1, unsigned short* __restrict__ x2,
    int n0, int n1, int n2)
{
  int i = blockIdx.x * 256 + threadIdx.x;
  const float* s; unsigned short* d; int loc = i;
  if (loc < n0) { s = e0; d = x0; }
  else {
    loc -= n0;
    if (loc < n1) { s = e1; d = x1; }
    else { loc -= n1; if (loc >= n2) return; s = e2; d = x2; }
  }
  float4 v = *(const float4*)(s + (long)loc * 4);
  ushort4 o = {f2b(v.x), f2b(v.y), f2b(v.z), f2b(v.w)};
  *(ushort4*)(d + (long)loc * 4) = o;
}

// ---------------------------------------------------------------------------
// Cast hs region (bf16) -> fp8 e4m3, 8 elements/thread (contiguous tables).
// ---------------------------------------------------------------------------
__global__ __launch_bounds__(256) void cast_fp8(
    const unsigned short* __restrict__ src, unsigned char* __restrict__ dst,
    long n8)
{
  long i = (long)blockIdx.x * 256 + threadIdx.x;
  if (i >= n8) return;
  uint4 v = *(const uint4*)(src + i * 8);
  f32x2 a = bf2x2(v.x), b = bf2x2(v.y), c = bf2x2(v.z), d = bf2x2(v.w);
  int lo = 0, hi = 0;
  lo = fp8x2_enc<false>(a.x, a.y, lo);
  lo = fp8x2_enc<true>(b.x, b.y, lo);
  hi = fp8x2_enc<false>(c.x, c.y, hi);
  hi = fp8x2_enc<true>(d.x, d.y, hi);
  uint2 o = {(unsigned)lo, (unsigned)hi};
  *(uint2*)(dst + i * 8) = o;
}

// ---------------------------------------------------------------------------
// MFMA projection tile (mode: 0 store f32, 2 store bf16).
// ---------------------------------------------------------------------------
__device__ __forceinline__ void mproj_tile(
    char* lx, char* lw, const unsigned short* __restrict__ xb,
    const unsigned short* __restrict__ wt, void* __restrict__ outv,
    int N, long r0, int tid, int mode)
{
#pragma unroll
  for (int i = 0; i < 8; ++i) {
    int ch = i * 256 + tid;              // 0..2047
    int row = ch >> 4, k0 = (ch & 15) << 3;
    uint4 xv = {0u, 0u, 0u, 0u};
    if (r0 + row < N) xv = *(const uint4*)(xb + (r0 + row) * 128 + k0);
    *(uint4*)(lx + ((row * 256 + k0 * 2) ^ ((row & 7) << 4))) = xv;
    uint4 wv = *(const uint4*)(wt + (long)ch * 8);
    *(uint4*)(lw + ((ch * 16) ^ ((row & 7) << 4))) = wv;
  }
  __syncthreads();

  const int lane = tid & 63;
  const int lr = lane & 15, lk = lane >> 4;
  const int rbase = (tid >> 6) * 32;
  f32x4 acc[2][8] = {};
#pragma unroll
  for (int kb = 0; kb < 4; ++kb) {
    int k = kb * 32 + lk * 8;
    int ra = rbase + lr;
    bf16x8 a0 = *(const bf16x8*)(lx + ((ra * 256 + k * 2) ^ ((ra & 7) << 4)));
    int rb = rbase + 16 + lr;
    bf16x8 a1 = *(const bf16x8*)(lx + ((rb * 256 + k * 2) ^ ((rb & 7) << 4)));
#pragma unroll
    for (int cc = 0; cc < 8; ++cc) {
      int col = cc * 16 + lr;
      bf16x8 bfr = *(const bf16x8*)(lw + ((col * 256 + k * 2) ^ ((col & 7) << 4)));
      acc[0][cc] = __builtin_amdgcn_mfma_f32_16x16x32_bf16(a0, bfr, acc[0][cc], 0, 0, 0);
      acc[1][cc] = __builtin_amdgcn_mfma_f32_16x16x32_bf16(a1, bfr, acc[1][cc], 0, 0, 0);
    }
  }
  __syncthreads();   // safe LDS reuse across segmented jobs
#pragma unroll
  for (int rt = 0; rt < 2; ++rt) {
    int rowb = rbase + rt * 16 + lk * 4;
#pragma unroll
    for (int cc = 0; cc < 8; ++cc) {
      int col = cc * 16 + lr;
#pragma unroll
      for (int q = 0; q < 4; ++q) {
        long row = r0 + rowb + q;
        if (row < N) {
          if (mode == 2)
            ((unsigned short*)outv)[row * 128 + col] = f2b(acc[rt][cc][q]);
          else
            ((float*)outv)[row * 128 + col] = acc[rt][cc][q];
        }
      }
    }
  }
}

struct PJob { const unsigned short* x; const unsigned short* wt; void* out; int N; int mode; };
struct PArgs { PJob j[13]; int off[14]; };

// All 13 projections of one layer in a single launch.
__global__ __launch_bounds__(256) void mproj_all(PArgs a)
{
  __shared__ __align__(16) char lx[32768];
  __shared__ __align__(16) char lw[32768];
  int blk = blockIdx.x, t = 0;
  while (blk >= a.off[t + 1]) ++t;
  const PJob& J = a.j[t];
  mproj_tile(lx, lw, J.x, J.wt, J.out, J.N, (long)(blk - a.off[t]) * 128,
             threadIdx.x, J.mode);
}

// ---------------------------------------------------------------------------
// Atomic-free bucketed CSR build (bucket = 128 dst nodes, 4096 edges/block).
// ---------------------------------------------------------------------------
struct BArgs {
  const int* src[5]; const int* dst[5];
  int* cnt[5];       // [B][NB] counts -> exclusive scan (bucket-major)
  int* tmp[5];       // E packed (dstLocal<<16 | src), bucket-sorted
  int* rs[5];        // row_start[Nd+1]
  int* csrc[5];      // E src ids, dst-sorted
  int E[5], Nd[5], NB[5], B[5];
  int cOff[6], fOff[6];
};

__global__ __launch_bounds__(256) void bucket_count(BArgs a)
{
  __shared__ int h[512];
  int blk = blockIdx.x, t = 0;
  while (blk >= a.cOff[t + 1]) ++t;
  int lb = blk - a.cOff[t];
  int B = a.B[t], NB = a.NB[t], E = a.E[t];
  for (int i = threadIdx.x; i < B; i += 256) h[i] = 0;
  __syncthreads();
  const int* dst = a.dst[t];
  int base = lb * 4096;
#pragma unroll
  for (int j = 0; j < 16; ++j) {
    int e = base + j * 256 + threadIdx.x;
    if (e < E) atomicAdd(&h[dst[e] >> 7], 1);   // LDS atomic
  }
  __syncthreads();
  int* cnt = a.cnt[t];
  for (int b = threadIdx.x; b < B; b += 256) cnt[b * NB + lb] = h[b];
}

// wave-shfl scan: 4 barriers per 16K chunk
__global__ __launch_bounds__(1024) void bucket_scan(BArgs a)
{
  int t = blockIdx.x;
  int n = a.B[t] * a.NB[t];
  int* dp = a.cnt[t];
  __shared__ int wsum[16];
  __shared__ int sbase, ctot;
  int tid = threadIdx.x;
  int lane = tid & 63, wid = tid >> 6;
  if (tid == 0) sbase = 0;
  __syncthreads();
  for (int chunk = 0; chunk < n; chunk += 16384) {
    int idx0 = chunk + tid * 16;
    int v[16], lsum = 0;
#pragma unroll
    for (int j = 0; j < 16; ++j) {
      v[j] = (idx0 + j < n) ? dp[idx0 + j] : 0;
      lsum += v[j];
    }
    int sc = lsum;                      // inclusive wave scan
#pragma unroll
    for (int o = 1; o < 64; o <<= 1) {
      int u = __shfl_up(sc, o);
      if (lane >= o) sc += u;
    }
    if (lane == 63) wsum[wid] = sc;
    __syncthreads();
    if (wid == 0) {
      int w = (lane < 16) ? wsum[lane] : 0;
      int s2 = w;
#pragma unroll
      for (int o = 1; o < 16; o <<= 1) {
        int u = __shfl_up(s2, o);
        if (lane >= o) s2 += u;
      }
      if (lane < 16) wsum[lane] = s2 - w;   // exclusive wave prefix
      if (lane == 15) ctot = s2;            // chunk total
    }
    __syncthreads();
    int excl = sbase + wsum[wid] + (sc - lsum);
#pragma unroll
    for (int j = 0; j < 16; ++j) {
      if (idx0 + j < n) dp[idx0 + j] = excl;
      excl += v[j];
    }
    __syncthreads();
    if (tid == 0) sbase += ctot;
    __syncthreads();
  }
}

__global__ __launch_bounds__(256) void bucket_scatter(BArgs a)
{
  __shared__ int cur[512];
  int blk = blockIdx.x, t = 0;
  while (blk >= a.cOff[t + 1]) ++t;
  int lb = blk - a.cOff[t];
  int B = a.B[t], NB = a.NB[t], E = a.E[t];
  const int* cnt = a.cnt[t];
  for (int b = threadIdx.x; b < B; b += 256) cur[b] = cnt[b * NB + lb];
  __syncthreads();
  const int* src = a.src[t];
  const int* dst = a.dst[t];
  int* tmp = a.tmp[t];
  int base = lb * 4096;
#pragma unroll
  for (int j = 0; j < 16; ++j) {
    int e = base + j * 256 + threadIdx.x;
    if (e < E) {
      int dv = dst[e];
      int pos = atomicAdd(&cur[dv >> 7], 1);    // LDS atomic
      tmp[pos] = ((dv & 127) << 16) | src[e];
    }
  }
}

__global__ __launch_bounds__(256) void bucket_finalize(BArgs a)
{
  __shared__ int h[128], sc[128], ex[128], cur[128];
  int blk = blockIdx.x, t = 0;
  while (blk >= a.fOff[t + 1]) ++t;
  int b = blk - a.fOff[t];
  int B = a.B[t], NB = a.NB[t], E = a.E[t], Nd = a.Nd[t];
  const int* cnt = a.cnt[t];
  const int* tmp = a.tmp[t];
  int* rs = a.rs[t];
  int* csrc = a.csrc[t];
  int tid = threadIdx.x;
  int beg = cnt[b * NB];
  int end = (b + 1 < B) ? cnt[(b + 1) * NB] : E;
  if (tid < 128) h[tid] = 0;
  __syncthreads();
  for (int i = beg + tid; i < end; i += 256)
    atomicAdd(&h[tmp[i] >> 16], 1);             // LDS atomic
  __syncthreads();
  if (tid < 128) sc[tid] = h[tid];
  __syncthreads();
#pragma unroll
  for (int off = 1; off < 128; off <<= 1) {
    int v = (tid < 128 && tid >= off) ? sc[tid - off] : 0;
    __syncthreads();
    if (tid < 128) sc[tid] += v;
    __syncthreads();
  }
  if (tid < 128) {
    ex[tid] = sc[tid] - h[tid];
    cur[tid] = 0;
    int dg = b * 128 + tid;
    if (dg < Nd) rs[dg] = beg + ex[tid];
  }
  if (b == B - 1 && tid == 0) rs[Nd] = E;
  __syncthreads();
  for (int i = beg + tid; i < end; i += 256) {
    int v = tmp[i];
    int d = v >> 16;
    int r = atomicAdd(&cur[d], 1);              // LDS atomic
    csrc[beg + ex[d] + r] = v & 0xFFFF;
  }
}

// ---------------------------------------------------------------------------
// Fused gather v3: hs in fp8 e4m3 (128B rows). Wave owns one dst row; 16
// lanes/edge (8 ch each), 4 quarter-streams, 2-deep unroll (8 rows in
// flight). Packed-f32 math; one shfl_xor(1) per edge; quarter streams
// combined per row via shfl_xor(16/32). Single non-atomic agg[d] += total.
// ---------------------------------------------------------------------------
struct GSeg {
  const int* rs[3]; const int* csrc[3];
  const unsigned char* hs[3]; const unsigned short* hd[3];
  const float* att[3];
  float* agg; int Nd; int ntypes;
};
struct GArgs { GSeg s[3]; int off[4]; };

__global__ __launch_bounds__(256) void gat_gather_all(GArgs g)
{
  int blk = blockIdx.x, si = 0;
  while (blk >= g.off[si + 1]) ++si;
  const GSeg& sg = g.s[si];
  int d = (blk - g.off[si]) * 4 + (threadIdx.x >> 6);
  if (d >= sg.Nd) return;
  int lane = threadIdx.x & 63;
  int q = lane >> 4, j = lane & 15;   // lane owns channels 8j..8j+7 (head j>>1)
  f32x2 T0 = {0.f, 0.f}, T1 = {0.f, 0.f}, T2 = {0.f, 0.f}, T3 = {0.f, 0.f};
  for (int k = 0; k < sg.ntypes; ++k) {
    const float* ap = sg.att[k] + 8 * j;
    float4 aa = *(const float4*)ap;
    float4 ab = *(const float4*)(ap + 4);
    f32x2 A0 = {aa.x, aa.y}, A1 = {aa.z, aa.w};
    f32x2 A2 = {ab.x, ab.y}, A3 = {ab.z, ab.w};
    uint4 hu = *((const uint4*)(sg.hd[k] + (long)d * 128) + j);
    f32x2 H0 = bf2x2(hu.x), H1 = bf2x2(hu.y);
    f32x2 H2 = bf2x2(hu.z), H3 = bf2x2(hu.w);
    const int* cs = sg.csrc[k];
    const unsigned char* hsk = sg.hs[k];
    int beg = sg.rs[k][d], end = sg.rs[k][d + 1];
    f32x2 n0 = {0.f, 0.f}, n1 = {0.f, 0.f}, n2 = {0.f, 0.f}, n3 = {0.f, 0.f};
    float D = 0.f;

#define GA_EDGE(U)                                                          \
    {                                                                       \
      f32x2 h0 = fp8x2_dec<false>((U).x), h1 = fp8x2_dec<true>((U).x);      \
      f32x2 h2 = fp8x2_dec<false>((U).y), h3 = fp8x2_dec<true>((U).y);      \
      f32x2 v0 = h0 + H0, v1 = h1 + H1, v2 = h2 + H2, v3 = h3 + H3;         \
      v0 = pk_max(v0, v0 * 0.2f);                                           \
      v1 = pk_max(v1, v1 * 0.2f);                                           \
      v2 = pk_max(v2, v2 * 0.2f);                                           \
      v3 = pk_max(v3, v3 * 0.2f);                                           \
      f32x2 pv = pk_fma(v0, A0, pk_fma(v1, A1, pk_fma(v2, A2, v3 * A3)));   \
      float p = pv.x + pv.y;                                                \
      p += __shfl_xor(p, 1);                                                \
      float a = __expf(fminf(p, 60.f));                                     \
      f32x2 av = {a, a};                                                    \
      n0 = pk_fma(h0, av, n0);                                              \
      n1 = pk_fma(h1, av, n1);                                              \
      n2 = pk_fma(h2, av, n2);                                              \
      n3 = pk_fma(h3, av, n3);                                              \
      D += a;                                                               \
    }

    int i = beg + q;
    for (; i + 4 < end; i += 8) {
      int s0 = cs[i], s1 = cs[i + 4];
      uint2 u0 = *((const uint2*)(hsk + (long)s0 * 128) + j);
      uint2 u1 = *((const uint2*)(hsk + (long)s1 * 128) + j);
      GA_EDGE(u0);
      GA_EDGE(u1);
    }
    if (i < end) {
      int s = cs[i];
      uint2 u = *((const uint2*)(hsk + (long)s * 128) + j);
      GA_EDGE(u);
    }
#undef GA_EDGE

    // combine the 4 quarter streams (flip lane bits 4 and 5)
#pragma unroll
    for (int o = 16; o < 64; o <<= 1) {
      n0.x += __shfl_xor(n0.x, o); n0.y += __shfl_xor(n0.y, o);
      n1.x += __shfl_xor(n1.x, o); n1.y += __shfl_xor(n1.y, o);
      n2.x += __shfl_xor(n2.x, o); n2.y += __shfl_xor(n2.y, o);
      n3.x += __shfl_xor(n3.x, o); n3.y += __shfl_xor(n3.y, o);
      D += __shfl_xor(D, o);
    }
    float inv = 1.f / (D + 1e-16f);
    f32x2 iv = {inv, inv};
    T0 = pk_fma(n0, iv, T0);
    T1 = pk_fma(n1, iv, T1);
    T2 = pk_fma(n2, iv, T2);
    T3 = pk_fma(n3, iv, T3);
  }
  if (q == 0) {                          // lanes 0..15 hold the full row
    float* apg = sg.agg + (long)d * 128 + 8 * j;
    float4 c0 = *(const float4*)apg;
    float4 c1 = *(const float4*)(apg + 4);
    c0.x += T0.x; c0.y += T0.y; c0.z += T1.x; c0.w += T1.y;
    c1.x += T2.x; c1.y += T2.y; c1.z += T3.x; c1.w += T3.y;
    *(float4*)apg = c0;
    *(float4*)(apg + 4) = c1;
  }
}

// ---------------------------------------------------------------------------
// Fused LayerNorm update for all 3 node types in one launch.
// ---------------------------------------------------------------------------
struct LJob {
  const float* xin; float* xf; unsigned short* xb;
  const float* agg; const float* biasl; int tmask;
  const float* gam; const float* bet; int N;
};
struct LArgs { LJob j[3]; int off[4]; };

__global__ __launch_bounds__(256) void update_ln_all(LArgs a)
{
  int blk = blockIdx.x, t = 0;
  while (blk >= a.off[t + 1]) ++t;
  const LJob& J = a.j[t];
  int row = (blk - a.off[t]) * 4 + (threadIdx.x >> 6);
  int lane = threadIdx.x & 63;
  if (row >= J.N) return;
  float bs0 = 0.f, bs1 = 0.f;
#pragma unroll
  for (int tt = 0; tt < 8; ++tt)
    if (J.tmask & (1 << tt)) {
      bs0 += J.biasl[tt * 128 + lane];
      bs1 += J.biasl[tt * 128 + 64 + lane];
    }
  long base = (long)row * 128;
  float v0 = J.agg[base + lane] + bs0, v1 = J.agg[base + 64 + lane] + bs1;
  v0 = v0 > 0.f ? v0 : __expf(v0) - 1.f;
  v1 = v1 > 0.f ? v1 : __expf(v1) - 1.f;
  float x0 = J.xin[base + lane] + v0, x1 = J.xin[base + 64 + lane] + v1;
  float s = x0 + x1;
#pragma unroll
  for (int o = 32; o > 0; o >>= 1) s += __shfl_xor(s, o);
  float mu = s * 0.0078125f;
  float dd0 = x0 - mu, dd1 = x1 - mu;
  float q = dd0 * dd0 + dd1 * dd1;
#pragma unroll
  for (int o = 32; o > 0; o >>= 1) q += __shfl_xor(q, o);
  float r = rsqrtf(q * 0.0078125f + 1e-5f);
  float y0 = dd0 * r * J.gam[lane] + J.bet[lane];
  float y1 = dd1 * r * J.gam[64 + lane] + J.bet[64 + lane];
  J.xf[base + lane] = y0; J.xf[base + 64 + lane] = y1;
  J.xb[base + lane] = f2b(y0); J.xb[base + 64 + lane] = f2b(y1);
}

// ---------------------------------------------------------------------------
// zgemm stage 1 fused over 3 types: one 64-row chunk per block, non-atomic.
// ---------------------------------------------------------------------------
struct ZArgs {
  const float* batch[3]; const float* x[3]; float* zp[3]; int N[3];
  int off[4];
};

__global__ __launch_bounds__(256) void zgemm_all(ZArgs z)
{
  __shared__ __align__(16) float xl[64 * 128];
  __shared__ __align__(16) float bl[64 * 65];
  int blk = blockIdx.x, s = 0;
  while (blk >= z.off[s + 1]) ++s;
  int chunk = blk - z.off[s];
  const float* batch = z.batch[s];
  const float* x = z.x[s];
  int N = z.N[s];
  int tid = threadIdx.x;
  int n0 = chunk * 64;
  for (int i = tid; i < 64 * 128; i += 256) {
    int nn = i >> 7;
    xl[i] = (n0 + nn < N) ? x[(long)(n0 + nn) * 128 + (i & 127)] : 0.f;
  }
  for (int i = tid; i < 64 * 64; i += 256) {
    int b = i >> 6, nn = i & 63;
    bl[nn * 65 + b] = (n0 + nn < N) ? batch[(long)b * N + n0 + nn] : 0.f;
  }
  __syncthreads();
  int cg = (tid & 31) * 4;
  int bg = (tid >> 5) * 8;
  float acc[8][4] = {};
  for (int nn = 0; nn < 64; ++nn) {
    float4 xv = *(const float4*)(xl + nn * 128 + cg);
#pragma unroll
    for (int i = 0; i < 8; ++i) {
      float bv = bl[nn * 65 + bg + i];
      acc[i][0] = fmaf(bv, xv.x, acc[i][0]);
      acc[i][1] = fmaf(bv, xv.y, acc[i][1]);
      acc[i][2] = fmaf(bv, xv.z, acc[i][2]);
      acc[i][3] = fmaf(bv, xv.w, acc[i][3]);
    }
  }
  float* zp = z.zp[s] + (long)chunk * 8192;
#pragma unroll
  for (int i = 0; i < 8; ++i) {
    float4 v = {acc[i][0], acc[i][1], acc[i][2], acc[i][3]};
    *(float4*)(zp + (bg + i) * 128 + cg) = v;
  }
}

// ---------------------------------------------------------------------------
// zgemm stage 2: 16 independent accumulators -> 16 loads in flight.
// ---------------------------------------------------------------------------
__global__ __launch_bounds__(256) void zreduce(
    const float* __restrict__ zp0, const float* __restrict__ zp1,
    const float* __restrict__ zp2, int G0, int G1, int G2,
    float s0, float s1, float s2, float* __restrict__ zpre)
{
  int blk = blockIdx.x;
  int ty = blk >> 5;
  int i = (blk & 31) * 256 + threadIdx.x;
  const float* zp = ty == 0 ? zp0 : (ty == 1 ? zp1 : zp2);
  int G = ty == 0 ? G0 : (ty == 1 ? G1 : G2);
  float sc = ty == 0 ? s0 : (ty == 1 ? s1 : s2);
  float a[16];
#pragma unroll
  for (int u = 0; u < 16; ++u) a[u] = 0.f;
  int g = 0;
  for (; g + 16 <= G; g += 16) {
#pragma unroll
    for (int u = 0; u < 16; ++u) a[u] += zp[(long)(g + u) * 8192 + i];
  }
  for (; g < G; ++g) a[0] += zp[(long)g * 8192 + i];
  float s = (((a[0] + a[1]) + (a[2] + a[3])) + ((a[4] + a[5]) + (a[6] + a[7])))
          + (((a[8] + a[9]) + (a[10] + a[11])) + ((a[12] + a[13]) + (a[14] + a[15])));
  zpre[ty * 8192 + i] = s * sc;
}

// ---------------------------------------------------------------------------
// Final LayerNorm over zpre[3*64,128] -> f32 out. 1 wave/row.
// ---------------------------------------------------------------------------
__global__ __launch_bounds__(256) void final_ln(
    const float* __restrict__ zpre, const float* __restrict__ gam,
    const float* __restrict__ bet, float* __restrict__ out)
{
  int row = blockIdx.x * 4 + (threadIdx.x >> 6);
  int lane = threadIdx.x & 63;
  if (row >= 192) return;
  int ty = row >> 6;
  long base = (long)row * 128;
  float x0 = zpre[base + lane], x1 = zpre[base + 64 + lane];
  float s = x0 + x1;
#pragma unroll
  for (int o = 32; o > 0; o >>= 1) s += __shfl_xor(s, o);
  float mu = s * 0.0078125f;
  float d0 = x0 - mu, d1 = x1 - mu;
  float q = d0 * d0 + d1 * d1;
#pragma unroll
  for (int o = 32; o > 0; o >>= 1) q += __shfl_xor(q, o);
  float r = rsqrtf(q * 0.0078125f + 1e-5f);
  out[base + lane]      = d0 * r * gam[ty * 128 + lane]      + bet[ty * 128 + lane];
  out[base + 64 + lane] = d1 * r * gam[ty * 128 + 64 + lane] + bet[ty * 128 + 64 + lane];
}

// ---------------------------------------------------------------------------
extern "C" void kernel_launch(void* const* d_in, const int* in_sizes, int n_in,
                              void* d_out, int out_size, void* d_ws, size_t ws_size,
                              hipStream_t stream)
{
  const float* batchp[3] = {(const float*)d_in[0], (const float*)d_in[1],
                            (const float*)d_in[2]};
  const float* emb[3] = {(const float*)d_in[3], (const float*)d_in[4],
                         (const float*)d_in[5]};
  const float* Wl   = (const float*)d_in[6];
  const float* Wr   = (const float*)d_in[7];
  const float* att  = (const float*)d_in[8];
  const float* bias = (const float*)d_in[9];
  const float* lng  = (const float*)d_in[10];
  const float* lnb  = (const float*)d_in[11];
  const float* outg = (const float*)d_in[12];
  const float* outb = (const float*)d_in[13];
  const int* eiP[8]; int E[8];
  for (int t = 0; t < 8; ++t) { eiP[t] = (const int*)d_in[14 + t]; E[t] = in_sizes[14 + t] / 2; }
  int Nn[3] = {in_sizes[3] / 128, in_sizes[4] / 128, in_sizes[5] / 128};
  long Ntot = (long)Nn[0] + Nn[1] + Nn[2];

  const int SI[5] = {1, 0, 2, 0, 0};
  const int DI[5] = {0, 1, 0, 2, 0};
  const int TMASK[3] = {0x35, 0x42, 0x88};  // gene: t0,t2,t4,t5; cpg: t1,t6; mirna: t3,t7

  char* p = (char*)d_ws;
  auto carve = [&](size_t b) -> void* {
    void* r = (void*)p; p += (b + 255) & ~(size_t)255; return r;
  };
  float* xf[3];
  for (int ty = 0; ty < 3; ++ty) xf[ty] = (float*)carve((size_t)Nn[ty] * 128 * 4);
  unsigned short* xb[3];
  for (int ty = 0; ty < 3; ++ty) xb[ty] = (unsigned short*)carve((size_t)Nn[ty] * 128 * 2);
  float* aggAll = (float*)carve((size_t)Ntot * 128 * 4);
  float* agg[3] = {aggAll, aggAll + (long)Nn[0] * 128, aggAll + ((long)Nn[0] + Nn[1]) * 128};
  // per-edge-type hs (bf16, contiguous) + hd (bf16)
  unsigned short* hsT[5];
  unsigned short* hdT[5];
  char* projRegion = p;
  for (int t = 0; t < 5; ++t) hsT[t] = (unsigned short*)carve((size_t)Nn[SI[t]] * 128 * 2);
  for (int t = 0; t < 5; ++t) hdT[t] = (unsigned short*)carve((size_t)Nn[DI[t]] * 128 * 2);
  size_t projBytes = (size_t)(p - projRegion);
  // fp8 hs region (contiguous, parallel layout to hsT)
  long hsElems = 0;
  for (int t = 0; t < 5; ++t) hsElems += (long)Nn[SI[t]] * 128;
  unsigned char* hs8base = (unsigned char*)carve((size_t)hsElems);
  unsigned char* hs8T[5];
  {
    unsigned char* q8 = hs8base;
    for (int t = 0; t < 5; ++t) { hs8T[t] = q8; q8 += (long)Nn[SI[t]] * 128; }
  }
  float* zpre = (float*)carve(3 * 64 * 128 * 4);
  unsigned short* wtb = (unsigned short*)carve((size_t)32 * 16384 * 2);

  // bucketed CSR build (no global atomics)
  BArgs ba;
  {
    int cOff = 0, fOff = 0;
    for (int t = 0; t < 5; ++t) {
      int nd = Nn[DI[t]];
      ba.src[t] = eiP[t];
      ba.dst[t] = eiP[t] + E[t];
      ba.E[t] = E[t];
      ba.Nd[t] = nd;
      ba.NB[t] = (E[t] + 4095) / 4096;
      ba.B[t] = (nd + 127) / 128;
      ba.cnt[t] = (int*)carve((size_t)ba.B[t] * ba.NB[t] * 4);
      ba.tmp[t] = (int*)carve((size_t)E[t] * 4);
      ba.rs[t] = (int*)carve((size_t)(nd + 1) * 4);
      ba.csrc[t] = (int*)carve((size_t)E[t] * 4);
      ba.cOff[t] = cOff; cOff += ba.NB[t];
      ba.fOff[t] = fOff; fOff += ba.B[t];
    }
    ba.cOff[5] = cOff;
    ba.fOff[5] = fOff;
  }
  if ((size_t)(p - (char*)d_ws) > ws_size) return;  // workspace too small

  // zgemm partials alias the hs/hd bf16 region (dead after the layer loop)
  int nch[3];
  for (int ty = 0; ty < 3; ++ty) nch[ty] = (Nn[ty] + 63) / 64;
  float* zp[3];
  zp[0] = (float*)projRegion;
  zp[1] = zp[0] + (long)nch[0] * 8192;
  zp[2] = zp[1] + (long)nch[1] * 8192;
  if ((size_t)(nch[0] + nch[1] + nch[2]) * 8192 * 4 > projBytes) return;

  auto WTB = [&](int l, int t, int which) {
    return wtb + ((long)((l * 8 + t) * 2 + which) << 14);
  };

  // 0) weight prep + emb casts
  prep_w<<<2048, 256, 0, stream>>>(Wl, Wr, wtb);
  {
    int n0 = Nn[0] * 32, n1 = Nn[1] * 32, n2 = Nn[2] * 32;
    cast_all<<<(int)((n0 + n1 + n2 + 255) / 256), 256, 0, stream>>>(
        emb[0], emb[1], emb[2], xb[0], xb[1], xb[2], n0, n1, n2);
  }

  // 1) CSR build (4 launches, zero global atomics)
  bucket_count<<<ba.cOff[5], 256, 0, stream>>>(ba);
  bucket_scan<<<5, 1024, 0, stream>>>(ba);
  bucket_scatter<<<ba.cOff[5], 256, 0, stream>>>(ba);
  bucket_finalize<<<ba.fOff[5], 256, 0, stream>>>(ba);

  const int GT[3][3] = {{0, 2, 4}, {1, -1, -1}, {3, -1, -1}};
  const int GN[3] = {3, 1, 1};

  for (int l = 0; l < 2; ++l) {
    const float* xinf[3] = {l == 0 ? emb[0] : xf[0],
                            l == 0 ? emb[1] : xf[1],
                            l == 0 ? emb[2] : xf[2]};
    // A) all 13 projections in one launch (self-convs STORE into agg)
    PArgs pa;
    {
      int off = 0, j = 0;
      auto add = [&](const unsigned short* x, const unsigned short* wt,
                     void* out, int N, int mode) {
        pa.j[j] = {x, wt, out, N, mode};
        pa.off[j] = off;
        off += (N + 127) / 128;
        ++j;
      };
      for (int t = 0; t < 5; ++t) add(xb[SI[t]], WTB(l, t, 0), hsT[t], Nn[SI[t]], 2);
      for (int t = 0; t < 5; ++t) add(xb[DI[t]], WTB(l, t, 1), hdT[t], Nn[DI[t]], 2);
      for (int ty = 0; ty < 3; ++ty) add(xb[ty], WTB(l, 5 + ty, 0), agg[ty], Nn[ty], 0);
      pa.off[13] = off;
      mproj_all<<<off, 256, 0, stream>>>(pa);
    }
    // A2) hs bf16 -> fp8 (contiguous region, one launch)
    {
      long n8 = hsElems / 8;
      cast_fp8<<<(int)((n8 + 255) / 256), 256, 0, stream>>>(hsT[0], hs8base, n8);
    }
    // B) all gathers in one launch (per-dst-row over its incident edge types)
    GArgs ga;
    {
      int off = 0;
      for (int s = 0; s < 3; ++s) {
        GSeg& sg = ga.s[s];
        sg.agg = agg[s];
        sg.Nd = Nn[s];
        sg.ntypes = GN[s];
        for (int k = 0; k < GN[s]; ++k) {
          int t = GT[s][k];
          sg.rs[k] = ba.rs[t];
          sg.csrc[k] = ba.csrc[t];
          sg.hs[k] = hs8T[t];
          sg.hd[k] = hdT[t];
          sg.att[k] = att + (long)(l * 8 + t) * 128;
        }
        ga.off[s] = off;
        off += (Nn[s] + 3) / 4;
      }
      ga.off[3] = off;
      gat_gather_all<<<off, 256, 0, stream>>>(ga);
    }
    // C) LN update for all 3 types in one launch
    LArgs la;
    {
      int off = 0;
      for (int ty = 0; ty < 3; ++ty) {
        la.j[ty] = {xinf[ty], xf[ty], xb[ty], agg[ty],
                    bias + (long)l * 8 * 128, TMASK[ty],
                    lng + (long)(l * 3 + ty) * 128,
                    lnb + (long)(l * 3 + ty) * 128, Nn[ty]};
        la.off[ty] = off;
        off += (Nn[ty] + 3) / 4;
      }
      la.off[3] = off;
      update_ln_all<<<off, 256, 0, stream>>>(la);
    }
  }

  // final: z = LN(batch @ x / sqrt(N))
  ZArgs za;
  {
    int off = 0;
    for (int ty = 0; ty < 3; ++ty) {
      za.batch[ty] = batchp[ty];
      za.x[ty] = xf[ty];
      za.zp[ty] = zp[ty];
      za.N[ty] = Nn[ty];
      za.off[ty] = off;
      off += nch[ty];
    }
    za.off[3] = off;
    zgemm_all<<<off, 256, 0, stream>>>(za);
  }
  zreduce<<<96, 256, 0, stream>>>(
      zp[0], zp[1], zp[2], nch[0], nch[1], nch[2],
      (float)(1.0 / sqrt((double)Nn[0])), (float)(1.0 / sqrt((double)Nn[1])),
      (float)(1.0 / sqrt((double)Nn[2])), zpre);
  final_ln<<<48, 256, 0, stream>>>(zpre, outg, outb, (float*)d_out);
}

// Round 15
// 558.539 us; speedup vs baseline: 3.7174x; 1.0354x over previous
//
#include <hip/hip_runtime.h>
#include <math.h>

typedef __attribute__((ext_vector_type(4))) float f32x4;
typedef __attribute__((ext_vector_type(2))) float f32x2;
typedef __attribute__((ext_vector_type(8))) short bf16x8;

__device__ __forceinline__ float b2f(unsigned short u) {
  return __uint_as_float(((unsigned)u) << 16);
}
__device__ __forceinline__ unsigned short f2b(float f) {
  unsigned x = __float_as_uint(f);
  unsigned r = (x + 0x7FFFu + ((x >> 16) & 1u)) >> 16;
  return (unsigned short)r;
}
__device__ __forceinline__ f32x2 bf2x2(unsigned u) {
  f32x2 r;
  r.x = __uint_as_float(u << 16);
  r.y = __uint_as_float(u & 0xFFFF0000u);
  return r;
}
__device__ __forceinline__ f32x2 pk_max(f32x2 a, f32x2 b) {
#if __has_builtin(__builtin_elementwise_max)
  return __builtin_elementwise_max(a, b);
#else
  f32x2 r; r.x = fmaxf(a.x, b.x); r.y = fmaxf(a.y, b.y); return r;
#endif
}
__device__ __forceinline__ f32x2 pk_fma(f32x2 a, f32x2 b, f32x2 c) {
#if __has_builtin(__builtin_elementwise_fma)
  return __builtin_elementwise_fma(a, b, c);
#else
  f32x2 r; r.x = fmaf(a.x, b.x, c.x); r.y = fmaf(a.y, b.y, c.y); return r;
#endif
}

// ---- fp8 e4m3 (OCP): HW cvt on gfx950 (hi-select is an immediate ->
// template), software fallback otherwise ------------------------------------
#if __has_builtin(__builtin_amdgcn_cvt_pk_f32_fp8)
template<bool HI>
__device__ __forceinline__ f32x2 fp8x2_dec(unsigned w) {
  return __builtin_amdgcn_cvt_pk_f32_fp8(w, HI);
}
#else
__device__ __forceinline__ float fp8_dec1(unsigned b) {
  unsigned s = b >> 7, e = (b >> 3) & 15, m = b & 7;
  float v = (e == 0) ? (float)m * 0.001953125f
                     : __uint_as_float(((e - 7 + 127) << 23) | (m << 20));
  return s ? -v : v;
}
template<bool HI>
__device__ __forceinline__ f32x2 fp8x2_dec(unsigned w) {
  unsigned h = HI ? (w >> 16) : w;
  f32x2 r; r.x = fp8_dec1(h & 0xFF); r.y = fp8_dec1((h >> 8) & 0xFF);
  return r;
}
#endif
#if __has_builtin(__builtin_amdgcn_cvt_pk_fp8_f32)
template<bool HI>
__device__ __forceinline__ int fp8x2_enc(float a, float b, int old) {
  return __builtin_amdgcn_cvt_pk_fp8_f32(a, b, old, HI);
}
#else
__device__ __forceinline__ unsigned fp8_enc1(float f) {
  unsigned s = (__float_as_uint(f) >> 31) << 7;
  float a = fabsf(f);
  if (a >= 448.f) return s | 0x7E;
  if (a < 0.015625f) {
    int m = (int)(a * 512.f + 0.5f);
    return s | (unsigned)(m > 7 ? 7 : m);
  }
  int ex; (void)frexpf(a, &ex);
  int E = ex - 1;
  float sig = a * exp2f((float)(-E));
  int m = (int)((sig - 1.f) * 8.f + 0.5f);
  if (m == 8) { m = 0; E += 1; }
  if (E > 8) return s | 0x7E;
  return s | (unsigned)((E + 7) << 3) | (unsigned)m;
}
template<bool HI>
__device__ __forceinline__ int fp8x2_enc(float a, float b, int old) {
  unsigned pk = fp8_enc1(a) | (fp8_enc1(b) << 8);
  return HI ? ((old & 0x0000FFFF) | (int)(pk << 16))
            : ((old & (int)0xFFFF0000) | (int)pk);
}
#endif

// ---------------------------------------------------------------------------
// Weight prep: wt[mat][c][k] = bf16(W[mat>>1][k][c]);  mat=(l*8+t)*2+which
// ---------------------------------------------------------------------------
__global__ __launch_bounds__(256) void prep_w(
    const float* __restrict__ Wl, const float* __restrict__ Wr,
    unsigned short* __restrict__ wt)
{
  int elem = blockIdx.x * 256 + threadIdx.x;
  int mat = elem >> 14;
  int c = (elem >> 7) & 127;
  int k = elem & 127;
  const float* srcb = (mat & 1) ? Wr : Wl;
  wt[elem] = f2b(srcb[((long)(mat >> 1) << 14) + (k << 7) + c]);
}

// ---------------------------------------------------------------------------
// Cast emb (f32) -> xb (bf16), all 3 types fused (float4 chunks).
// ---------------------------------------------------------------------------
__global__ __launch_bounds__(256) void cast_all(
    const float* __restrict__ e0, const float* __restrict__ e1,
    const float* __restrict__ e2, unsigned short* __restrict__ x0,
    unsigned short* __restrict__ x1, unsigned short* __restrict__ x2,
    int n0, int n1, int n2)
{
  int i = blockIdx.x * 256 + threadIdx.x;
  const float* s; unsigned short* d; int loc = i;
  if (loc < n0) { s = e0; d = x0; }
  else {
    loc -= n0;
    if (loc < n1) { s = e1; d = x1; }
    else { loc -= n1; if (loc >= n2) return; s = e2; d = x2; }
  }
  float4 v = *(const float4*)(s + (long)loc * 4);
  ushort4 o = {f2b(v.x), f2b(v.y), f2b(v.z), f2b(v.w)};
  *(ushort4*)(d + (long)loc * 4) = o;
}

// ---------------------------------------------------------------------------
// Precompute masked bias sums: bsum[l][ty][c] = sum_{t in mask(ty)} bias[l,t,c]
// ---------------------------------------------------------------------------
__global__ __launch_bounds__(128) void prep_bias(
    const float* __restrict__ bias, float* __restrict__ bsum)
{
  int c = threadIdx.x;
  const int TM[3] = {0x35, 0x42, 0x88};
  for (int l = 0; l < 2; ++l)
    for (int ty = 0; ty < 3; ++ty) {
      float s = 0.f;
      for (int t = 0; t < 8; ++t)
        if (TM[ty] & (1 << t)) s += bias[(l * 8 + t) * 128 + c];
      bsum[(l * 3 + ty) * 128 + c] = s;
    }
}

// ---------------------------------------------------------------------------
// Cast hs region (bf16) -> fp8 e4m3, 8 elements/thread.
// ---------------------------------------------------------------------------
__global__ __launch_bounds__(256) void cast_fp8(
    const unsigned short* __restrict__ src, unsigned char* __restrict__ dst,
    long n8)
{
  long i = (long)blockIdx.x * 256 + threadIdx.x;
  if (i >= n8) return;
  uint4 v = *(const uint4*)(src + i * 8);
  f32x2 a = bf2x2(v.x), b = bf2x2(v.y), c = bf2x2(v.z), d = bf2x2(v.w);
  int lo = 0, hi = 0;
  lo = fp8x2_enc<false>(a.x, a.y, lo);
  lo = fp8x2_enc<true>(b.x, b.y, lo);
  hi = fp8x2_enc<false>(c.x, c.y, hi);
  hi = fp8x2_enc<true>(d.x, d.y, hi);
  uint2 o = {(unsigned)lo, (unsigned)hi};
  *(uint2*)(dst + i * 8) = o;
}

// ---------------------------------------------------------------------------
// MFMA projection tile (mode: 0 store f32, 2 store bf16).
// ---------------------------------------------------------------------------
__device__ __forceinline__ void mproj_tile(
    char* lx, char* lw, const unsigned short* __restrict__ xb,
    const unsigned short* __restrict__ wt, void* __restrict__ outv,
    int N, long r0, int tid, int mode)
{
#pragma unroll
  for (int i = 0; i < 8; ++i) {
    int ch = i * 256 + tid;
    int row = ch >> 4, k0 = (ch & 15) << 3;
    uint4 xv = {0u, 0u, 0u, 0u};
    if (r0 + row < N) xv = *(const uint4*)(xb + (r0 + row) * 128 + k0);
    *(uint4*)(lx + ((row * 256 + k0 * 2) ^ ((row & 7) << 4))) = xv;
    uint4 wv = *(const uint4*)(wt + (long)ch * 8);
    *(uint4*)(lw + ((ch * 16) ^ ((row & 7) << 4))) = wv;
  }
  __syncthreads();

  const int lane = tid & 63;
  const int lr = lane & 15, lk = lane >> 4;
  const int rbase = (tid >> 6) * 32;
  f32x4 acc[2][8] = {};
#pragma unroll
  for (int kb = 0; kb < 4; ++kb) {
    int k = kb * 32 + lk * 8;
    int ra = rbase + lr;
    bf16x8 a0 = *(const bf16x8*)(lx + ((ra * 256 + k * 2) ^ ((ra & 7) << 4)));
    int rb = rbase + 16 + lr;
    bf16x8 a1 = *(const bf16x8*)(lx + ((rb * 256 + k * 2) ^ ((rb & 7) << 4)));
#pragma unroll
    for (int cc = 0; cc < 8; ++cc) {
      int col = cc * 16 + lr;
      bf16x8 bfr = *(const bf16x8*)(lw + ((col * 256 + k * 2) ^ ((col & 7) << 4)));
      acc[0][cc] = __builtin_amdgcn_mfma_f32_16x16x32_bf16(a0, bfr, acc[0][cc], 0, 0, 0);
      acc[1][cc] = __builtin_amdgcn_mfma_f32_16x16x32_bf16(a1, bfr, acc[1][cc], 0, 0, 0);
    }
  }
  __syncthreads();   // safe LDS reuse across segmented jobs
#pragma unroll
  for (int rt = 0; rt < 2; ++rt) {
    int rowb = rbase + rt * 16 + lk * 4;
#pragma unroll
    for (int cc = 0; cc < 8; ++cc) {
      int col = cc * 16 + lr;
#pragma unroll
      for (int q = 0; q < 4; ++q) {
        long row = r0 + rowb + q;
        if (row < N) {
          if (mode == 2)
            ((unsigned short*)outv)[row * 128 + col] = f2b(acc[rt][cc][q]);
          else
            ((float*)outv)[row * 128 + col] = acc[rt][cc][q];
        }
      }
    }
  }
}

struct PJob { const unsigned short* x; const unsigned short* wt; void* out; int N; int mode; };
struct PArgs { PJob j[13]; int off[14]; };

__global__ __launch_bounds__(256) void mproj_all(PArgs a)
{
  __shared__ __align__(16) char lx[32768];
  __shared__ __align__(16) char lw[32768];
  int blk = blockIdx.x, t = 0;
  while (blk >= a.off[t + 1]) ++t;
  const PJob& J = a.j[t];
  mproj_tile(lx, lw, J.x, J.wt, J.out, J.N, (long)(blk - a.off[t]) * 128,
             threadIdx.x, J.mode);
}

// ---------------------------------------------------------------------------
// Atomic-free bucketed CSR build (bucket = 128 dst nodes, 4096 edges/block).
// ---------------------------------------------------------------------------
struct BArgs {
  const int* src[5]; const int* dst[5];
  int* cnt[5];
  int* tmp[5];
  int* rs[5];
  int* csrc[5];
  int E[5], Nd[5], NB[5], B[5];
  int cOff[6], fOff[6];
};

__global__ __launch_bounds__(256) void bucket_count(BArgs a)
{
  __shared__ int h[512];
  int blk = blockIdx.x, t = 0;
  while (blk >= a.cOff[t + 1]) ++t;
  int lb = blk - a.cOff[t];
  int B = a.B[t], NB = a.NB[t], E = a.E[t];
  for (int i = threadIdx.x; i < B; i += 256) h[i] = 0;
  __syncthreads();
  const int* dst = a.dst[t];
  int base = lb * 4096;
#pragma unroll
  for (int j = 0; j < 16; ++j) {
    int e = base + j * 256 + threadIdx.x;
    if (e < E) atomicAdd(&h[dst[e] >> 7], 1);   // LDS atomic
  }
  __syncthreads();
  int* cnt = a.cnt[t];
  for (int b = threadIdx.x; b < B; b += 256) cnt[b * NB + lb] = h[b];
}

__global__ __launch_bounds__(1024) void bucket_scan(BArgs a)
{
  int t = blockIdx.x;
  int n = a.B[t] * a.NB[t];
  int* dp = a.cnt[t];
  __shared__ int wsum[16];
  __shared__ int sbase, ctot;
  int tid = threadIdx.x;
  int lane = tid & 63, wid = tid >> 6;
  if (tid == 0) sbase = 0;
  __syncthreads();
  for (int chunk = 0; chunk < n; chunk += 16384) {
    int idx0 = chunk + tid * 16;
    int v[16], lsum = 0;
#pragma unroll
    for (int j = 0; j < 16; ++j) {
      v[j] = (idx0 + j < n) ? dp[idx0 + j] : 0;
      lsum += v[j];
    }
    int sc = lsum;
#pragma unroll
    for (int o = 1; o < 64; o <<= 1) {
      int u = __shfl_up(sc, o);
      if (lane >= o) sc += u;
    }
    if (lane == 63) wsum[wid] = sc;
    __syncthreads();
    if (wid == 0) {
      int w = (lane < 16) ? wsum[lane] : 0;
      int s2 = w;
#pragma unroll
      for (int o = 1; o < 16; o <<= 1) {
        int u = __shfl_up(s2, o);
        if (lane >= o) s2 += u;
      }
      if (lane < 16) wsum[lane] = s2 - w;
      if (lane == 15) ctot = s2;
    }
    __syncthreads();
    int excl = sbase + wsum[wid] + (sc - lsum);
#pragma unroll
    for (int j = 0; j < 16; ++j) {
      if (idx0 + j < n) dp[idx0 + j] = excl;
      excl += v[j];
    }
    __syncthreads();
    if (tid == 0) sbase += ctot;
    __syncthreads();
  }
}

__global__ __launch_bounds__(256) void bucket_scatter(BArgs a)
{
  __shared__ int cur[512];
  int blk = blockIdx.x, t = 0;
  while (blk >= a.cOff[t + 1]) ++t;
  int lb = blk - a.cOff[t];
  int B = a.B[t], NB = a.NB[t], E = a.E[t];
  const int* cnt = a.cnt[t];
  for (int b = threadIdx.x; b < B; b += 256) cur[b] = cnt[b * NB + lb];
  __syncthreads();
  const int* src = a.src[t];
  const int* dst = a.dst[t];
  int* tmp = a.tmp[t];
  int base = lb * 4096;
#pragma unroll
  for (int j = 0; j < 16; ++j) {
    int e = base + j * 256 + threadIdx.x;
    if (e < E) {
      int dv = dst[e];
      int pos = atomicAdd(&cur[dv >> 7], 1);    // LDS atomic
      tmp[pos] = ((dv & 127) << 16) | src[e];
    }
  }
}

__global__ __launch_bounds__(256) void bucket_finalize(BArgs a)
{
  __shared__ int h[128], sc[128], ex[128], cur[128];
  int blk = blockIdx.x, t = 0;
  while (blk >= a.fOff[t + 1]) ++t;
  int b = blk - a.fOff[t];
  int B = a.B[t], NB = a.NB[t], E = a.E[t], Nd = a.Nd[t];
  const int* cnt = a.cnt[t];
  const int* tmp = a.tmp[t];
  int* rs = a.rs[t];
  int* csrc = a.csrc[t];
  int tid = threadIdx.x;
  int beg = cnt[b * NB];
  int end = (b + 1 < B) ? cnt[(b + 1) * NB] : E;
  if (tid < 128) h[tid] = 0;
  __syncthreads();
  for (int i = beg + tid; i < end; i += 256)
    atomicAdd(&h[tmp[i] >> 16], 1);             // LDS atomic
  __syncthreads();
  if (tid < 128) sc[tid] = h[tid];
  __syncthreads();
#pragma unroll
  for (int off = 1; off < 128; off <<= 1) {
    int v = (tid < 128 && tid >= off) ? sc[tid - off] : 0;
    __syncthreads();
    if (tid < 128) sc[tid] += v;
    __syncthreads();
  }
  if (tid < 128) {
    ex[tid] = sc[tid] - h[tid];
    cur[tid] = 0;
    int dg = b * 128 + tid;
    if (dg < Nd) rs[dg] = beg + ex[tid];
  }
  if (b == B - 1 && tid == 0) rs[Nd] = E;
  __syncthreads();
  for (int i = beg + tid; i < end; i += 256) {
    int v = tmp[i];
    int d = v >> 16;
    int r = atomicAdd(&cur[d], 1);              // LDS atomic
    csrc[beg + ex[d] + r] = v & 0xFFFF;
  }
}

// ---------------------------------------------------------------------------
// Fused gather + LayerNorm: wave owns one dst row. hs fp8 (128B rows), hd
// bf16. 16 lanes/edge (8 ch each), 4 quarter-streams, index-prefetched
// 2-deep pipeline. After the butterfly every lane holds the full gathered
// totals for its 8 channels -> apply bias+ELU+residual+LN in-register and
// write xf (f32) + xb (bf16). No agg round-trip, no separate LN kernel.
// ---------------------------------------------------------------------------
struct GSeg {
  const int* rs[3]; const int* csrc[3];
  const unsigned char* hs[3]; const unsigned short* hd[3];
  const float* att[3];
  const float* aggSelf;   // self-conv result [Nd][128] f32
  const float* xin;       // residual input  [Nd][128] f32
  float* xf; unsigned short* xb;
  const float* bsum;      // [128] masked bias sum
  const float* gam; const float* bet;
  int Nd; int ntypes;
};
struct GArgs { GSeg s[3]; int off[4]; };

__global__ __launch_bounds__(256) void gat_gather_ln(GArgs g)
{
  int blk = blockIdx.x, si = 0;
  while (blk >= g.off[si + 1]) ++si;
  const GSeg& sg = g.s[si];
  int d = (blk - g.off[si]) * 4 + (threadIdx.x >> 6);
  if (d >= sg.Nd) return;
  int lane = threadIdx.x & 63;
  int q = lane >> 4, j = lane & 15;   // lane owns channels 8j..8j+7
  f32x2 T0 = {0.f, 0.f}, T1 = {0.f, 0.f}, T2 = {0.f, 0.f}, T3 = {0.f, 0.f};
  for (int k = 0; k < sg.ntypes; ++k) {
    const float* ap = sg.att[k] + 8 * j;
    float4 aa = *(const float4*)ap;
    float4 ab = *(const float4*)(ap + 4);
    f32x2 A0 = {aa.x, aa.y}, A1 = {aa.z, aa.w};
    f32x2 A2 = {ab.x, ab.y}, A3 = {ab.z, ab.w};
    uint4 hu = *((const uint4*)(sg.hd[k] + (long)d * 128) + j);
    f32x2 H0 = bf2x2(hu.x), H1 = bf2x2(hu.y);
    f32x2 H2 = bf2x2(hu.z), H3 = bf2x2(hu.w);
    const int* cs = sg.csrc[k];
    const unsigned char* hsk = sg.hs[k];
    int beg = sg.rs[k][d], end = sg.rs[k][d + 1];
    f32x2 n0 = {0.f, 0.f}, n1 = {0.f, 0.f}, n2 = {0.f, 0.f}, n3 = {0.f, 0.f};
    float D = 0.f;

#define GA_EDGE(U)                                                          \
    {                                                                       \
      f32x2 h0 = fp8x2_dec<false>((U).x), h1 = fp8x2_dec<true>((U).x);      \
      f32x2 h2 = fp8x2_dec<false>((U).y), h3 = fp8x2_dec<true>((U).y);      \
      f32x2 v0 = h0 + H0, v1 = h1 + H1, v2 = h2 + H2, v3 = h3 + H3;         \
      v0 = pk_max(v0, v0 * 0.2f);                                           \
      v1 = pk_max(v1, v1 * 0.2f);                                           \
      v2 = pk_max(v2, v2 * 0.2f);                                           \
      v3 = pk_max(v3, v3 * 0.2f);                                           \
      f32x2 pv = pk_fma(v0, A0, pk_fma(v1, A1, pk_fma(v2, A2, v3 * A3)));   \
      float p = pv.x + pv.y;                                                \
      p += __shfl_xor(p, 1);                                                \
      float a = __expf(fminf(p, 60.f));                                     \
      f32x2 av = {a, a};                                                    \
      n0 = pk_fma(h0, av, n0);                                              \
      n1 = pk_fma(h1, av, n1);                                              \
      n2 = pk_fma(h2, av, n2);                                              \
      n3 = pk_fma(h3, av, n3);                                              \
      D += a;                                                               \
    }

    int i = beg + q;
    int sA = (i < end) ? cs[i] : 0;
    int sB = (i + 4 < end) ? cs[i + 4] : 0;
    for (; i + 4 < end; i += 8) {
      uint2 u0 = *((const uint2*)(hsk + (long)sA * 128) + j);
      uint2 u1 = *((const uint2*)(hsk + (long)sB * 128) + j);
      sA = (i + 8 < end) ? cs[i + 8] : 0;
      sB = (i + 12 < end) ? cs[i + 12] : 0;
      GA_EDGE(u0);
      GA_EDGE(u1);
    }
    if (i < end) {
      uint2 u = *((const uint2*)(hsk + (long)sA * 128) + j);
      GA_EDGE(u);
    }
#undef GA_EDGE

#pragma unroll
    for (int o = 16; o < 64; o <<= 1) {
      n0.x += __shfl_xor(n0.x, o); n0.y += __shfl_xor(n0.y, o);
      n1.x += __shfl_xor(n1.x, o); n1.y += __shfl_xor(n1.y, o);
      n2.x += __shfl_xor(n2.x, o); n2.y += __shfl_xor(n2.y, o);
      n3.x += __shfl_xor(n3.x, o); n3.y += __shfl_xor(n3.y, o);
      D += __shfl_xor(D, o);
    }
    float inv = 1.f / (D + 1e-16f);
    f32x2 iv = {inv, inv};
    T0 = pk_fma(n0, iv, T0);
    T1 = pk_fma(n1, iv, T1);
    T2 = pk_fma(n2, iv, T2);
    T3 = pk_fma(n3, iv, T3);
  }

  // ---- fused bias + ELU + residual + LayerNorm epilogue ----
  long base = (long)d * 128 + 8 * j;
  float4 sA0 = *(const float4*)(sg.aggSelf + base);
  float4 sA1 = *(const float4*)(sg.aggSelf + base + 4);
  float4 bb0 = *(const float4*)(sg.bsum + 8 * j);
  float4 bb1 = *(const float4*)(sg.bsum + 8 * j + 4);
  float v[8];
  v[0] = sA0.x + T0.x + bb0.x; v[1] = sA0.y + T0.y + bb0.y;
  v[2] = sA0.z + T1.x + bb0.z; v[3] = sA0.w + T1.y + bb0.w;
  v[4] = sA1.x + T2.x + bb1.x; v[5] = sA1.y + T2.y + bb1.y;
  v[6] = sA1.z + T3.x + bb1.z; v[7] = sA1.w + T3.y + bb1.w;
#pragma unroll
  for (int c = 0; c < 8; ++c) v[c] = v[c] > 0.f ? v[c] : __expf(v[c]) - 1.f;
  float4 xi0 = *(const float4*)(sg.xin + base);
  float4 xi1 = *(const float4*)(sg.xin + base + 4);
  float xr[8] = {xi0.x + v[0], xi0.y + v[1], xi0.z + v[2], xi0.w + v[3],
                 xi1.x + v[4], xi1.y + v[5], xi1.z + v[6], xi1.w + v[7]};
  float ssum = ((xr[0] + xr[1]) + (xr[2] + xr[3])) +
               ((xr[4] + xr[5]) + (xr[6] + xr[7]));
#pragma unroll
  for (int o = 1; o < 16; o <<= 1) ssum += __shfl_xor(ssum, o);
  float mu = ssum * 0.0078125f;
  float qs = 0.f;
#pragma unroll
  for (int c = 0; c < 8; ++c) { float dd = xr[c] - mu; qs += dd * dd; }
#pragma unroll
  for (int o = 1; o < 16; o <<= 1) qs += __shfl_xor(qs, o);
  float rr = rsqrtf(qs * 0.0078125f + 1e-5f);
  float4 g0 = *(const float4*)(sg.gam + 8 * j);
  float4 g1 = *(const float4*)(sg.gam + 8 * j + 4);
  float4 e0 = *(const float4*)(sg.bet + 8 * j);
  float4 e1 = *(const float4*)(sg.bet + 8 * j + 4);
  float y[8];
  y[0] = (xr[0] - mu) * rr * g0.x + e0.x;
  y[1] = (xr[1] - mu) * rr * g0.y + e0.y;
  y[2] = (xr[2] - mu) * rr * g0.z + e0.z;
  y[3] = (xr[3] - mu) * rr * g0.w + e0.w;
  y[4] = (xr[4] - mu) * rr * g1.x + e1.x;
  y[5] = (xr[5] - mu) * rr * g1.y + e1.y;
  y[6] = (xr[6] - mu) * rr * g1.z + e1.z;
  y[7] = (xr[7] - mu) * rr * g1.w + e1.w;
  if (q == 0) {
    float4 o0 = {y[0], y[1], y[2], y[3]};
    float4 o1 = {y[4], y[5], y[6], y[7]};
    *(float4*)(sg.xf + base) = o0;
    *(float4*)(sg.xf + base + 4) = o1;
    uint4 ub;
    ub.x = (unsigned)f2b(y[0]) | ((unsigned)f2b(y[1]) << 16);
    ub.y = (unsigned)f2b(y[2]) | ((unsigned)f2b(y[3]) << 16);
    ub.z = (unsigned)f2b(y[4]) | ((unsigned)f2b(y[5]) << 16);
    ub.w = (unsigned)f2b(y[6]) | ((unsigned)f2b(y[7]) << 16);
    *(uint4*)(sg.xb + base) = ub;
  }
}

// ---------------------------------------------------------------------------
// zgemm stage 1 fused over 3 types: one 64-row chunk per block, non-atomic.
// ---------------------------------------------------------------------------
struct ZArgs {
  const float* batch[3]; const float* x[3]; float* zp[3]; int N[3];
  int off[4];
};

__global__ __launch_bounds__(256) void zgemm_all(ZArgs z)
{
  __shared__ __align__(16) float xl[64 * 128];
  __shared__ __align__(16) float bl[64 * 65];
  int blk = blockIdx.x, s = 0;
  while (blk >= z.off[s + 1]) ++s;
  int chunk = blk - z.off[s];
  const float* batch = z.batch[s];
  const float* x = z.x[s];
  int N = z.N[s];
  int tid = threadIdx.x;
  int n0 = chunk * 64;
  for (int i = tid; i < 64 * 128; i += 256) {
    int nn = i >> 7;
    xl[i] = (n0 + nn < N) ? x[(long)(n0 + nn) * 128 + (i & 127)] : 0.f;
  }
  for (int i = tid; i < 64 * 64; i += 256) {
    int b = i >> 6, nn = i & 63;
    bl[nn * 65 + b] = (n0 + nn < N) ? batch[(long)b * N + n0 + nn] : 0.f;
  }
  __syncthreads();
  int cg = (tid & 31) * 4;
  int bg = (tid >> 5) * 8;
  float acc[8][4] = {};
  for (int nn = 0; nn < 64; ++nn) {
    float4 xv = *(const float4*)(xl + nn * 128 + cg);
#pragma unroll
    for (int i = 0; i < 8; ++i) {
      float bv = bl[nn * 65 + bg + i];
      acc[i][0] = fmaf(bv, xv.x, acc[i][0]);
      acc[i][1] = fmaf(bv, xv.y, acc[i][1]);
      acc[i][2] = fmaf(bv, xv.z, acc[i][2]);
      acc[i][3] = fmaf(bv, xv.w, acc[i][3]);
    }
  }
  float* zp = z.zp[s] + (long)chunk * 8192;
#pragma unroll
  for (int i = 0; i < 8; ++i) {
    float4 v = {acc[i][0], acc[i][1], acc[i][2], acc[i][3]};
    *(float4*)(zp + (bg + i) * 128 + cg) = v;
  }
}

// ---------------------------------------------------------------------------
// zfinal: partial reduce (8 dual accumulators) + scale + LayerNorm -> out.
// 48 blocks x 256; wave w of block handles row (blk%16)*4+w of type blk/16.
// ---------------------------------------------------------------------------
__global__ __launch_bounds__(256) void zfinal(
    const float* __restrict__ zp0, const float* __restrict__ zp1,
    const float* __restrict__ zp2, int G0, int G1, int G2,
    float s0, float s1, float s2, const float* __restrict__ gam,
    const float* __restrict__ bet, float* __restrict__ out)
{
  int blk = blockIdx.x;
  int ty = blk >> 4;
  int rowL = (blk & 15) * 4 + (threadIdx.x >> 6);
  int lane = threadIdx.x & 63;
  const float* zp = ty == 0 ? zp0 : (ty == 1 ? zp1 : zp2);
  int G = ty == 0 ? G0 : (ty == 1 ? G1 : G2);
  float sc = ty == 0 ? s0 : (ty == 1 ? s1 : s2);
  long i0 = rowL * 128 + lane, i1 = i0 + 64;
  float a0[8], a1[8];
#pragma unroll
  for (int u = 0; u < 8; ++u) { a0[u] = 0.f; a1[u] = 0.f; }
  int g = 0;
  for (; g + 8 <= G; g += 8) {
#pragma unroll
    for (int u = 0; u < 8; ++u) {
      a0[u] += zp[(long)(g + u) * 8192 + i0];
      a1[u] += zp[(long)(g + u) * 8192 + i1];
    }
  }
  for (; g < G; ++g) { a0[0] += zp[(long)g * 8192 + i0]; a1[0] += zp[(long)g * 8192 + i1]; }
  float x0 = (((a0[0] + a0[1]) + (a0[2] + a0[3])) + ((a0[4] + a0[5]) + (a0[6] + a0[7]))) * sc;
  float x1 = (((a1[0] + a1[1]) + (a1[2] + a1[3])) + ((a1[4] + a1[5]) + (a1[6] + a1[7]))) * sc;
  float s = x0 + x1;
#pragma unroll
  for (int o = 32; o > 0; o >>= 1) s += __shfl_xor(s, o);
  float mu = s * 0.0078125f;
  float d0 = x0 - mu, d1 = x1 - mu;
  float qv = d0 * d0 + d1 * d1;
#pragma unroll
  for (int o = 32; o > 0; o >>= 1) qv += __shfl_xor(qv, o);
  float r = rsqrtf(qv * 0.0078125f + 1e-5f);
  long base = (long)(ty * 64 + rowL) * 128;
  out[base + lane]      = d0 * r * gam[ty * 128 + lane]      + bet[ty * 128 + lane];
  out[base + 64 + lane] = d1 * r * gam[ty * 128 + 64 + lane] + bet[ty * 128 + 64 + lane];
}

// ---------------------------------------------------------------------------
extern "C" void kernel_launch(void* const* d_in, const int* in_sizes, int n_in,
                              void* d_out, int out_size, void* d_ws, size_t ws_size,
                              hipStream_t stream)
{
  const float* batchp[3] = {(const float*)d_in[0], (const float*)d_in[1],
                            (const float*)d_in[2]};
  const float* emb[3] = {(const float*)d_in[3], (const float*)d_in[4],
                         (const float*)d_in[5]};
  const float* Wl   = (const float*)d_in[6];
  const float* Wr   = (const float*)d_in[7];
  const float* att  = (const float*)d_in[8];
  const float* bias = (const float*)d_in[9];
  const float* lng  = (const float*)d_in[10];
  const float* lnb  = (const float*)d_in[11];
  const float* outg = (const float*)d_in[12];
  const float* outb = (const float*)d_in[13];
  const int* eiP[8]; int E[8];
  for (int t = 0; t < 8; ++t) { eiP[t] = (const int*)d_in[14 + t]; E[t] = in_sizes[14 + t] / 2; }
  int Nn[3] = {in_sizes[3] / 128, in_sizes[4] / 128, in_sizes[5] / 128};
  long Ntot = (long)Nn[0] + Nn[1] + Nn[2];

  const int SI[5] = {1, 0, 2, 0, 0};
  const int DI[5] = {0, 1, 0, 2, 0};

  char* p = (char*)d_ws;
  auto carve = [&](size_t b) -> void* {
    void* r = (void*)p; p += (b + 255) & ~(size_t)255; return r;
  };
  float* xf[3];
  for (int ty = 0; ty < 3; ++ty) xf[ty] = (float*)carve((size_t)Nn[ty] * 128 * 4);
  unsigned short* xb[3];
  for (int ty = 0; ty < 3; ++ty) xb[ty] = (unsigned short*)carve((size_t)Nn[ty] * 128 * 2);
  float* aggAll = (float*)carve((size_t)Ntot * 128 * 4);
  float* agg[3] = {aggAll, aggAll + (long)Nn[0] * 128, aggAll + ((long)Nn[0] + Nn[1]) * 128};
  // per-edge-type hs (bf16, contiguous) + hd (bf16)
  unsigned short* hsT[5];
  unsigned short* hdT[5];
  char* projRegion = p;
  for (int t = 0; t < 5; ++t) hsT[t] = (unsigned short*)carve((size_t)Nn[SI[t]] * 128 * 2);
  for (int t = 0; t < 5; ++t) hdT[t] = (unsigned short*)carve((size_t)Nn[DI[t]] * 128 * 2);
  size_t projBytes = (size_t)(p - projRegion);
  // fp8 hs region (contiguous, parallel layout to hsT)
  long hsElems = 0;
  for (int t = 0; t < 5; ++t) hsElems += (long)Nn[SI[t]] * 128;
  unsigned char* hs8base = (unsigned char*)carve((size_t)hsElems);
  unsigned char* hs8T[5];
  {
    unsigned char* q8 = hs8base;
    for (int t = 0; t < 5; ++t) { hs8T[t] = q8; q8 += (long)Nn[SI[t]] * 128; }
  }
  float* bsumBuf = (float*)carve(2 * 3 * 128 * 4);
  unsigned short* wtb = (unsigned short*)carve((size_t)32 * 16384 * 2);

  // bucketed CSR build (no global atomics)
  BArgs ba;
  {
    int cOff = 0, fOff = 0;
    for (int t = 0; t < 5; ++t) {
      int nd = Nn[DI[t]];
      ba.src[t] = eiP[t];
      ba.dst[t] = eiP[t] + E[t];
      ba.E[t] = E[t];
      ba.Nd[t] = nd;
      ba.NB[t] = (E[t] + 4095) / 4096;
      ba.B[t] = (nd + 127) / 128;
      ba.cnt[t] = (int*)carve((size_t)ba.B[t] * ba.NB[t] * 4);
      ba.tmp[t] = (int*)carve((size_t)E[t] * 4);
      ba.rs[t] = (int*)carve((size_t)(nd + 1) * 4);
      ba.csrc[t] = (int*)carve((size_t)E[t] * 4);
      ba.cOff[t] = cOff; cOff += ba.NB[t];
      ba.fOff[t] = fOff; fOff += ba.B[t];
    }
    ba.cOff[5] = cOff;
    ba.fOff[5] = fOff;
  }
  if ((size_t)(p - (char*)d_ws) > ws_size) return;  // workspace too small

  // zgemm partials alias the hs/hd bf16 region (dead after the layer loop)
  int nch[3];
  for (int ty = 0; ty < 3; ++ty) nch[ty] = (Nn[ty] + 63) / 64;
  float* zp[3];
  zp[0] = (float*)projRegion;
  zp[1] = zp[0] + (long)nch[0] * 8192;
  zp[2] = zp[1] + (long)nch[1] * 8192;
  if ((size_t)(nch[0] + nch[1] + nch[2]) * 8192 * 4 > projBytes) return;

  auto WTB = [&](int l, int t, int which) {
    return wtb + ((long)((l * 8 + t) * 2 + which) << 14);
  };

  // 0) weight prep + emb casts + bias sums
  prep_w<<<2048, 256, 0, stream>>>(Wl, Wr, wtb);
  {
    int n0 = Nn[0] * 32, n1 = Nn[1] * 32, n2 = Nn[2] * 32;
    cast_all<<<(int)((n0 + n1 + n2 + 255) / 256), 256, 0, stream>>>(
        emb[0], emb[1], emb[2], xb[0], xb[1], xb[2], n0, n1, n2);
  }
  prep_bias<<<1, 128, 0, stream>>>(bias, bsumBuf);

  // 1) CSR build (4 launches, zero global atomics)
  bucket_count<<<ba.cOff[5], 256, 0, stream>>>(ba);
  bucket_scan<<<5, 1024, 0, stream>>>(ba);
  bucket_scatter<<<ba.cOff[5], 256, 0, stream>>>(ba);
  bucket_finalize<<<ba.fOff[5], 256, 0, stream>>>(ba);

  const int GT[3][3] = {{0, 2, 4}, {1, -1, -1}, {3, -1, -1}};
  const int GN[3] = {3, 1, 1};

  for (int l = 0; l < 2; ++l) {
    const float* xinf[3] = {l == 0 ? emb[0] : xf[0],
                            l == 0 ? emb[1] : xf[1],
                            l == 0 ? emb[2] : xf[2]};
    // A) all 13 projections in one launch (self-convs STORE f32 into agg)
    PArgs pa;
    {
      int off = 0, j = 0;
      auto add = [&](const unsigned short* x, const unsigned short* wt,
                     void* out, int N, int mode) {
        pa.j[j] = {x, wt, out, N, mode};
        pa.off[j] = off;
        off += (N + 127) / 128;
        ++j;
      };
      for (int t = 0; t < 5; ++t) add(xb[SI[t]], WTB(l, t, 0), hsT[t], Nn[SI[t]], 2);
      for (int t = 0; t < 5; ++t) add(xb[DI[t]], WTB(l, t, 1), hdT[t], Nn[DI[t]], 2);
      for (int ty = 0; ty < 3; ++ty) add(xb[ty], WTB(l, 5 + ty, 0), agg[ty], Nn[ty], 0);
      pa.off[13] = off;
      mproj_all<<<off, 256, 0, stream>>>(pa);
    }
    // A2) hs bf16 -> fp8
    {
      long n8 = hsElems / 8;
      cast_fp8<<<(int)((n8 + 255) / 256), 256, 0, stream>>>(hsT[0], hs8base, n8);
    }
    // B) fused gather + LN, one launch for all 3 dst types
    GArgs ga;
    {
      int off = 0;
      for (int s = 0; s < 3; ++s) {
        GSeg& sg = ga.s[s];
        sg.aggSelf = agg[s];
        sg.xin = xinf[s];
        sg.xf = xf[s];
        sg.xb = xb[s];
        sg.bsum = bsumBuf + (long)(l * 3 + s) * 128;
        sg.gam = lng + (long)(l * 3 + s) * 128;
        sg.bet = lnb + (long)(l * 3 + s) * 128;
        sg.Nd = Nn[s];
        sg.ntypes = GN[s];
        for (int k = 0; k < GN[s]; ++k) {
          int t = GT[s][k];
          sg.rs[k] = ba.rs[t];
          sg.csrc[k] = ba.csrc[t];
          sg.hs[k] = hs8T[t];
          sg.hd[k] = hdT[t];
          sg.att[k] = att + (long)(l * 8 + t) * 128;
        }
        ga.off[s] = off;
        off += (Nn[s] + 3) / 4;
      }
      ga.off[3] = off;
      gat_gather_ln<<<off, 256, 0, stream>>>(ga);
    }
  }

  // final: z = LN(batch @ x / sqrt(N))
  ZArgs za;
  {
    int off = 0;
    for (int ty = 0; ty < 3; ++ty) {
      za.batch[ty] = batchp[ty];
      za.x[ty] = xf[ty];
      za.zp[ty] = zp[ty];
      za.N[ty] = Nn[ty];
      za.off[ty] = off;
      off += nch[ty];
    }
    za.off[3] = off;
    zgemm_all<<<off, 256, 0, stream>>>(za);
  }
  zfinal<<<48, 256, 0, stream>>>(
      zp[0], zp[1], zp[2], nch[0], nch[1], nch[2],
      (float)(1.0 / sqrt((double)Nn[0])), (float)(1.0 / sqrt((double)Nn[1])),
      (float)(1.0 / sqrt((double)Nn[2])), outg, outb, (float*)d_out);
}